// Round 7
// baseline (272.252 us; speedup 1.0000x reference)
//
#include <hip/hip_runtime.h>
#include <hip/hip_bf16.h>

#define B_ 4
#define T_ 512
#define N_ 16
#define D_ 256
#define H_ 8
#define DK_ 32
#define NT_ (N_ * T_)
#define CTS_ 6
#define CN_ 4
#define CE_ 3
#define TSE_ 192
#define AUXE_ 64
#define SPLIT_ 4
#define KWORDS_ (NT_ / 64)   // 128 mask words per row

// Q pre-scale: (1/sqrt(32)) * log2(e)  -> MFMA output is already in exp2 domain
#define QSCALE_ 0.2550689747f
// fixed softmax shift (exp2 domain): 8 * log2(e)
#define C2_ 11.5415603f

typedef unsigned long long ull;
typedef unsigned int uint;
typedef __bf16 bf16x8 __attribute__((ext_vector_type(8)));
typedef float f32x4 __attribute__((ext_vector_type(4)));

// ---------------------------------------------------------------- PE table
__global__ __launch_bounds__(256) void pe_kernel(float* pe) {
    int t = blockIdx.x;
    int d = threadIdx.x;
    int j = d >> 1;
    float div = expf((float)(2 * j) * (-9.210340371976184f / 256.0f)); // -ln(10000)/D
    float a = (float)t * div;
    pe[t * D_ + d] = (d & 1) ? cosf(a) : sinf(a);
}

// ------------------------------------- mask -> transposed bitmask [B][128][T]
__global__ __launch_bounds__(256) void maskbits_kernel(const int* __restrict__ mask,
                                                       ull* __restrict__ bitsT) {
    int row = blockIdx.x;  // b*T + t
    int b = row >> 9, t = row & (T_ - 1);
    const int* mrow = mask + (size_t)row * NT_;
    int lane = threadIdx.x & 63, wave = threadIdx.x >> 6;
    for (int it = 0; it < NT_ / 256; ++it) {
        int k = it * 256 + wave * 64 + lane;
        ull bal = __ballot(mrow[k] != 0);
        if (lane == 0) bitsT[((size_t)b * KWORDS_ + (k >> 6)) * T_ + t] = bal;
    }
}

// -------------------------------- weight prep: bf16, fragment-tiled layouts
__global__ __launch_bounds__(256) void wprep_kernel(
    const float* __restrict__ W_ts1, const float* __restrict__ W_a1,
    const float* __restrict__ W_e1, const float* __restrict__ W_ts2,
    const float* __restrict__ W_a2, const float* __restrict__ W_e2,
    const float* __restrict__ Wk, const float* __restrict__ Wv,
    __bf16* __restrict__ ts1P, __bf16* __restrict__ a1P, __bf16* __restrict__ e1P,
    __bf16* __restrict__ ts2T, __bf16* __restrict__ a2T, __bf16* __restrict__ e2T,
    __bf16* __restrict__ WkT, __bf16* __restrict__ WvT) {
    int i = blockIdx.x * 256 + threadIdx.x;
    if (i < 6144) { int col = i >> 5, k = i & 31;
        ts1P[i] = (__bf16)(k < 6 ? W_ts1[k * TSE_ + col] : 0.f); return; }
    i -= 6144;
    if (i < 2048) { int col = i >> 5, k = i & 31;
        a1P[i] = (__bf16)((k >= 6 && k < 10) ? W_a1[(k - 6) * AUXE_ + col] : 0.f); return; }
    i -= 2048;
    if (i < 8192) { int col = i >> 5, k = i & 31;
        e1P[i] = (__bf16)((k >= 10 && k < 13) ? W_e1[(k - 10) * D_ + col] : 0.f); return; }
    i -= 8192;
    if (i < 36864) {  // ts2: COLS=192, KS=6
        int tile = i >> 9, lr = (i >> 5) & 15, kk = i & 31;
        int ct = tile / 6, ks = tile % 6;
        ts2T[i] = (__bf16)W_ts2[(ks * 32 + kk) * TSE_ + ct * 16 + lr]; return; }
    i -= 36864;
    if (i < 4096) {   // a2: COLS=64, KS=2
        int tile = i >> 9, lr = (i >> 5) & 15, kk = i & 31;
        int ct = tile / 2, ks = tile % 2;
        a2T[i] = (__bf16)W_a2[(ks * 32 + kk) * AUXE_ + ct * 16 + lr]; return; }
    i -= 4096;
    if (i < 65536) {  // e2: COLS=256, KS=8
        int tile = i >> 9, lr = (i >> 5) & 15, kk = i & 31;
        int ct = tile >> 3, ks = tile & 7;
        e2T[i] = (__bf16)W_e2[(ks * 32 + kk) * D_ + ct * 16 + lr]; return; }
    i -= 65536;
    if (i < 65536) {  // Wk
        int tile = i >> 9, lr = (i >> 5) & 15, kk = i & 31;
        int ct = tile >> 3, ks = tile & 7;
        WkT[i] = (__bf16)Wk[(ks * 32 + kk) * D_ + ct * 16 + lr]; return; }
    i -= 65536;
    {                 // Wv
        int tile = i >> 9, lr = (i >> 5) & 15, kk = i & 31;
        int ct = tile >> 3, ks = tile & 7;
        WvT[i] = (__bf16)Wv[(ks * 32 + kk) * D_ + ct * 16 + lr]; }
}

// ------------------------- MFMA kv chain: 64 rows/block, 4 waves x 16-row tiles
__global__ __launch_bounds__(256, 2) void kv_mfma_kernel(
    const float* __restrict__ md, const float* __restrict__ na, const float* __restrict__ ea,
    const __bf16* __restrict__ ts1P, const __bf16* __restrict__ a1P,
    const __bf16* __restrict__ e1P,
    const float* __restrict__ b_ts1, const float* __restrict__ b_a1,
    const float* __restrict__ b_e1,
    const __bf16* __restrict__ ts2T, const __bf16* __restrict__ a2T,
    const __bf16* __restrict__ e2T,
    const float* __restrict__ b_ts2, const float* __restrict__ b_a2,
    const float* __restrict__ b_e2,
    const __bf16* __restrict__ WkT, const float* __restrict__ bk,
    const __bf16* __restrict__ WvT, const float* __restrict__ bv,
    const float* __restrict__ pe, __bf16* __restrict__ Kb, __bf16* __restrict__ Vt) {
    int blk = blockIdx.x;          // 4b * 16n * 8t = 512
    int t0 = (blk & 7) * 64;
    int n = (blk >> 3) & 15;
    int b = blk >> 7;
    int tid = threadIdx.x, lane = tid & 63, w = tid >> 6;
    int lr = lane & 15, lg = lane >> 4;

    __shared__ __bf16 sA[64 * 40];      // A_all: 13 channels + zero pad to K=32
    __shared__ __bf16 sU[34304];        // union: {hts,haux,hedge} then {skey,sval}
    __bf16* hts = sU;                   // [64][200]
    __bf16* haux = sU + 12800;          // [64][72]
    __bf16* hedge = sU + 17408;         // [64][264]
    __bf16* skey = sU;                  // [64][264]
    __bf16* sval = sU + 16896;          // [64][264]

    for (int i = tid; i < 64 * 40; i += 256) sA[i] = (__bf16)0.f;
    __syncthreads();
    {
        int t = tid & 63, cg = tid >> 6;
        size_t bn = (size_t)b * N_ + n;
        for (int c = cg; c < 13; c += 4) {
            float v;
            if (c < 6) v = md[(bn * CTS_ + c) * T_ + t0 + t];
            else if (c < 10) v = na[(bn * CN_ + (c - 6)) * T_ + t0 + t];
            else v = ea[(bn * CE_ + (c - 10)) * T_ + t0 + t];
            sA[t * 40 + c] = (__bf16)v;
        }
    }
    __syncthreads();

    int arow = w * 16 + lr;       // A-fragment row
    int crow = w * 16 + lg * 4;   // C-fragment row base (+reg)
    bf16x8 afrag1 = *(const bf16x8*)(sA + arow * 40 + lg * 8);
    int foff = lr * 32 + lg * 8;  // per-lane offset within a 512-elem fragment tile

    // ---- phase 2: first layers (K=32, one MFMA per col-tile), ReLU, store bf16
#pragma unroll 1
    for (int ct = 0; ct < 12; ++ct) {
        int gcol = ct * 16 + lr;
        bf16x8 bf = *(const bf16x8*)(ts1P + ct * 512 + foff);
        f32x4 z = {0.f, 0.f, 0.f, 0.f};
        f32x4 c = __builtin_amdgcn_mfma_f32_16x16x32_bf16(afrag1, bf, z, 0, 0, 0);
        float bias = b_ts1[gcol];
#pragma unroll
        for (int r = 0; r < 4; ++r) hts[(crow + r) * 200 + gcol] = (__bf16)fmaxf(c[r] + bias, 0.f);
    }
#pragma unroll 1
    for (int ct = 0; ct < 4; ++ct) {
        int gcol = ct * 16 + lr;
        bf16x8 bf = *(const bf16x8*)(a1P + ct * 512 + foff);
        f32x4 z = {0.f, 0.f, 0.f, 0.f};
        f32x4 c = __builtin_amdgcn_mfma_f32_16x16x32_bf16(afrag1, bf, z, 0, 0, 0);
        float bias = b_a1[gcol];
#pragma unroll
        for (int r = 0; r < 4; ++r) haux[(crow + r) * 72 + gcol] = (__bf16)fmaxf(c[r] + bias, 0.f);
    }
#pragma unroll 1
    for (int ct = 0; ct < 16; ++ct) {
        int gcol = ct * 16 + lr;
        bf16x8 bf = *(const bf16x8*)(e1P + ct * 512 + foff);
        f32x4 z = {0.f, 0.f, 0.f, 0.f};
        f32x4 c = __builtin_amdgcn_mfma_f32_16x16x32_bf16(afrag1, bf, z, 0, 0, 0);
        float bias = b_e1[gcol];
#pragma unroll
        for (int r = 0; r < 4; ++r) hedge[(crow + r) * 264 + gcol] = (__bf16)fmaxf(c[r] + bias, 0.f);
    }
    __syncthreads();

    // ---- phase 3: nbr (ts2|a2) and edg (e2) accumulators in registers
    f32x4 nacc[16], eacc[16];
#pragma unroll
    for (int ct = 0; ct < 16; ++ct) {
        nacc[ct] = (f32x4){0.f, 0.f, 0.f, 0.f};
        eacc[ct] = (f32x4){0.f, 0.f, 0.f, 0.f};
    }
#pragma unroll 1
    for (int ks = 0; ks < 8; ++ks) {
        bf16x8 af = *(const bf16x8*)(hedge + arow * 264 + ks * 32 + lg * 8);
#pragma unroll
        for (int ct = 0; ct < 16; ++ct) {
            bf16x8 bf = *(const bf16x8*)(e2T + (ct * 8 + ks) * 512 + foff);
            eacc[ct] = __builtin_amdgcn_mfma_f32_16x16x32_bf16(af, bf, eacc[ct], 0, 0, 0);
        }
    }
#pragma unroll 1
    for (int ks = 0; ks < 6; ++ks) {
        bf16x8 af = *(const bf16x8*)(hts + arow * 200 + ks * 32 + lg * 8);
#pragma unroll
        for (int ct = 0; ct < 12; ++ct) {
            bf16x8 bf = *(const bf16x8*)(ts2T + (ct * 6 + ks) * 512 + foff);
            nacc[ct] = __builtin_amdgcn_mfma_f32_16x16x32_bf16(af, bf, nacc[ct], 0, 0, 0);
        }
    }
#pragma unroll
    for (int ks = 0; ks < 2; ++ks) {
        bf16x8 af = *(const bf16x8*)(haux + arow * 72 + ks * 32 + lg * 8);
#pragma unroll
        for (int ct = 0; ct < 4; ++ct) {
            bf16x8 bf = *(const bf16x8*)(a2T + (ct * 2 + ks) * 512 + foff);
            nacc[12 + ct] = __builtin_amdgcn_mfma_f32_16x16x32_bf16(af, bf, nacc[12 + ct], 0, 0, 0);
        }
    }
    __syncthreads();   // hts/haux/hedge reads done; safe to overwrite union

    // ---- phase 3b: key = nbr*edg + pe, val = nbr + pe (bf16 into LDS)
#pragma unroll
    for (int ct = 0; ct < 16; ++ct) {
        int gcol = ct * 16 + lr;
        float nb_bias = (ct < 12) ? b_ts2[gcol] : b_a2[gcol - 192];
        float ed_bias = b_e2[gcol];
#pragma unroll
        for (int r = 0; r < 4; ++r) {
            int row = crow + r;
            float p = pe[(t0 + row) * D_ + gcol];
            float nb = nacc[ct][r] + nb_bias;
            float ed = eacc[ct][r] + ed_bias;
            skey[row * 264 + gcol] = (__bf16)(nb * ed + p);
            sval[row * 264 + gcol] = (__bf16)(nb + p);
        }
    }
    __syncthreads();

    // ---- phase 4: K/V projections (K=256 -> 8 ksteps per col-tile)
    size_t key0 = (size_t)n * T_ + t0;
#pragma unroll 1
    for (int ct = 0; ct < 16; ++ct) {
        int gcol = ct * 16 + lr;
        f32x4 ka = {0.f, 0.f, 0.f, 0.f}, va = {0.f, 0.f, 0.f, 0.f};
#pragma unroll
        for (int ks = 0; ks < 8; ++ks) {
            bf16x8 afk = *(const bf16x8*)(skey + arow * 264 + ks * 32 + lg * 8);
            bf16x8 afv = *(const bf16x8*)(sval + arow * 264 + ks * 32 + lg * 8);
            bf16x8 b8k = *(const bf16x8*)(WkT + (ct * 8 + ks) * 512 + foff);
            bf16x8 b8v = *(const bf16x8*)(WvT + (ct * 8 + ks) * 512 + foff);
            ka = __builtin_amdgcn_mfma_f32_16x16x32_bf16(afk, b8k, ka, 0, 0, 0);
            va = __builtin_amdgcn_mfma_f32_16x16x32_bf16(afv, b8v, va, 0, 0, 0);
        }
        float kbias = bk[gcol], vbias = bv[gcol];
        int h = gcol >> 5, dd = gcol & 31;
        size_t bh = (size_t)b * H_ + h;
#pragma unroll
        for (int r = 0; r < 4; ++r)
            Kb[(bh * NT_ + key0 + crow + r) * DK_ + dd] = (__bf16)(ka[r] + kbias);
        __bf16 tmp[4];
#pragma unroll
        for (int r = 0; r < 4; ++r) tmp[r] = (__bf16)(va[r] + vbias);
        *(ushort4*)(Vt + (bh * DK_ + dd) * NT_ + key0 + crow) = *(ushort4*)tmp;
    }
}

// -------------------------- xq = x + pe, LayerNorm, Q proj -> bf16 Qb (pre-scaled)
__global__ __launch_bounds__(256) void q_kernel(
    const float* __restrict__ x, const float* __restrict__ pe,
    const float* __restrict__ Wq, const float* __restrict__ bq,
    const float* __restrict__ ln_g, const float* __restrict__ ln_b,
    float* __restrict__ xq, __bf16* __restrict__ Qb) {
    int blk = blockIdx.x;
    int t0 = (blk & 31) * 16;
    int b = blk >> 5;
    int tid = threadIdx.x;

    __shared__ float s_xn[16][D_];
    __shared__ float s_red[8];

    for (int r = 0; r < 16; ++r) {
        int t = t0 + r;
        size_t off = ((size_t)b * T_ + t) * D_ + tid;
        float v = x[off] + pe[t * D_ + tid];
        xq[off] = v;
        float s1 = v, s2 = v * v;
#pragma unroll
        for (int o = 32; o; o >>= 1) {
            s1 += __shfl_down(s1, o, 64);
            s2 += __shfl_down(s2, o, 64);
        }
        if ((tid & 63) == 0) {
            s_red[tid >> 6] = s1;
            s_red[4 + (tid >> 6)] = s2;
        }
        __syncthreads();
        float t1 = s_red[0] + s_red[1] + s_red[2] + s_red[3];
        float t2 = s_red[4] + s_red[5] + s_red[6] + s_red[7];
        float mu = t1 * (1.f / D_);
        float var = t2 * (1.f / D_) - mu * mu;
        float rs = rsqrtf(var + 1e-6f);
        s_xn[r][tid] = (v - mu) * rs * ln_g[tid] + ln_b[tid];
        __syncthreads();
    }

    float acc[16];
#pragma unroll
    for (int r = 0; r < 16; ++r) acc[r] = bq[tid];
    for (int e = 0; e < D_; ++e) {
        float w = Wq[e * D_ + tid];
#pragma unroll
        for (int r = 0; r < 16; ++r) acc[r] += s_xn[r][e] * w;
    }
    for (int r = 0; r < 16; ++r) {
        Qb[((size_t)b * T_ + t0 + r) * D_ + tid] = (__bf16)(acc[r] * QSCALE_);
    }
}

// ---------------- MFMA attention: swapped QK^T, in-register P, PINNED prefetch
// grid: B*H*(T/64)*SPLIT = 1024 blocks, 256 threads (4 waves x 16 queries)
__global__ __launch_bounds__(256, 4) void attn_mfma_kernel(
    const __bf16* __restrict__ Qb, const __bf16* __restrict__ Kb,
    const __bf16* __restrict__ Vt, const ull* __restrict__ bitsT,
    float* __restrict__ Opart, float* __restrict__ Lpart) {
    int blk = blockIdx.x;
    int kh = blk & (SPLIT_ - 1);
    int qt = (blk >> 2) & 7;
    int h = (blk >> 5) & 7;
    int b = blk >> 8;
    int tid = threadIdx.x, lane = tid & 63, w = tid >> 6;
    int lg = lane >> 4, lr = lane & 15;

    const size_t bh = (size_t)b * H_ + h;
    const int TILES = KWORDS_ / SPLIT_;   // 32

    // Q fragment (B-role): lane holds Q[q=lr][d=lg*8..+8], pre-scaled by QSCALE
    int qrow = qt * 64 + w * 16 + lr;
    bf16x8 qfrag = *(const bf16x8*)(Qb + ((size_t)b * T_ + qrow) * D_ + h * DK_ + lg * 8);

    const __bf16* kp = Kb + bh * NT_ * DK_ + (size_t)(kh * TILES) * 64 * DK_;
    const __bf16* vp = Vt + bh * DK_ * NT_ + (size_t)(kh * TILES) * 64;
    const ull* mp = bitsT + (size_t)b * KWORDS_ * T_ + (size_t)(kh * TILES) * T_ + qrow;

    int koff[4], voff[4];
#pragma unroll
    for (int s = 0; s < 4; ++s) koff[s] = (s * 16 + lr) * DK_ + lg * 8;
#pragma unroll
    for (int i = 0; i < 4; ++i) voff[i] = ((i >> 1) * 16 + lr) * NT_ + (i & 1) * 32 + lg * 8;
    int src0 = ((2 * lg) & 3) * 16 + lr;
    int src1 = ((2 * lg + 1) & 3) * 16 + lr;
    bool hiHalf = (lg >= 2);

    f32x4 acc0 = {0.f, 0.f, 0.f, 0.f}, acc1 = {0.f, 0.f, 0.f, 0.f};
    float l_lane = 0.f;

    // preload tile 0 (K frags + mask)
    bf16x8 kc[4];
#pragma unroll
    for (int s = 0; s < 4; ++s) kc[s] = *(const bf16x8*)(kp + koff[s]);
    ull mw = *mp;

#pragma unroll 1
    for (int kt = 0; kt < TILES; ++kt) {
        // ---- issue current-tile V loads (consumed after softmax, latency hidden)
        bf16x8 vc[4];
#pragma unroll
        for (int i = 0; i < 4; ++i) vc[i] = *(const bf16x8*)(vp + voff[i]);
        // ---- issue next-tile K + mask loads (consumed next iteration)
        bf16x8 kn[4];
        ull mn = 0;
        if (kt + 1 < TILES) {
#pragma unroll
            for (int s = 0; s < 4; ++s) kn[s] = *(const bf16x8*)(kp + 64 * DK_ + koff[s]);
            mn = mp[T_];
        }
        // pin: loads above may NOT sink below this point
        __builtin_amdgcn_sched_barrier(0);

        // ---- S^T = mfma(K, Q): lane holds S[key=sub*16+lg*4+r][q=lr]
        f32x4 s4[4];
#pragma unroll
        for (int s = 0; s < 4; ++s) {
            f32x4 z = {0.f, 0.f, 0.f, 0.f};
            s4[s] = __builtin_amdgcn_mfma_f32_16x16x32_bf16(kc[s], qfrag, z, 0, 0, 0);
        }

        // ---- masked fixed-shift softmax (exp2 domain), l accumulates per-lane
        ull sh = mw >> (lg * 4);
        float p[4][4];
#pragma unroll
        for (int s = 0; s < 4; ++s) {
            uint nib = (uint)(sh >> (s * 16)) & 0xFu;
#pragma unroll
            for (int r = 0; r < 4; ++r) {
                float t = s4[s][r] - C2_;
                t = ((nib >> r) & 1u) ? t : -1e30f;
                float pv = exp2f(t);
                p[s][r] = pv;
                l_lane += pv;
            }
        }

        // ---- pack to bf16 pairs
        uint pk[4][2];
#pragma unroll
        for (int s = 0; s < 4; ++s)
#pragma unroll
            for (int r2 = 0; r2 < 2; ++r2) {
                uint r;
                asm("v_cvt_pk_bf16_f32 %0, %1, %2" : "=v"(r) : "v"(p[s][2 * r2]), "v"(p[s][2 * r2 + 1]));
                pk[s][r2] = r;
            }

        // ---- redistribute to P^T B-fragments
        uint pt[2][4];
#pragma unroll
        for (int kstep = 0; kstep < 2; ++kstep)
#pragma unroll
            for (int j = 0; j < 4; ++j) {
                int src = (j >> 1) ? src1 : src0;
                uint vA = __shfl(pk[kstep * 2 + 0][j & 1], src, 64);
                uint vB = __shfl(pk[kstep * 2 + 1][j & 1], src, 64);
                pt[kstep][j] = hiHalf ? vB : vA;
            }

        // ---- PV
#pragma unroll
        for (int kstep = 0; kstep < 2; ++kstep) {
            union { uint u[4]; bf16x8 v; } cvt;
            cvt.u[0] = pt[kstep][0]; cvt.u[1] = pt[kstep][1];
            cvt.u[2] = pt[kstep][2]; cvt.u[3] = pt[kstep][3];
            acc0 = __builtin_amdgcn_mfma_f32_16x16x32_bf16(vc[kstep], cvt.v, acc0, 0, 0, 0);
            acc1 = __builtin_amdgcn_mfma_f32_16x16x32_bf16(vc[2 + kstep], cvt.v, acc1, 0, 0, 0);
        }

        // advance; rotate prefetched K/mask into current
        kp += 64 * DK_;
        vp += 64;
        mp += T_;
        if (kt + 1 < TILES) {
#pragma unroll
            for (int s = 0; s < 4; ++s) kc[s] = kn[s];
            mw = mn;
        }
    }

    // ---- l: reduce across key-owning lane groups (lane bits 4,5)
    l_lane += __shfl_xor(l_lane, 16, 64);
    l_lane += __shfl_xor(l_lane, 32, 64);

    // ---- write partials
    size_t obase = (((size_t)kh * B_ + b) * H_ + h) * T_ + qt * 64;
    int qloc = w * 16 + lr;
    *(f32x4*)(Opart + (obase + qloc) * DK_ + lg * 4) = acc0;
    *(f32x4*)(Opart + (obase + qloc) * DK_ + 16 + lg * 4) = acc1;
    if (lg == 0) Lpart[obase + qloc] = l_lane;
}

// ------------------------------------ merge split-K partials (plain sums) -> ctx
__global__ __launch_bounds__(256) void merge_kernel(
    const float* __restrict__ Opart, const float* __restrict__ Lpart,
    float* __restrict__ ctx) {
    int idx = blockIdx.x * 256 + threadIdx.x;  // B*H*T*32 total
    int d = idx & 31;
    int t = (idx >> 5) & (T_ - 1);
    int bh = idx >> 14;
    int h = bh & 7, b = bh >> 3;
    size_t ps = (size_t)B_ * H_ * T_;
    size_t base = (size_t)bh * T_ + t;
    float L = 0.f, o = 0.f;
#pragma unroll
    for (int s = 0; s < SPLIT_; ++s) {
        L += Lpart[s * ps + base];
        o += Opart[(s * ps + base) * DK_ + d];
    }
    ctx[((size_t)b * T_ + t) * D_ + h * DK_ + d] = o / L;
}

// ------------------------------------------------ out = xq + ctx@Wo + bo
__global__ __launch_bounds__(256) void out_kernel(
    const float* __restrict__ ctx, const float* __restrict__ xq,
    const float* __restrict__ Wo, const float* __restrict__ bo, float* __restrict__ out) {
    int blk = blockIdx.x;
    int t0 = (blk & 31) * 16;
    int b = blk >> 5;
    int tid = threadIdx.x;
    __shared__ float s_c[16][D_];
    for (int r = 0; r < 16; ++r)
        s_c[r][tid] = ctx[((size_t)b * T_ + t0 + r) * D_ + tid];
    __syncthreads();
    float acc[16];
#pragma unroll
    for (int r = 0; r < 16; ++r) acc[r] = bo[tid];
    for (int e = 0; e < D_; ++e) {
        float w = Wo[e * D_ + tid];
#pragma unroll
        for (int r = 0; r < 16; ++r) acc[r] += s_c[r][e] * w;
    }
    for (int r = 0; r < 16; ++r) {
        size_t off = ((size_t)b * T_ + t0 + r) * D_ + tid;
        out[off] = xq[off] + acc[r];
    }
}

// ---------------------------------------------------------------- launcher
extern "C" void kernel_launch(void* const* d_in, const int* in_sizes, int n_in,
                              void* d_out, int out_size, void* d_ws, size_t ws_size,
                              hipStream_t stream) {
    const float* x = (const float*)d_in[0];
    const float* md = (const float*)d_in[1];
    const float* na = (const float*)d_in[2];
    const float* ea = (const float*)d_in[3];
    const int* mask = (const int*)d_in[4];
    const float* W_ts1 = (const float*)d_in[5];
    const float* b_ts1 = (const float*)d_in[6];
    const float* W_ts2 = (const float*)d_in[7];
    const float* b_ts2 = (const float*)d_in[8];
    const float* W_a1 = (const float*)d_in[9];
    const float* b_a1 = (const float*)d_in[10];
    const float* W_a2 = (const float*)d_in[11];
    const float* b_a2 = (const float*)d_in[12];
    const float* W_e1 = (const float*)d_in[13];
    const float* b_e1 = (const float*)d_in[14];
    const float* W_e2 = (const float*)d_in[15];
    const float* b_e2 = (const float*)d_in[16];
    const float* Wq = (const float*)d_in[17];
    const float* bq = (const float*)d_in[18];
    const float* Wk = (const float*)d_in[19];
    const float* bk = (const float*)d_in[20];
    const float* Wv = (const float*)d_in[21];
    const float* bv = (const float*)d_in[22];
    const float* Wo = (const float*)d_in[23];
    const float* bo = (const float*)d_in[24];
    const float* ln_g = (const float*)d_in[25];
    const float* ln_b = (const float*)d_in[26];
    float* out = (float*)d_out;

    char* ws = (char*)d_ws;
    float* pe = (float*)ws;    ws += (size_t)T_ * D_ * 4;
    ull* bitsT = (ull*)ws;     ws += (size_t)B_ * KWORDS_ * T_ * 8;
    __bf16* Kb = (__bf16*)ws;  ws += (size_t)B_ * H_ * NT_ * DK_ * 2;
    __bf16* Vt = (__bf16*)ws;  ws += (size_t)B_ * H_ * DK_ * NT_ * 2;
    float* xq = (float*)ws;    ws += (size_t)B_ * T_ * D_ * 4;
    __bf16* Qb = (__bf16*)ws;  ws += (size_t)B_ * T_ * D_ * 2;
    float* ctx = (float*)ws;   ws += (size_t)B_ * T_ * D_ * 4;
    float* Opart = (float*)ws; ws += (size_t)SPLIT_ * B_ * H_ * T_ * DK_ * 4;
    float* Lpart = (float*)ws; ws += (size_t)SPLIT_ * B_ * H_ * T_ * 4;
    // bf16 prepped weights
    __bf16* ts1P = (__bf16*)ws; ws += 6144 * 2;
    __bf16* a1P = (__bf16*)ws;  ws += 2048 * 2;
    __bf16* e1P = (__bf16*)ws;  ws += 8192 * 2;
    __bf16* ts2T = (__bf16*)ws; ws += 36864 * 2;
    __bf16* a2T = (__bf16*)ws;  ws += 4096 * 2;
    __bf16* e2T = (__bf16*)ws;  ws += 65536 * 2;
    __bf16* WkT = (__bf16*)ws;  ws += 65536 * 2;
    __bf16* WvT = (__bf16*)ws;  ws += 65536 * 2;

    pe_kernel<<<T_, 256, 0, stream>>>(pe);
    maskbits_kernel<<<B_ * T_, 256, 0, stream>>>(mask, bitsT);
    wprep_kernel<<<992, 256, 0, stream>>>(W_ts1, W_a1, W_e1, W_ts2, W_a2, W_e2, Wk, Wv,
                                          ts1P, a1P, e1P, ts2T, a2T, e2T, WkT, WvT);
    kv_mfma_kernel<<<B_ * N_ * (T_ / 64), 256, 0, stream>>>(
        md, na, ea, ts1P, a1P, e1P, b_ts1, b_a1, b_e1,
        ts2T, a2T, e2T, b_ts2, b_a2, b_e2, WkT, bk, WvT, bv, pe, Kb, Vt);
    q_kernel<<<B_ * (T_ / 16), 256, 0, stream>>>(x, pe, Wq, bq, ln_g, ln_b, xq, Qb);
    attn_mfma_kernel<<<B_ * H_ * (T_ / 64) * SPLIT_, 256, 0, stream>>>(
        Qb, Kb, Vt, bitsT, Opart, Lpart);
    merge_kernel<<<(B_ * H_ * T_ * DK_) / 256, 256, 0, stream>>>(Opart, Lpart, ctx);
    out_kernel<<<B_ * (T_ / 16), 256, 0, stream>>>(ctx, xq, Wo, bo, out);
}

// Round 8
// 231.714 us; speedup vs baseline: 1.1749x; 1.1749x over previous
//
#include <hip/hip_runtime.h>
#include <hip/hip_bf16.h>

#define B_ 4
#define T_ 512
#define N_ 16
#define D_ 256
#define H_ 8
#define DK_ 32
#define NT_ (N_ * T_)
#define CTS_ 6
#define CN_ 4
#define CE_ 3
#define TSE_ 192
#define AUXE_ 64
#define SPLIT_ 8
#define KWORDS_ (NT_ / 64)   // 128 mask words per row

// Q pre-scale: (1/sqrt(32)) * log2(e)  -> MFMA output is already in exp2 domain
#define QSCALE_ 0.2550689747f
// fixed softmax shift (exp2 domain): 8 * log2(e)
#define C2_ 11.5415603f

typedef unsigned long long ull;
typedef unsigned int uint;
typedef __bf16 bf16x8 __attribute__((ext_vector_type(8)));
typedef float f32x4 __attribute__((ext_vector_type(4)));
typedef float f32x16 __attribute__((ext_vector_type(16)));

// ---------------------------------------------------------------- PE table
__global__ __launch_bounds__(256) void pe_kernel(float* pe) {
    int t = blockIdx.x;
    int d = threadIdx.x;
    int j = d >> 1;
    float div = expf((float)(2 * j) * (-9.210340371976184f / 256.0f)); // -ln(10000)/D
    float a = (float)t * div;
    pe[t * D_ + d] = (d & 1) ? cosf(a) : sinf(a);
}

// ------------------------------------- mask -> transposed bitmask [B][128][T]
__global__ __launch_bounds__(256) void maskbits_kernel(const int* __restrict__ mask,
                                                       ull* __restrict__ bitsT) {
    int row = blockIdx.x;  // b*T + t
    int b = row >> 9, t = row & (T_ - 1);
    const int* mrow = mask + (size_t)row * NT_;
    int lane = threadIdx.x & 63, wave = threadIdx.x >> 6;
    for (int it = 0; it < NT_ / 256; ++it) {
        int k = it * 256 + wave * 64 + lane;
        ull bal = __ballot(mrow[k] != 0);
        if (lane == 0) bitsT[((size_t)b * KWORDS_ + (k >> 6)) * T_ + t] = bal;
    }
}

// -------------------------------- weight prep: bf16, fragment-tiled layouts
__global__ __launch_bounds__(256) void wprep_kernel(
    const float* __restrict__ W_ts1, const float* __restrict__ W_a1,
    const float* __restrict__ W_e1, const float* __restrict__ W_ts2,
    const float* __restrict__ W_a2, const float* __restrict__ W_e2,
    const float* __restrict__ Wk, const float* __restrict__ Wv,
    __bf16* __restrict__ ts1P, __bf16* __restrict__ a1P, __bf16* __restrict__ e1P,
    __bf16* __restrict__ ts2T, __bf16* __restrict__ a2T, __bf16* __restrict__ e2T,
    __bf16* __restrict__ WkT, __bf16* __restrict__ WvT) {
    int i = blockIdx.x * 256 + threadIdx.x;
    if (i < 6144) { int col = i >> 5, k = i & 31;
        ts1P[i] = (__bf16)(k < 6 ? W_ts1[k * TSE_ + col] : 0.f); return; }
    i -= 6144;
    if (i < 2048) { int col = i >> 5, k = i & 31;
        a1P[i] = (__bf16)((k >= 6 && k < 10) ? W_a1[(k - 6) * AUXE_ + col] : 0.f); return; }
    i -= 2048;
    if (i < 8192) { int col = i >> 5, k = i & 31;
        e1P[i] = (__bf16)((k >= 10 && k < 13) ? W_e1[(k - 10) * D_ + col] : 0.f); return; }
    i -= 8192;
    if (i < 36864) {  // ts2: COLS=192, KS=6
        int tile = i >> 9, lr = (i >> 5) & 15, kk = i & 31;
        int ct = tile / 6, ks = tile % 6;
        ts2T[i] = (__bf16)W_ts2[(ks * 32 + kk) * TSE_ + ct * 16 + lr]; return; }
    i -= 36864;
    if (i < 4096) {   // a2: COLS=64, KS=2
        int tile = i >> 9, lr = (i >> 5) & 15, kk = i & 31;
        int ct = tile / 2, ks = tile % 2;
        a2T[i] = (__bf16)W_a2[(ks * 32 + kk) * AUXE_ + ct * 16 + lr]; return; }
    i -= 4096;
    if (i < 65536) {  // e2: COLS=256, KS=8
        int tile = i >> 9, lr = (i >> 5) & 15, kk = i & 31;
        int ct = tile >> 3, ks = tile & 7;
        e2T[i] = (__bf16)W_e2[(ks * 32 + kk) * D_ + ct * 16 + lr]; return; }
    i -= 65536;
    if (i < 65536) {  // Wk
        int tile = i >> 9, lr = (i >> 5) & 15, kk = i & 31;
        int ct = tile >> 3, ks = tile & 7;
        WkT[i] = (__bf16)Wk[(ks * 32 + kk) * D_ + ct * 16 + lr]; return; }
    i -= 65536;
    {                 // Wv
        int tile = i >> 9, lr = (i >> 5) & 15, kk = i & 31;
        int ct = tile >> 3, ks = tile & 7;
        WvT[i] = (__bf16)Wv[(ks * 32 + kk) * D_ + ct * 16 + lr]; }
}

// ------------------------- MFMA kv chain: 64 rows/block, 4 waves x 16-row tiles
// V output is pre-fragmented: Vf[bh][tile64][kstep(4)][lane(64)][8 bf16]
//   value = V[key = tile*64 + kstep*16 + (lane>>5)*8 + j][d = lane&31]
__global__ __launch_bounds__(256, 2) void kv_mfma_kernel(
    const float* __restrict__ md, const float* __restrict__ na, const float* __restrict__ ea,
    const __bf16* __restrict__ ts1P, const __bf16* __restrict__ a1P,
    const __bf16* __restrict__ e1P,
    const float* __restrict__ b_ts1, const float* __restrict__ b_a1,
    const float* __restrict__ b_e1,
    const __bf16* __restrict__ ts2T, const __bf16* __restrict__ a2T,
    const __bf16* __restrict__ e2T,
    const float* __restrict__ b_ts2, const float* __restrict__ b_a2,
    const float* __restrict__ b_e2,
    const __bf16* __restrict__ WkT, const float* __restrict__ bk,
    const __bf16* __restrict__ WvT, const float* __restrict__ bv,
    const float* __restrict__ pe, __bf16* __restrict__ Kb, __bf16* __restrict__ Vf) {
    int blk = blockIdx.x;          // 4b * 16n * 8t = 512
    int t0 = (blk & 7) * 64;
    int n = (blk >> 3) & 15;
    int b = blk >> 7;
    int tid = threadIdx.x, lane = tid & 63, w = tid >> 6;
    int lr = lane & 15, lg = lane >> 4;

    __shared__ __bf16 sA[64 * 40];      // A_all: 13 channels + zero pad to K=32
    __shared__ __bf16 sU[34304];        // union: {hts,haux,hedge} then {skey,sval}
    __bf16* hts = sU;                   // [64][200]
    __bf16* haux = sU + 12800;          // [64][72]
    __bf16* hedge = sU + 17408;         // [64][264]
    __bf16* skey = sU;                  // [64][264]
    __bf16* sval = sU + 16896;          // [64][264]

    for (int i = tid; i < 64 * 40; i += 256) sA[i] = (__bf16)0.f;
    __syncthreads();
    {
        int t = tid & 63, cg = tid >> 6;
        size_t bn = (size_t)b * N_ + n;
        for (int c = cg; c < 13; c += 4) {
            float v;
            if (c < 6) v = md[(bn * CTS_ + c) * T_ + t0 + t];
            else if (c < 10) v = na[(bn * CN_ + (c - 6)) * T_ + t0 + t];
            else v = ea[(bn * CE_ + (c - 10)) * T_ + t0 + t];
            sA[t * 40 + c] = (__bf16)v;
        }
    }
    __syncthreads();

    int arow = w * 16 + lr;       // A-fragment row
    int crow = w * 16 + lg * 4;   // C-fragment row base (+reg)
    bf16x8 afrag1 = *(const bf16x8*)(sA + arow * 40 + lg * 8);
    int foff = lr * 32 + lg * 8;  // per-lane offset within a 512-elem fragment tile

    // ---- phase 2: first layers (K=32, one MFMA per col-tile), ReLU, store bf16
#pragma unroll 1
    for (int ct = 0; ct < 12; ++ct) {
        int gcol = ct * 16 + lr;
        bf16x8 bf = *(const bf16x8*)(ts1P + ct * 512 + foff);
        f32x4 z = {0.f, 0.f, 0.f, 0.f};
        f32x4 c = __builtin_amdgcn_mfma_f32_16x16x32_bf16(afrag1, bf, z, 0, 0, 0);
        float bias = b_ts1[gcol];
#pragma unroll
        for (int r = 0; r < 4; ++r) hts[(crow + r) * 200 + gcol] = (__bf16)fmaxf(c[r] + bias, 0.f);
    }
#pragma unroll 1
    for (int ct = 0; ct < 4; ++ct) {
        int gcol = ct * 16 + lr;
        bf16x8 bf = *(const bf16x8*)(a1P + ct * 512 + foff);
        f32x4 z = {0.f, 0.f, 0.f, 0.f};
        f32x4 c = __builtin_amdgcn_mfma_f32_16x16x32_bf16(afrag1, bf, z, 0, 0, 0);
        float bias = b_a1[gcol];
#pragma unroll
        for (int r = 0; r < 4; ++r) haux[(crow + r) * 72 + gcol] = (__bf16)fmaxf(c[r] + bias, 0.f);
    }
#pragma unroll 1
    for (int ct = 0; ct < 16; ++ct) {
        int gcol = ct * 16 + lr;
        bf16x8 bf = *(const bf16x8*)(e1P + ct * 512 + foff);
        f32x4 z = {0.f, 0.f, 0.f, 0.f};
        f32x4 c = __builtin_amdgcn_mfma_f32_16x16x32_bf16(afrag1, bf, z, 0, 0, 0);
        float bias = b_e1[gcol];
#pragma unroll
        for (int r = 0; r < 4; ++r) hedge[(crow + r) * 264 + gcol] = (__bf16)fmaxf(c[r] + bias, 0.f);
    }
    __syncthreads();

    // ---- phase 3: nbr (ts2|a2) and edg (e2) accumulators in registers
    f32x4 nacc[16], eacc[16];
#pragma unroll
    for (int ct = 0; ct < 16; ++ct) {
        nacc[ct] = (f32x4){0.f, 0.f, 0.f, 0.f};
        eacc[ct] = (f32x4){0.f, 0.f, 0.f, 0.f};
    }
#pragma unroll 1
    for (int ks = 0; ks < 8; ++ks) {
        bf16x8 af = *(const bf16x8*)(hedge + arow * 264 + ks * 32 + lg * 8);
#pragma unroll
        for (int ct = 0; ct < 16; ++ct) {
            bf16x8 bf = *(const bf16x8*)(e2T + (ct * 8 + ks) * 512 + foff);
            eacc[ct] = __builtin_amdgcn_mfma_f32_16x16x32_bf16(af, bf, eacc[ct], 0, 0, 0);
        }
    }
#pragma unroll 1
    for (int ks = 0; ks < 6; ++ks) {
        bf16x8 af = *(const bf16x8*)(hts + arow * 200 + ks * 32 + lg * 8);
#pragma unroll
        for (int ct = 0; ct < 12; ++ct) {
            bf16x8 bf = *(const bf16x8*)(ts2T + (ct * 6 + ks) * 512 + foff);
            nacc[ct] = __builtin_amdgcn_mfma_f32_16x16x32_bf16(af, bf, nacc[ct], 0, 0, 0);
        }
    }
#pragma unroll
    for (int ks = 0; ks < 2; ++ks) {
        bf16x8 af = *(const bf16x8*)(haux + arow * 72 + ks * 32 + lg * 8);
#pragma unroll
        for (int ct = 0; ct < 4; ++ct) {
            bf16x8 bf = *(const bf16x8*)(a2T + (ct * 2 + ks) * 512 + foff);
            nacc[12 + ct] = __builtin_amdgcn_mfma_f32_16x16x32_bf16(af, bf, nacc[12 + ct], 0, 0, 0);
        }
    }
    __syncthreads();   // hts/haux/hedge reads done; safe to overwrite union

    // ---- phase 3b: key = nbr*edg + pe, val = nbr + pe (bf16 into LDS)
#pragma unroll
    for (int ct = 0; ct < 16; ++ct) {
        int gcol = ct * 16 + lr;
        float nb_bias = (ct < 12) ? b_ts2[gcol] : b_a2[gcol - 192];
        float ed_bias = b_e2[gcol];
#pragma unroll
        for (int r = 0; r < 4; ++r) {
            int row = crow + r;
            float p = pe[(t0 + row) * D_ + gcol];
            float nb = nacc[ct][r] + nb_bias;
            float ed = eacc[ct][r] + ed_bias;
            skey[row * 264 + gcol] = (__bf16)(nb * ed + p);
            sval[row * 264 + gcol] = (__bf16)(nb + p);
        }
    }
    __syncthreads();

    // ---- phase 4: K/V projections (K=256 -> 8 ksteps per col-tile)
    size_t key0 = (size_t)n * T_ + t0;
    int tile = (int)(key0 >> 6);
#pragma unroll 1
    for (int ct = 0; ct < 16; ++ct) {
        int gcol = ct * 16 + lr;
        f32x4 ka = {0.f, 0.f, 0.f, 0.f}, va = {0.f, 0.f, 0.f, 0.f};
#pragma unroll
        for (int ks = 0; ks < 8; ++ks) {
            bf16x8 afk = *(const bf16x8*)(skey + arow * 264 + ks * 32 + lg * 8);
            bf16x8 afv = *(const bf16x8*)(sval + arow * 264 + ks * 32 + lg * 8);
            bf16x8 b8k = *(const bf16x8*)(WkT + (ct * 8 + ks) * 512 + foff);
            bf16x8 b8v = *(const bf16x8*)(WvT + (ct * 8 + ks) * 512 + foff);
            ka = __builtin_amdgcn_mfma_f32_16x16x32_bf16(afk, b8k, ka, 0, 0, 0);
            va = __builtin_amdgcn_mfma_f32_16x16x32_bf16(afv, b8v, va, 0, 0, 0);
        }
        float kbias = bk[gcol], vbias = bv[gcol];
        int h = gcol >> 5, dd = gcol & 31;
        size_t bh = (size_t)b * H_ + h;
#pragma unroll
        for (int r = 0; r < 4; ++r)
            Kb[(bh * NT_ + key0 + crow + r) * DK_ + dd] = (__bf16)(ka[r] + kbias);
        __bf16 tmp[4];
#pragma unroll
        for (int r = 0; r < 4; ++r) tmp[r] = (__bf16)(va[r] + vbias);
        // pre-fragmented V write: keys crow..crow+3 at dim dd
        int vks = crow >> 4;
        int vl5 = (crow >> 3) & 1;
        int vlane = vl5 * 32 + dd;
        size_t vaddr = ((bh * (NT_ / 64) + tile) * 4 + vks) * 512 + vlane * 8 + (crow & 7);
        *(ushort4*)(Vf + vaddr) = *(ushort4*)tmp;
    }
}

// -------------------------- xq = x + pe, LayerNorm, Q proj -> bf16 Qb (pre-scaled)
__global__ __launch_bounds__(256) void q_kernel(
    const float* __restrict__ x, const float* __restrict__ pe,
    const float* __restrict__ Wq, const float* __restrict__ bq,
    const float* __restrict__ ln_g, const float* __restrict__ ln_b,
    float* __restrict__ xq, __bf16* __restrict__ Qb) {
    int blk = blockIdx.x;
    int t0 = (blk & 31) * 16;
    int b = blk >> 5;
    int tid = threadIdx.x;

    __shared__ float s_xn[16][D_];
    __shared__ float s_red[8];

    for (int r = 0; r < 16; ++r) {
        int t = t0 + r;
        size_t off = ((size_t)b * T_ + t) * D_ + tid;
        float v = x[off] + pe[t * D_ + tid];
        xq[off] = v;
        float s1 = v, s2 = v * v;
#pragma unroll
        for (int o = 32; o; o >>= 1) {
            s1 += __shfl_down(s1, o, 64);
            s2 += __shfl_down(s2, o, 64);
        }
        if ((tid & 63) == 0) {
            s_red[tid >> 6] = s1;
            s_red[4 + (tid >> 6)] = s2;
        }
        __syncthreads();
        float t1 = s_red[0] + s_red[1] + s_red[2] + s_red[3];
        float t2 = s_red[4] + s_red[5] + s_red[6] + s_red[7];
        float mu = t1 * (1.f / D_);
        float var = t2 * (1.f / D_) - mu * mu;
        float rs = rsqrtf(var + 1e-6f);
        s_xn[r][tid] = (v - mu) * rs * ln_g[tid] + ln_b[tid];
        __syncthreads();
    }

    float acc[16];
#pragma unroll
    for (int r = 0; r < 16; ++r) acc[r] = bq[tid];
    for (int e = 0; e < D_; ++e) {
        float w = Wq[e * D_ + tid];
#pragma unroll
        for (int r = 0; r < 16; ++r) acc[r] += s_xn[r][e] * w;
    }
    for (int r = 0; r < 16; ++r) {
        Qb[((size_t)b * T_ + t0 + r) * D_ + tid] = (__bf16)(acc[r] * QSCALE_);
    }
}

// ------- 32x32 MFMA attention: swapped QK^T, permlane32_swap P-transpose, no LDS
// grid: B*H*(T/128)*SPLIT = 1024 blocks, 256 threads (4 waves x 32 queries each)
__global__ __launch_bounds__(256, 4) void attn_mfma_kernel(
    const __bf16* __restrict__ Qb, const __bf16* __restrict__ Kb,
    const __bf16* __restrict__ Vf, const ull* __restrict__ bitsT,
    float* __restrict__ Opart, float* __restrict__ Lpart) {
    int blk = blockIdx.x;
    int kh = blk & (SPLIT_ - 1);
    int qt = (blk >> 3) & 3;
    int h = (blk >> 5) & 7;
    int b = blk >> 8;
    int tid = threadIdx.x, lane = tid & 63, w = tid >> 6;
    int lq = lane & 31, l5 = lane >> 5;

    const size_t bh = (size_t)b * H_ + h;
    const int TILES = KWORDS_ / SPLIT_;   // 16

    int qglob = qt * 128 + w * 32 + lq;
    // Q B-fragments: B[dk = l5*8+j (+16 step)][q = lq]
    const __bf16* qbase = Qb + ((size_t)b * T_ + qglob) * D_ + h * DK_ + l5 * 8;
    bf16x8 qf0 = *(const bf16x8*)(qbase);
    bf16x8 qf1 = *(const bf16x8*)(qbase + 16);

    const __bf16* kp = Kb + bh * NT_ * DK_ + (size_t)(kh * TILES) * 64 * DK_;
    const __bf16* vp = Vf + (bh * (NT_ / 64) + (size_t)(kh * TILES)) * 2048;
    const ull* mp = bitsT + (size_t)b * KWORDS_ * T_ + (size_t)(kh * TILES) * T_ + qglob;

    // K A-frag offsets: subtile s keys s*32 + lq, d-step st: st*16 + l5*8
    int k00 = lq * DK_ + l5 * 8;
    int k01 = k00 + 16;
    int k10 = (32 + lq) * DK_ + l5 * 8;
    int k11 = k10 + 16;
    int shamt = 4 * l5;

    f32x16 acc;
    f32x16 zv;
#pragma unroll
    for (int i = 0; i < 16; ++i) { acc[i] = 0.f; zv[i] = 0.f; }
    float l_lane = 0.f;

    // preload tile 0 K + mask
    bf16x8 kc0 = *(const bf16x8*)(kp + k00);
    bf16x8 kc1 = *(const bf16x8*)(kp + k01);
    bf16x8 kc2 = *(const bf16x8*)(kp + k10);
    bf16x8 kc3 = *(const bf16x8*)(kp + k11);
    ull mw = *mp;

#pragma unroll 1
    for (int kt = 0; kt < TILES; ++kt) {
        // issue current-tile V (4 x 1KB contiguous) — consumed after softmax
        bf16x8 vc0 = *(const bf16x8*)(vp + 0 * 512 + lane * 8);
        bf16x8 vc1 = *(const bf16x8*)(vp + 1 * 512 + lane * 8);
        bf16x8 vc2 = *(const bf16x8*)(vp + 2 * 512 + lane * 8);
        bf16x8 vc3 = *(const bf16x8*)(vp + 3 * 512 + lane * 8);
        // issue next-tile K + mask
        bf16x8 kn0, kn1, kn2, kn3;
        ull mn = 0;
        if (kt + 1 < TILES) {
            kn0 = *(const bf16x8*)(kp + 2048 + k00);
            kn1 = *(const bf16x8*)(kp + 2048 + k01);
            kn2 = *(const bf16x8*)(kp + 2048 + k10);
            kn3 = *(const bf16x8*)(kp + 2048 + k11);
            mn = mp[T_];
        }
        __builtin_amdgcn_sched_barrier(0);

        ull sh = mw >> shamt;

#pragma unroll
        for (int s = 0; s < 2; ++s) {
            // ---- S^T = K . Q^T over DK=32 (2 accumulating MFMAs)
            f32x16 sc = __builtin_amdgcn_mfma_f32_32x32x16_bf16(
                s ? kc2 : kc0, qf0, zv, 0, 0, 0);
            sc = __builtin_amdgcn_mfma_f32_32x32x16_bf16(
                s ? kc3 : kc1, qf1, sc, 0, 0, 0);

            // ---- masked fixed-shift softmax: key=(r&3)+8*(r>>2)(+4l5 folded in sh)
            uint ms = (uint)(sh >> (32 * s));
            float p[16];
#pragma unroll
            for (int r = 0; r < 16; ++r) {
                int pos = (r & 3) + 8 * (r >> 2);
                float t = sc[r] - C2_;
                t = (ms & (1u << pos)) ? t : -1e30f;
                p[r] = exp2f(t);
                l_lane += p[r];
            }

            // ---- P -> A-fragments via cvt_pk + permlane32_swap, PV MFMA per kstep
#pragma unroll
            for (int h2 = 0; h2 < 2; ++h2) {
                uint w0, w1, w2, w3;
                asm("v_cvt_pk_bf16_f32 %0, %1, %2" : "=v"(w0) : "v"(p[8 * h2 + 0]), "v"(p[8 * h2 + 1]));
                asm("v_cvt_pk_bf16_f32 %0, %1, %2" : "=v"(w1) : "v"(p[8 * h2 + 2]), "v"(p[8 * h2 + 3]));
                asm("v_cvt_pk_bf16_f32 %0, %1, %2" : "=v"(w2) : "v"(p[8 * h2 + 4]), "v"(p[8 * h2 + 5]));
                asm("v_cvt_pk_bf16_f32 %0, %1, %2" : "=v"(w3) : "v"(p[8 * h2 + 6]), "v"(p[8 * h2 + 7]));
                asm volatile("v_permlane32_swap_b32 %0, %1" : "+v"(w0), "+v"(w2));
                asm volatile("v_permlane32_swap_b32 %0, %1" : "+v"(w1), "+v"(w3));
                union { uint u[4]; bf16x8 v; } pa;
                pa.u[0] = w0; pa.u[1] = w1; pa.u[2] = w2; pa.u[3] = w3;
                bf16x8 vfr = (s == 0) ? (h2 == 0 ? vc0 : vc1) : (h2 == 0 ? vc2 : vc3);
                acc = __builtin_amdgcn_mfma_f32_32x32x16_bf16(pa.v, vfr, acc, 0, 0, 0);
            }
        }

        kp += 2048;
        vp += 2048;
        mp += T_;
        if (kt + 1 < TILES) {
            kc0 = kn0; kc1 = kn1; kc2 = kn2; kc3 = kn3;
            mw = mn;
        }
    }

    // ---- l: reduce across the two key-owning halves
    l_lane += __shfl_xor(l_lane, 32, 64);

    // ---- write partials: acc[r] = O[q = (r&3)+8*(r>>2)+4*l5][d = lq]
    size_t obase = (((size_t)kh * B_ + b) * H_ + h) * T_ + qt * 128 + w * 32;
#pragma unroll
    for (int r = 0; r < 16; ++r) {
        int q = (r & 3) + 8 * (r >> 2) + 4 * l5;
        Opart[(obase + q) * DK_ + lq] = acc[r];
    }
    if (l5 == 0) Lpart[obase + lq] = l_lane;
}

// ------------------------------------ merge split-K partials (plain sums) -> ctx
__global__ __launch_bounds__(256) void merge_kernel(
    const float* __restrict__ Opart, const float* __restrict__ Lpart,
    float* __restrict__ ctx) {
    int idx = blockIdx.x * 256 + threadIdx.x;  // B*H*T*32 total
    int d = idx & 31;
    int t = (idx >> 5) & (T_ - 1);
    int bh = idx >> 14;
    int h = bh & 7, b = bh >> 3;
    size_t ps = (size_t)B_ * H_ * T_;
    size_t base = (size_t)bh * T_ + t;
    float L = 0.f, o = 0.f;
#pragma unroll
    for (int s = 0; s < SPLIT_; ++s) {
        L += Lpart[s * ps + base];
        o += Opart[(s * ps + base) * DK_ + d];
    }
    ctx[((size_t)b * T_ + t) * D_ + h * DK_ + d] = o / L;
}

// ------------------------------------------------ out = xq + ctx@Wo + bo
__global__ __launch_bounds__(256) void out_kernel(
    const float* __restrict__ ctx, const float* __restrict__ xq,
    const float* __restrict__ Wo, const float* __restrict__ bo, float* __restrict__ out) {
    int blk = blockIdx.x;
    int t0 = (blk & 31) * 16;
    int b = blk >> 5;
    int tid = threadIdx.x;
    __shared__ float s_c[16][D_];
    for (int r = 0; r < 16; ++r)
        s_c[r][tid] = ctx[((size_t)b * T_ + t0 + r) * D_ + tid];
    __syncthreads();
    float acc[16];
#pragma unroll
    for (int r = 0; r < 16; ++r) acc[r] = bo[tid];
    for (int e = 0; e < D_; ++e) {
        float w = Wo[e * D_ + tid];
#pragma unroll
        for (int r = 0; r < 16; ++r) acc[r] += s_c[r][e] * w;
    }
    for (int r = 0; r < 16; ++r) {
        size_t off = ((size_t)b * T_ + t0 + r) * D_ + tid;
        out[off] = xq[off] + acc[r];
    }
}

// ---------------------------------------------------------------- launcher
extern "C" void kernel_launch(void* const* d_in, const int* in_sizes, int n_in,
                              void* d_out, int out_size, void* d_ws, size_t ws_size,
                              hipStream_t stream) {
    const float* x = (const float*)d_in[0];
    const float* md = (const float*)d_in[1];
    const float* na = (const float*)d_in[2];
    const float* ea = (const float*)d_in[3];
    const int* mask = (const int*)d_in[4];
    const float* W_ts1 = (const float*)d_in[5];
    const float* b_ts1 = (const float*)d_in[6];
    const float* W_ts2 = (const float*)d_in[7];
    const float* b_ts2 = (const float*)d_in[8];
    const float* W_a1 = (const float*)d_in[9];
    const float* b_a1 = (const float*)d_in[10];
    const float* W_a2 = (const float*)d_in[11];
    const float* b_a2 = (const float*)d_in[12];
    const float* W_e1 = (const float*)d_in[13];
    const float* b_e1 = (const float*)d_in[14];
    const float* W_e2 = (const float*)d_in[15];
    const float* b_e2 = (const float*)d_in[16];
    const float* Wq = (const float*)d_in[17];
    const float* bq = (const float*)d_in[18];
    const float* Wk = (const float*)d_in[19];
    const float* bk = (const float*)d_in[20];
    const float* Wv = (const float*)d_in[21];
    const float* bv = (const float*)d_in[22];
    const float* Wo = (const float*)d_in[23];
    const float* bo = (const float*)d_in[24];
    const float* ln_g = (const float*)d_in[25];
    const float* ln_b = (const float*)d_in[26];
    float* out = (float*)d_out;

    char* ws = (char*)d_ws;
    float* pe = (float*)ws;    ws += (size_t)T_ * D_ * 4;
    ull* bitsT = (ull*)ws;     ws += (size_t)B_ * KWORDS_ * T_ * 8;
    __bf16* Kb = (__bf16*)ws;  ws += (size_t)B_ * H_ * NT_ * DK_ * 2;
    __bf16* Vf = (__bf16*)ws;  ws += (size_t)B_ * H_ * NT_ * DK_ * 2;
    float* xq = (float*)ws;    ws += (size_t)B_ * T_ * D_ * 4;
    __bf16* Qb = (__bf16*)ws;  ws += (size_t)B_ * T_ * D_ * 2;
    float* ctx = (float*)ws;   ws += (size_t)B_ * T_ * D_ * 4;
    float* Opart = (float*)ws; ws += (size_t)SPLIT_ * B_ * H_ * T_ * DK_ * 4;
    float* Lpart = (float*)ws; ws += (size_t)SPLIT_ * B_ * H_ * T_ * 4;
    // bf16 prepped weights
    __bf16* ts1P = (__bf16*)ws; ws += 6144 * 2;
    __bf16* a1P = (__bf16*)ws;  ws += 2048 * 2;
    __bf16* e1P = (__bf16*)ws;  ws += 8192 * 2;
    __bf16* ts2T = (__bf16*)ws; ws += 36864 * 2;
    __bf16* a2T = (__bf16*)ws;  ws += 4096 * 2;
    __bf16* e2T = (__bf16*)ws;  ws += 65536 * 2;
    __bf16* WkT = (__bf16*)ws;  ws += 65536 * 2;
    __bf16* WvT = (__bf16*)ws;  ws += 65536 * 2;

    pe_kernel<<<T_, 256, 0, stream>>>(pe);
    maskbits_kernel<<<B_ * T_, 256, 0, stream>>>(mask, bitsT);
    wprep_kernel<<<992, 256, 0, stream>>>(W_ts1, W_a1, W_e1, W_ts2, W_a2, W_e2, Wk, Wv,
                                          ts1P, a1P, e1P, ts2T, a2T, e2T, WkT, WvT);
    kv_mfma_kernel<<<B_ * N_ * (T_ / 64), 256, 0, stream>>>(
        md, na, ea, ts1P, a1P, e1P, b_ts1, b_a1, b_e1,
        ts2T, a2T, e2T, b_ts2, b_a2, b_e2, WkT, bk, WvT, bv, pe, Kb, Vf);
    q_kernel<<<B_ * (T_ / 16), 256, 0, stream>>>(x, pe, Wq, bq, ln_g, ln_b, xq, Qb);
    attn_mfma_kernel<<<B_ * H_ * (T_ / 128) * SPLIT_, 256, 0, stream>>>(
        Qb, Kb, Vf, bitsT, Opart, Lpart);
    merge_kernel<<<(B_ * H_ * T_ * DK_) / 256, 256, 0, stream>>>(Opart, Lpart, ctx);
    out_kernel<<<B_ * (T_ / 16), 256, 0, stream>>>(ctx, xq, Wo, bo, out);
}

// Round 9
// 207.706 us; speedup vs baseline: 1.3108x; 1.1156x over previous
//
#include <hip/hip_runtime.h>
#include <hip/hip_bf16.h>

#define B_ 4
#define T_ 512
#define N_ 16
#define D_ 256
#define H_ 8
#define DK_ 32
#define NT_ (N_ * T_)
#define CTS_ 6
#define CN_ 4
#define CE_ 3
#define TSE_ 192
#define AUXE_ 64
#define SPLIT_ 8
#define KWORDS_ (NT_ / 64)   // 128 mask words per row

// Q pre-scale: (1/sqrt(32)) * log2(e)  -> MFMA output is already in exp2 domain
#define QSCALE_ 0.2550689747f
// fixed softmax shift (exp2 domain): 8 * log2(e)
#define C2_ 11.5415603f

typedef unsigned long long ull;
typedef unsigned int uint;
typedef __bf16 bf16x8 __attribute__((ext_vector_type(8)));
typedef float f32x4 __attribute__((ext_vector_type(4)));
typedef float f32x16 __attribute__((ext_vector_type(16)));

// ---------------------------------------------------------------- PE table
__global__ __launch_bounds__(256) void pe_kernel(float* pe) {
    int t = blockIdx.x;
    int d = threadIdx.x;
    int j = d >> 1;
    float div = expf((float)(2 * j) * (-9.210340371976184f / 256.0f)); // -ln(10000)/D
    float a = (float)t * div;
    pe[t * D_ + d] = (d & 1) ? cosf(a) : sinf(a);
}

// ------------------------------------- mask -> transposed bitmask [B][128][T]
__global__ __launch_bounds__(256) void maskbits_kernel(const int* __restrict__ mask,
                                                       ull* __restrict__ bitsT) {
    int row = blockIdx.x;  // b*T + t
    int b = row >> 9, t = row & (T_ - 1);
    const int* mrow = mask + (size_t)row * NT_;
    int lane = threadIdx.x & 63, wave = threadIdx.x >> 6;
    for (int it = 0; it < NT_ / 256; ++it) {
        int k = it * 256 + wave * 64 + lane;
        ull bal = __ballot(mrow[k] != 0);
        if (lane == 0) bitsT[((size_t)b * KWORDS_ + (k >> 6)) * T_ + t] = bal;
    }
}

// -------------------------------- weight prep: bf16, fragment-tiled layouts
__global__ __launch_bounds__(256) void wprep_kernel(
    const float* __restrict__ W_ts1, const float* __restrict__ W_a1,
    const float* __restrict__ W_e1, const float* __restrict__ W_ts2,
    const float* __restrict__ W_a2, const float* __restrict__ W_e2,
    const float* __restrict__ Wk, const float* __restrict__ Wv,
    __bf16* __restrict__ ts1P, __bf16* __restrict__ a1P, __bf16* __restrict__ e1P,
    __bf16* __restrict__ ts2T, __bf16* __restrict__ a2T, __bf16* __restrict__ e2T,
    __bf16* __restrict__ WkT, __bf16* __restrict__ WvT) {
    int i = blockIdx.x * 256 + threadIdx.x;
    if (i < 6144) { int col = i >> 5, k = i & 31;
        ts1P[i] = (__bf16)(k < 6 ? W_ts1[k * TSE_ + col] : 0.f); return; }
    i -= 6144;
    if (i < 2048) { int col = i >> 5, k = i & 31;
        a1P[i] = (__bf16)((k >= 6 && k < 10) ? W_a1[(k - 6) * AUXE_ + col] : 0.f); return; }
    i -= 2048;
    if (i < 8192) { int col = i >> 5, k = i & 31;
        e1P[i] = (__bf16)((k >= 10 && k < 13) ? W_e1[(k - 10) * D_ + col] : 0.f); return; }
    i -= 8192;
    if (i < 36864) {  // ts2: COLS=192, KS=6
        int tile = i >> 9, lr = (i >> 5) & 15, kk = i & 31;
        int ct = tile / 6, ks = tile % 6;
        ts2T[i] = (__bf16)W_ts2[(ks * 32 + kk) * TSE_ + ct * 16 + lr]; return; }
    i -= 36864;
    if (i < 4096) {   // a2: COLS=64, KS=2
        int tile = i >> 9, lr = (i >> 5) & 15, kk = i & 31;
        int ct = tile / 2, ks = tile % 2;
        a2T[i] = (__bf16)W_a2[(ks * 32 + kk) * AUXE_ + ct * 16 + lr]; return; }
    i -= 4096;
    if (i < 65536) {  // e2: COLS=256, KS=8
        int tile = i >> 9, lr = (i >> 5) & 15, kk = i & 31;
        int ct = tile >> 3, ks = tile & 7;
        e2T[i] = (__bf16)W_e2[(ks * 32 + kk) * D_ + ct * 16 + lr]; return; }
    i -= 65536;
    if (i < 65536) {  // Wk
        int tile = i >> 9, lr = (i >> 5) & 15, kk = i & 31;
        int ct = tile >> 3, ks = tile & 7;
        WkT[i] = (__bf16)Wk[(ks * 32 + kk) * D_ + ct * 16 + lr]; return; }
    i -= 65536;
    {                 // Wv
        int tile = i >> 9, lr = (i >> 5) & 15, kk = i & 31;
        int ct = tile >> 3, ks = tile & 7;
        WvT[i] = (__bf16)Wv[(ks * 32 + kk) * D_ + ct * 16 + lr]; }
}

// --------- MFMA kv chain: 32 rows/block, 4 waves = 2 row-halves x 2 col-halves
// V output pre-fragmented: Vf[bh][tile64][kstep(4)][lane(64)][8 bf16]
//   value = V[key = tile*64 + kstep*16 + (lane>>5)*8 + j][d = lane&31]
__global__ __launch_bounds__(256, 4) void kv_mfma_kernel(
    const float* __restrict__ md, const float* __restrict__ na, const float* __restrict__ ea,
    const __bf16* __restrict__ ts1P, const __bf16* __restrict__ a1P,
    const __bf16* __restrict__ e1P,
    const float* __restrict__ b_ts1, const float* __restrict__ b_a1,
    const float* __restrict__ b_e1,
    const __bf16* __restrict__ ts2T, const __bf16* __restrict__ a2T,
    const __bf16* __restrict__ e2T,
    const float* __restrict__ b_ts2, const float* __restrict__ b_a2,
    const float* __restrict__ b_e2,
    const __bf16* __restrict__ WkT, const float* __restrict__ bk,
    const __bf16* __restrict__ WvT, const float* __restrict__ bv,
    const float* __restrict__ pe, __bf16* __restrict__ Kb, __bf16* __restrict__ Vf) {
    int blk = blockIdx.x;          // 4b * 16n * 16t = 1024
    int t0 = (blk & 15) * 32;
    int n = (blk >> 4) & 15;
    int b = blk >> 8;
    int tid = threadIdx.x, lane = tid & 63, w = tid >> 6;
    int wr = w & 1, wc = w >> 1;
    int lr = lane & 15, lg = lane >> 4;

    __shared__ __bf16 sA[32 * 40];      // 13 channels + zero pad to K=32 (2.5 KB)
    __shared__ __bf16 sU[17152];        // union: {hts,haux,hedge} then {skey,sval} (34.3 KB)
    __bf16* hts = sU;                   // [32][200]
    __bf16* haux = sU + 6400;           // [32][72]
    __bf16* hedge = sU + 8704;          // [32][264]
    __bf16* skey = sU;                  // [32][264]
    __bf16* sval = sU + 8448;           // [32][264]

    for (int i = tid; i < 32 * 40; i += 256) sA[i] = (__bf16)0.f;
    __syncthreads();
    {
        int t = tid & 31, c0 = tid >> 5;
        size_t bn = (size_t)b * N_ + n;
        for (int c = c0; c < 13; c += 8) {
            float v;
            if (c < 6) v = md[(bn * CTS_ + c) * T_ + t0 + t];
            else if (c < 10) v = na[(bn * CN_ + (c - 6)) * T_ + t0 + t];
            else v = ea[(bn * CE_ + (c - 10)) * T_ + t0 + t];
            sA[t * 40 + c] = (__bf16)v;
        }
    }
    __syncthreads();

    int arow = wr * 16 + lr;       // A-fragment row (0..31)
    int crow = wr * 16 + lg * 4;   // C-fragment row base (+reg)
    bf16x8 afrag1 = *(const bf16x8*)(sA + arow * 40 + lg * 8);
    int foff = lr * 32 + lg * 8;   // per-lane offset within a 512-elem fragment tile

    // ---- phase 2: first layers (K=32), col-split across wc, ReLU -> LDS bf16
#pragma unroll 1
    for (int i = 0; i < 6; ++i) {
        int ct = wc * 6 + i;
        int gcol = ct * 16 + lr;
        bf16x8 bf = *(const bf16x8*)(ts1P + ct * 512 + foff);
        f32x4 z = {0.f, 0.f, 0.f, 0.f};
        f32x4 c = __builtin_amdgcn_mfma_f32_16x16x32_bf16(afrag1, bf, z, 0, 0, 0);
        float bias = b_ts1[gcol];
#pragma unroll
        for (int r = 0; r < 4; ++r) hts[(crow + r) * 200 + gcol] = (__bf16)fmaxf(c[r] + bias, 0.f);
    }
#pragma unroll
    for (int i = 0; i < 2; ++i) {
        int ct = wc * 2 + i;
        int gcol = ct * 16 + lr;
        bf16x8 bf = *(const bf16x8*)(a1P + ct * 512 + foff);
        f32x4 z = {0.f, 0.f, 0.f, 0.f};
        f32x4 c = __builtin_amdgcn_mfma_f32_16x16x32_bf16(afrag1, bf, z, 0, 0, 0);
        float bias = b_a1[gcol];
#pragma unroll
        for (int r = 0; r < 4; ++r) haux[(crow + r) * 72 + gcol] = (__bf16)fmaxf(c[r] + bias, 0.f);
    }
#pragma unroll 1
    for (int i = 0; i < 8; ++i) {
        int ct = wc * 8 + i;
        int gcol = ct * 16 + lr;
        bf16x8 bf = *(const bf16x8*)(e1P + ct * 512 + foff);
        f32x4 z = {0.f, 0.f, 0.f, 0.f};
        f32x4 c = __builtin_amdgcn_mfma_f32_16x16x32_bf16(afrag1, bf, z, 0, 0, 0);
        float bias = b_e1[gcol];
#pragma unroll
        for (int r = 0; r < 4; ++r) hedge[(crow + r) * 264 + gcol] = (__bf16)fmaxf(c[r] + bias, 0.f);
    }
    __syncthreads();

    // ---- phase 3: nacc/eacc for this wave's 8 output col-tiles (gcol = wc*128 + i*16)
    f32x4 nacc[8], eacc[8];
#pragma unroll
    for (int i = 0; i < 8; ++i) {
        nacc[i] = (f32x4){0.f, 0.f, 0.f, 0.f};
        eacc[i] = (f32x4){0.f, 0.f, 0.f, 0.f};
    }
#pragma unroll 1
    for (int ks = 0; ks < 8; ++ks) {
        bf16x8 af = *(const bf16x8*)(hedge + arow * 264 + ks * 32 + lg * 8);
#pragma unroll
        for (int i = 0; i < 8; ++i) {
            bf16x8 bf = *(const bf16x8*)(e2T + ((wc * 8 + i) * 8 + ks) * 512 + foff);
            eacc[i] = __builtin_amdgcn_mfma_f32_16x16x32_bf16(af, bf, eacc[i], 0, 0, 0);
        }
    }
    if (wc == 0) {
        // ts2 cts 0..7 (gcols 0..127)
#pragma unroll 1
        for (int ks = 0; ks < 6; ++ks) {
            bf16x8 af = *(const bf16x8*)(hts + arow * 200 + ks * 32 + lg * 8);
#pragma unroll
            for (int i = 0; i < 8; ++i) {
                bf16x8 bf = *(const bf16x8*)(ts2T + (i * 6 + ks) * 512 + foff);
                nacc[i] = __builtin_amdgcn_mfma_f32_16x16x32_bf16(af, bf, nacc[i], 0, 0, 0);
            }
        }
    } else {
        // ts2 cts 8..11 (gcols 128..191) + a2 cts 0..3 (gcols 192..255)
#pragma unroll 1
        for (int ks = 0; ks < 6; ++ks) {
            bf16x8 af = *(const bf16x8*)(hts + arow * 200 + ks * 32 + lg * 8);
#pragma unroll
            for (int i = 0; i < 4; ++i) {
                bf16x8 bf = *(const bf16x8*)(ts2T + ((8 + i) * 6 + ks) * 512 + foff);
                nacc[i] = __builtin_amdgcn_mfma_f32_16x16x32_bf16(af, bf, nacc[i], 0, 0, 0);
            }
        }
#pragma unroll
        for (int ks = 0; ks < 2; ++ks) {
            bf16x8 af = *(const bf16x8*)(haux + arow * 72 + ks * 32 + lg * 8);
#pragma unroll
            for (int i = 0; i < 4; ++i) {
                bf16x8 bf = *(const bf16x8*)(a2T + (i * 2 + ks) * 512 + foff);
                nacc[4 + i] = __builtin_amdgcn_mfma_f32_16x16x32_bf16(af, bf, nacc[4 + i], 0, 0, 0);
            }
        }
    }
    __syncthreads();   // hidden reads done; safe to overwrite union

    // ---- phase 3b: key = nbr*edg + pe, val = nbr + pe (bf16 into LDS)
#pragma unroll
    for (int i = 0; i < 8; ++i) {
        int gcol = wc * 128 + i * 16 + lr;
        float nb_bias = (gcol < 192) ? b_ts2[gcol] : b_a2[gcol - 192];
        float ed_bias = b_e2[gcol];
#pragma unroll
        for (int r = 0; r < 4; ++r) {
            int row = crow + r;
            float p = pe[(t0 + row) * D_ + gcol];
            float nb = nacc[i][r] + nb_bias;
            float ed = eacc[i][r] + ed_bias;
            skey[row * 264 + gcol] = (__bf16)(nb * ed + p);
            sval[row * 264 + gcol] = (__bf16)(nb + p);
        }
    }
    __syncthreads();

    // ---- phase 4: K/V projections (K=256), this wave's 8 col-tiles
    size_t key0 = (size_t)n * T_ + t0;
#pragma unroll 1
    for (int i = 0; i < 8; ++i) {
        int ct = wc * 8 + i;
        int gcol = ct * 16 + lr;
        f32x4 ka = {0.f, 0.f, 0.f, 0.f}, va = {0.f, 0.f, 0.f, 0.f};
#pragma unroll
        for (int ks = 0; ks < 8; ++ks) {
            bf16x8 afk = *(const bf16x8*)(skey + arow * 264 + ks * 32 + lg * 8);
            bf16x8 afv = *(const bf16x8*)(sval + arow * 264 + ks * 32 + lg * 8);
            bf16x8 b8k = *(const bf16x8*)(WkT + (ct * 8 + ks) * 512 + foff);
            bf16x8 b8v = *(const bf16x8*)(WvT + (ct * 8 + ks) * 512 + foff);
            ka = __builtin_amdgcn_mfma_f32_16x16x32_bf16(afk, b8k, ka, 0, 0, 0);
            va = __builtin_amdgcn_mfma_f32_16x16x32_bf16(afv, b8v, va, 0, 0, 0);
        }
        float kbias = bk[gcol], vbias = bv[gcol];
        int h = gcol >> 5, dd = gcol & 31;
        size_t bh = (size_t)b * H_ + h;
#pragma unroll
        for (int r = 0; r < 4; ++r)
            Kb[(bh * NT_ + key0 + crow + r) * DK_ + dd] = (__bf16)(ka[r] + kbias);
        __bf16 tmp[4];
#pragma unroll
        for (int r = 0; r < 4; ++r) tmp[r] = (__bf16)(va[r] + vbias);
        // pre-fragmented V write: 4 consecutive keys (8-aligned group since crow&3==0)
        size_t kg = key0 + crow;
        int within = (int)(kg & 63);
        int vks = within >> 4, vl5 = (within >> 3) & 1, j0 = within & 7;
        size_t tile = kg >> 6;
        size_t vaddr = ((bh * (NT_ / 64) + tile) * 4 + vks) * 512 + (size_t)(vl5 * 32 + dd) * 8 + j0;
        *(ushort4*)(Vf + vaddr) = *(ushort4*)tmp;
    }
}

// -------------------------- xq = x + pe, LayerNorm, Q proj -> bf16 Qb (pre-scaled)
__global__ __launch_bounds__(256) void q_kernel(
    const float* __restrict__ x, const float* __restrict__ pe,
    const float* __restrict__ Wq, const float* __restrict__ bq,
    const float* __restrict__ ln_g, const float* __restrict__ ln_b,
    float* __restrict__ xq, __bf16* __restrict__ Qb) {
    int blk = blockIdx.x;
    int t0 = (blk & 31) * 16;
    int b = blk >> 5;
    int tid = threadIdx.x;

    __shared__ float s_xn[16][D_];
    __shared__ float s_red[8];

    for (int r = 0; r < 16; ++r) {
        int t = t0 + r;
        size_t off = ((size_t)b * T_ + t) * D_ + tid;
        float v = x[off] + pe[t * D_ + tid];
        xq[off] = v;
        float s1 = v, s2 = v * v;
#pragma unroll
        for (int o = 32; o; o >>= 1) {
            s1 += __shfl_down(s1, o, 64);
            s2 += __shfl_down(s2, o, 64);
        }
        if ((tid & 63) == 0) {
            s_red[tid >> 6] = s1;
            s_red[4 + (tid >> 6)] = s2;
        }
        __syncthreads();
        float t1 = s_red[0] + s_red[1] + s_red[2] + s_red[3];
        float t2 = s_red[4] + s_red[5] + s_red[6] + s_red[7];
        float mu = t1 * (1.f / D_);
        float var = t2 * (1.f / D_) - mu * mu;
        float rs = rsqrtf(var + 1e-6f);
        s_xn[r][tid] = (v - mu) * rs * ln_g[tid] + ln_b[tid];
        __syncthreads();
    }

    float acc[16];
#pragma unroll
    for (int r = 0; r < 16; ++r) acc[r] = bq[tid];
    for (int e = 0; e < D_; ++e) {
        float w = Wq[e * D_ + tid];
#pragma unroll
        for (int r = 0; r < 16; ++r) acc[r] += s_xn[r][e] * w;
    }
    for (int r = 0; r < 16; ++r) {
        Qb[((size_t)b * T_ + t0 + r) * D_ + tid] = (__bf16)(acc[r] * QSCALE_);
    }
}

// ------- 32x32 MFMA attention: swapped QK^T, permlane32_swap P-transpose, no LDS
// grid: B*H*(T/128)*SPLIT = 1024 blocks, 256 threads (4 waves x 32 queries each)
__global__ __launch_bounds__(256, 4) void attn_mfma_kernel(
    const __bf16* __restrict__ Qb, const __bf16* __restrict__ Kb,
    const __bf16* __restrict__ Vf, const ull* __restrict__ bitsT,
    float* __restrict__ Opart, float* __restrict__ Lpart) {
    int blk = blockIdx.x;
    int kh = blk & (SPLIT_ - 1);
    int qt = (blk >> 3) & 3;
    int h = (blk >> 5) & 7;
    int b = blk >> 8;
    int tid = threadIdx.x, lane = tid & 63, w = tid >> 6;
    int lq = lane & 31, l5 = lane >> 5;

    const size_t bh = (size_t)b * H_ + h;
    const int TILES = KWORDS_ / SPLIT_;   // 16

    int qglob = qt * 128 + w * 32 + lq;
    // Q B-fragments: B[dk = l5*8+j (+16 step)][q = lq]
    const __bf16* qbase = Qb + ((size_t)b * T_ + qglob) * D_ + h * DK_ + l5 * 8;
    bf16x8 qf0 = *(const bf16x8*)(qbase);
    bf16x8 qf1 = *(const bf16x8*)(qbase + 16);

    const __bf16* kp = Kb + bh * NT_ * DK_ + (size_t)(kh * TILES) * 64 * DK_;
    const __bf16* vp = Vf + (bh * (NT_ / 64) + (size_t)(kh * TILES)) * 2048;
    const ull* mp = bitsT + (size_t)b * KWORDS_ * T_ + (size_t)(kh * TILES) * T_ + qglob;

    // K A-frag offsets: subtile s keys s*32 + lq, d-step st: st*16 + l5*8
    int k00 = lq * DK_ + l5 * 8;
    int k01 = k00 + 16;
    int k10 = (32 + lq) * DK_ + l5 * 8;
    int k11 = k10 + 16;
    int shamt = 4 * l5;

    f32x16 acc;
    f32x16 zv;
#pragma unroll
    for (int i = 0; i < 16; ++i) { acc[i] = 0.f; zv[i] = 0.f; }
    float l_lane = 0.f;

    // preload tile 0 K + mask
    bf16x8 kc0 = *(const bf16x8*)(kp + k00);
    bf16x8 kc1 = *(const bf16x8*)(kp + k01);
    bf16x8 kc2 = *(const bf16x8*)(kp + k10);
    bf16x8 kc3 = *(const bf16x8*)(kp + k11);
    ull mw = *mp;

#pragma unroll 1
    for (int kt = 0; kt < TILES; ++kt) {
        // issue current-tile V (4 x 1KB contiguous) — consumed after softmax
        bf16x8 vc0 = *(const bf16x8*)(vp + 0 * 512 + lane * 8);
        bf16x8 vc1 = *(const bf16x8*)(vp + 1 * 512 + lane * 8);
        bf16x8 vc2 = *(const bf16x8*)(vp + 2 * 512 + lane * 8);
        bf16x8 vc3 = *(const bf16x8*)(vp + 3 * 512 + lane * 8);
        // issue next-tile K + mask
        bf16x8 kn0, kn1, kn2, kn3;
        ull mn = 0;
        if (kt + 1 < TILES) {
            kn0 = *(const bf16x8*)(kp + 2048 + k00);
            kn1 = *(const bf16x8*)(kp + 2048 + k01);
            kn2 = *(const bf16x8*)(kp + 2048 + k10);
            kn3 = *(const bf16x8*)(kp + 2048 + k11);
            mn = mp[T_];
        }
        __builtin_amdgcn_sched_barrier(0);

        ull sh = mw >> shamt;

#pragma unroll
        for (int s = 0; s < 2; ++s) {
            // ---- S^T = K . Q^T over DK=32 (2 accumulating MFMAs)
            f32x16 sc = __builtin_amdgcn_mfma_f32_32x32x16_bf16(
                s ? kc2 : kc0, qf0, zv, 0, 0, 0);
            sc = __builtin_amdgcn_mfma_f32_32x32x16_bf16(
                s ? kc3 : kc1, qf1, sc, 0, 0, 0);

            // ---- masked fixed-shift softmax: key=(r&3)+8*(r>>2)(+4l5 folded in sh)
            uint ms = (uint)(sh >> (32 * s));
            float p[16];
#pragma unroll
            for (int r = 0; r < 16; ++r) {
                int pos = (r & 3) + 8 * (r >> 2);
                float t = sc[r] - C2_;
                t = (ms & (1u << pos)) ? t : -1e30f;
                p[r] = exp2f(t);
                l_lane += p[r];
            }

            // ---- P -> A-fragments via cvt_pk + permlane32_swap, PV MFMA per kstep
#pragma unroll
            for (int h2 = 0; h2 < 2; ++h2) {
                uint w0, w1, w2, w3;
                asm("v_cvt_pk_bf16_f32 %0, %1, %2" : "=v"(w0) : "v"(p[8 * h2 + 0]), "v"(p[8 * h2 + 1]));
                asm("v_cvt_pk_bf16_f32 %0, %1, %2" : "=v"(w1) : "v"(p[8 * h2 + 2]), "v"(p[8 * h2 + 3]));
                asm("v_cvt_pk_bf16_f32 %0, %1, %2" : "=v"(w2) : "v"(p[8 * h2 + 4]), "v"(p[8 * h2 + 5]));
                asm("v_cvt_pk_bf16_f32 %0, %1, %2" : "=v"(w3) : "v"(p[8 * h2 + 6]), "v"(p[8 * h2 + 7]));
                asm volatile("v_permlane32_swap_b32 %0, %1" : "+v"(w0), "+v"(w2));
                asm volatile("v_permlane32_swap_b32 %0, %1" : "+v"(w1), "+v"(w3));
                union { uint u[4]; bf16x8 v; } pa;
                pa.u[0] = w0; pa.u[1] = w1; pa.u[2] = w2; pa.u[3] = w3;
                bf16x8 vfr = (s == 0) ? (h2 == 0 ? vc0 : vc1) : (h2 == 0 ? vc2 : vc3);
                acc = __builtin_amdgcn_mfma_f32_32x32x16_bf16(pa.v, vfr, acc, 0, 0, 0);
            }
        }

        kp += 2048;
        vp += 2048;
        mp += T_;
        if (kt + 1 < TILES) {
            kc0 = kn0; kc1 = kn1; kc2 = kn2; kc3 = kn3;
            mw = mn;
        }
    }

    // ---- l: reduce across the two key-owning halves
    l_lane += __shfl_xor(l_lane, 32, 64);

    // ---- write partials: acc[r] = O[q = (r&3)+8*(r>>2)+4*l5][d = lq]
    size_t obase = (((size_t)kh * B_ + b) * H_ + h) * T_ + qt * 128 + w * 32;
#pragma unroll
    for (int r = 0; r < 16; ++r) {
        int q = (r & 3) + 8 * (r >> 2) + 4 * l5;
        Opart[(obase + q) * DK_ + lq] = acc[r];
    }
    if (l5 == 0) Lpart[obase + lq] = l_lane;
}

// ------------------------------------ merge split-K partials (plain sums) -> ctx
__global__ __launch_bounds__(256) void merge_kernel(
    const float* __restrict__ Opart, const float* __restrict__ Lpart,
    float* __restrict__ ctx) {
    int idx = blockIdx.x * 256 + threadIdx.x;  // B*H*T*32 total
    int d = idx & 31;
    int t = (idx >> 5) & (T_ - 1);
    int bh = idx >> 14;
    int h = bh & 7, b = bh >> 3;
    size_t ps = (size_t)B_ * H_ * T_;
    size_t base = (size_t)bh * T_ + t;
    float L = 0.f, o = 0.f;
#pragma unroll
    for (int s = 0; s < SPLIT_; ++s) {
        L += Lpart[s * ps + base];
        o += Opart[(s * ps + base) * DK_ + d];
    }
    ctx[((size_t)b * T_ + t) * D_ + h * DK_ + d] = o / L;
}

// ------------------------------------------------ out = xq + ctx@Wo + bo
__global__ __launch_bounds__(256) void out_kernel(
    const float* __restrict__ ctx, const float* __restrict__ xq,
    const float* __restrict__ Wo, const float* __restrict__ bo, float* __restrict__ out) {
    int blk = blockIdx.x;
    int t0 = (blk & 31) * 16;
    int b = blk >> 5;
    int tid = threadIdx.x;
    __shared__ float s_c[16][D_];
    for (int r = 0; r < 16; ++r)
        s_c[r][tid] = ctx[((size_t)b * T_ + t0 + r) * D_ + tid];
    __syncthreads();
    float acc[16];
#pragma unroll
    for (int r = 0; r < 16; ++r) acc[r] = bo[tid];
    for (int e = 0; e < D_; ++e) {
        float w = Wo[e * D_ + tid];
#pragma unroll
        for (int r = 0; r < 16; ++r) acc[r] += s_c[r][e] * w;
    }
    for (int r = 0; r < 16; ++r) {
        size_t off = ((size_t)b * T_ + t0 + r) * D_ + tid;
        out[off] = xq[off] + acc[r];
    }
}

// ---------------------------------------------------------------- launcher
extern "C" void kernel_launch(void* const* d_in, const int* in_sizes, int n_in,
                              void* d_out, int out_size, void* d_ws, size_t ws_size,
                              hipStream_t stream) {
    const float* x = (const float*)d_in[0];
    const float* md = (const float*)d_in[1];
    const float* na = (const float*)d_in[2];
    const float* ea = (const float*)d_in[3];
    const int* mask = (const int*)d_in[4];
    const float* W_ts1 = (const float*)d_in[5];
    const float* b_ts1 = (const float*)d_in[6];
    const float* W_ts2 = (const float*)d_in[7];
    const float* b_ts2 = (const float*)d_in[8];
    const float* W_a1 = (const float*)d_in[9];
    const float* b_a1 = (const float*)d_in[10];
    const float* W_a2 = (const float*)d_in[11];
    const float* b_a2 = (const float*)d_in[12];
    const float* W_e1 = (const float*)d_in[13];
    const float* b_e1 = (const float*)d_in[14];
    const float* W_e2 = (const float*)d_in[15];
    const float* b_e2 = (const float*)d_in[16];
    const float* Wq = (const float*)d_in[17];
    const float* bq = (const float*)d_in[18];
    const float* Wk = (const float*)d_in[19];
    const float* bk = (const float*)d_in[20];
    const float* Wv = (const float*)d_in[21];
    const float* bv = (const float*)d_in[22];
    const float* Wo = (const float*)d_in[23];
    const float* bo = (const float*)d_in[24];
    const float* ln_g = (const float*)d_in[25];
    const float* ln_b = (const float*)d_in[26];
    float* out = (float*)d_out;

    char* ws = (char*)d_ws;
    float* pe = (float*)ws;    ws += (size_t)T_ * D_ * 4;
    ull* bitsT = (ull*)ws;     ws += (size_t)B_ * KWORDS_ * T_ * 8;
    __bf16* Kb = (__bf16*)ws;  ws += (size_t)B_ * H_ * NT_ * DK_ * 2;
    __bf16* Vf = (__bf16*)ws;  ws += (size_t)B_ * H_ * NT_ * DK_ * 2;
    float* xq = (float*)ws;    ws += (size_t)B_ * T_ * D_ * 4;
    __bf16* Qb = (__bf16*)ws;  ws += (size_t)B_ * T_ * D_ * 2;
    float* ctx = (float*)ws;   ws += (size_t)B_ * T_ * D_ * 4;
    float* Opart = (float*)ws; ws += (size_t)SPLIT_ * B_ * H_ * T_ * DK_ * 4;
    float* Lpart = (float*)ws; ws += (size_t)SPLIT_ * B_ * H_ * T_ * 4;
    // bf16 prepped weights
    __bf16* ts1P = (__bf16*)ws; ws += 6144 * 2;
    __bf16* a1P = (__bf16*)ws;  ws += 2048 * 2;
    __bf16* e1P = (__bf16*)ws;  ws += 8192 * 2;
    __bf16* ts2T = (__bf16*)ws; ws += 36864 * 2;
    __bf16* a2T = (__bf16*)ws;  ws += 4096 * 2;
    __bf16* e2T = (__bf16*)ws;  ws += 65536 * 2;
    __bf16* WkT = (__bf16*)ws;  ws += 65536 * 2;
    __bf16* WvT = (__bf16*)ws;  ws += 65536 * 2;

    pe_kernel<<<T_, 256, 0, stream>>>(pe);
    maskbits_kernel<<<B_ * T_, 256, 0, stream>>>(mask, bitsT);
    wprep_kernel<<<992, 256, 0, stream>>>(W_ts1, W_a1, W_e1, W_ts2, W_a2, W_e2, Wk, Wv,
                                          ts1P, a1P, e1P, ts2T, a2T, e2T, WkT, WvT);
    kv_mfma_kernel<<<B_ * N_ * (T_ / 32), 256, 0, stream>>>(
        md, na, ea, ts1P, a1P, e1P, b_ts1, b_a1, b_e1,
        ts2T, a2T, e2T, b_ts2, b_a2, b_e2, WkT, bk, WvT, bv, pe, Kb, Vf);
    q_kernel<<<B_ * (T_ / 16), 256, 0, stream>>>(x, pe, Wq, bq, ln_g, ln_b, xq, Qb);
    attn_mfma_kernel<<<B_ * H_ * (T_ / 128) * SPLIT_, 256, 0, stream>>>(
        Qb, Kb, Vf, bitsT, Opart, Lpart);
    merge_kernel<<<(B_ * H_ * T_ * DK_) / 256, 256, 0, stream>>>(Opart, Lpart, ctx);
    out_kernel<<<B_ * (T_ / 16), 256, 0, stream>>>(ctx, xq, Wo, bo, out);
}

// Round 10
// 178.728 us; speedup vs baseline: 1.5233x; 1.1621x over previous
//
#include <hip/hip_runtime.h>
#include <hip/hip_bf16.h>

#define B_ 4
#define T_ 512
#define N_ 16
#define D_ 256
#define H_ 8
#define DK_ 32
#define NT_ (N_ * T_)
#define CTS_ 6
#define CN_ 4
#define CE_ 3
#define TSE_ 192
#define AUXE_ 64
#define SPLIT_ 8
#define KWORDS_ (NT_ / 64)   // 128 mask words per row

// Q pre-scale: (1/sqrt(32)) * log2(e)  -> MFMA output is already in exp2 domain
#define QSCALE_ 0.2550689747f
// fixed softmax shift (exp2 domain): 8 * log2(e)
#define C2_ 11.5415603f

// padded LDS strides (elements): stride/2 dwords ≡ 6 mod 32 -> conflict-free b128
#define HTS_S 204
#define HAUX_S 76
#define HED_S 268
#define SK_S 268

typedef unsigned long long ull;
typedef unsigned int uint;
typedef __bf16 bf16x8 __attribute__((ext_vector_type(8)));
typedef float f32x4 __attribute__((ext_vector_type(4)));
typedef float f32x16 __attribute__((ext_vector_type(16)));

// ---------------------------------------------------------------- PE table
__global__ __launch_bounds__(256) void pe_kernel(float* pe) {
    int t = blockIdx.x;
    int d = threadIdx.x;
    int j = d >> 1;
    float div = expf((float)(2 * j) * (-9.210340371976184f / 256.0f)); // -ln(10000)/D
    float a = (float)t * div;
    pe[t * D_ + d] = (d & 1) ? cosf(a) : sinf(a);
}

// ------------------------------------- mask -> transposed bitmask [B][128][T]
__global__ __launch_bounds__(256) void maskbits_kernel(const int* __restrict__ mask,
                                                       ull* __restrict__ bitsT) {
    int row = blockIdx.x;  // b*T + t
    int b = row >> 9, t = row & (T_ - 1);
    const int* mrow = mask + (size_t)row * NT_;
    int lane = threadIdx.x & 63, wave = threadIdx.x >> 6;
    for (int it = 0; it < NT_ / 256; ++it) {
        int k = it * 256 + wave * 64 + lane;
        ull bal = __ballot(mrow[k] != 0);
        if (lane == 0) bitsT[((size_t)b * KWORDS_ + (k >> 6)) * T_ + t] = bal;
    }
}

// -------------------------------- weight prep: bf16, fragment-tiled layouts
__global__ __launch_bounds__(256) void wprep_kernel(
    const float* __restrict__ W_ts1, const float* __restrict__ W_a1,
    const float* __restrict__ W_e1, const float* __restrict__ W_ts2,
    const float* __restrict__ W_a2, const float* __restrict__ W_e2,
    const float* __restrict__ Wk, const float* __restrict__ Wv,
    __bf16* __restrict__ ts1P, __bf16* __restrict__ a1P, __bf16* __restrict__ e1P,
    __bf16* __restrict__ ts2T, __bf16* __restrict__ a2T, __bf16* __restrict__ e2T,
    __bf16* __restrict__ WkT, __bf16* __restrict__ WvT) {
    int i = blockIdx.x * 256 + threadIdx.x;
    if (i < 6144) { int col = i >> 5, k = i & 31;
        ts1P[i] = (__bf16)(k < 6 ? W_ts1[k * TSE_ + col] : 0.f); return; }
    i -= 6144;
    if (i < 2048) { int col = i >> 5, k = i & 31;
        a1P[i] = (__bf16)((k >= 6 && k < 10) ? W_a1[(k - 6) * AUXE_ + col] : 0.f); return; }
    i -= 2048;
    if (i < 8192) { int col = i >> 5, k = i & 31;
        e1P[i] = (__bf16)((k >= 10 && k < 13) ? W_e1[(k - 10) * D_ + col] : 0.f); return; }
    i -= 8192;
    if (i < 36864) {  // ts2: COLS=192, KS=6
        int tile = i >> 9, lr = (i >> 5) & 15, kk = i & 31;
        int ct = tile / 6, ks = tile % 6;
        ts2T[i] = (__bf16)W_ts2[(ks * 32 + kk) * TSE_ + ct * 16 + lr]; return; }
    i -= 36864;
    if (i < 4096) {   // a2: COLS=64, KS=2
        int tile = i >> 9, lr = (i >> 5) & 15, kk = i & 31;
        int ct = tile / 2, ks = tile % 2;
        a2T[i] = (__bf16)W_a2[(ks * 32 + kk) * AUXE_ + ct * 16 + lr]; return; }
    i -= 4096;
    if (i < 65536) {  // e2: COLS=256, KS=8
        int tile = i >> 9, lr = (i >> 5) & 15, kk = i & 31;
        int ct = tile >> 3, ks = tile & 7;
        e2T[i] = (__bf16)W_e2[(ks * 32 + kk) * D_ + ct * 16 + lr]; return; }
    i -= 65536;
    if (i < 65536) {  // Wk
        int tile = i >> 9, lr = (i >> 5) & 15, kk = i & 31;
        int ct = tile >> 3, ks = tile & 7;
        WkT[i] = (__bf16)Wk[(ks * 32 + kk) * D_ + ct * 16 + lr]; return; }
    i -= 65536;
    {                 // Wv
        int tile = i >> 9, lr = (i >> 5) & 15, kk = i & 31;
        int ct = tile >> 3, ks = tile & 7;
        WvT[i] = (__bf16)Wv[(ks * 32 + kk) * D_ + ct * 16 + lr]; }
}

// --------- MFMA kv chain: 32 rows/block, wave = 64-col quarter x ALL 32 rows
// Each B-fragment load feeds 2 MFMAs (2 row-fragments). Padded LDS strides.
// V output pre-fragmented: Vf[bh][tile64][kstep(4)][lane(64)][8 bf16]
__global__ __launch_bounds__(256, 4) void kv_mfma_kernel(
    const float* __restrict__ md, const float* __restrict__ na, const float* __restrict__ ea,
    const __bf16* __restrict__ ts1P, const __bf16* __restrict__ a1P,
    const __bf16* __restrict__ e1P,
    const float* __restrict__ b_ts1, const float* __restrict__ b_a1,
    const float* __restrict__ b_e1,
    const __bf16* __restrict__ ts2T, const __bf16* __restrict__ a2T,
    const __bf16* __restrict__ e2T,
    const float* __restrict__ b_ts2, const float* __restrict__ b_a2,
    const float* __restrict__ b_e2,
    const __bf16* __restrict__ WkT, const float* __restrict__ bk,
    const __bf16* __restrict__ WvT, const float* __restrict__ bv,
    const float* __restrict__ pe, __bf16* __restrict__ Kb, __bf16* __restrict__ Vf) {
    int blk = blockIdx.x;          // 4b * 16n * 16t = 1024
    int t0 = (blk & 15) * 32;
    int n = (blk >> 4) & 15;
    int b = blk >> 8;
    int tid = threadIdx.x, lane = tid & 63;
    int wq = tid >> 6;             // wave = col quarter
    int lr = lane & 15, lg = lane >> 4;

    __shared__ __bf16 sA[32 * 40];      // 13 channels + pad to K=32 (2.5 KB)
    __shared__ __bf16 sU[17536];        // union: hidden | {skey,sval} (35.1 KB)
    __bf16* hts = sU;                   // [32][204]
    __bf16* haux = sU + 6528;           // [32][76]
    __bf16* hedge = sU + 8960;          // [32][268]
    __bf16* skey = sU;                  // [32][268]
    __bf16* sval = sU + 8576;           // [32][268]

    for (int i = tid; i < 32 * 40; i += 256) sA[i] = (__bf16)0.f;
    __syncthreads();
    {
        int t = tid & 31, c0 = tid >> 5;
        size_t bn = (size_t)b * N_ + n;
        for (int c = c0; c < 13; c += 8) {
            float v;
            if (c < 6) v = md[(bn * CTS_ + c) * T_ + t0 + t];
            else if (c < 10) v = na[(bn * CN_ + (c - 6)) * T_ + t0 + t];
            else v = ea[(bn * CE_ + (c - 10)) * T_ + t0 + t];
            sA[t * 40 + c] = (__bf16)v;
        }
    }
    __syncthreads();

    int foff = lr * 32 + lg * 8;   // per-lane offset within a 512-elem fragment tile
    f32x4 z4 = {0.f, 0.f, 0.f, 0.f};

    // A-fragments for both 16-row halves (K=32 first layers)
    bf16x8 a1f0 = *(const bf16x8*)(sA + lr * 40 + lg * 8);
    bf16x8 a1f1 = *(const bf16x8*)(sA + (16 + lr) * 40 + lg * 8);
    int crow0 = lg * 4;            // C rows: rf*16 + lg*4 + r

    // ---- phase 2: first layers (K=32), fully unrolled: 8 B-loads, 16 MFMAs
    {
        bool isTs = (wq < 3);      // [ts1|a1] quarter type (wave-uniform)
#pragma unroll
        for (int i = 0; i < 4; ++i) {
            int ctn = wq * 4 + i;
            const __bf16* src = isTs ? (ts1P + ctn * 512) : (a1P + (ctn - 12) * 512);
            bf16x8 bf = *(const bf16x8*)(src + foff);
            f32x4 c0 = __builtin_amdgcn_mfma_f32_16x16x32_bf16(a1f0, bf, z4, 0, 0, 0);
            f32x4 c1 = __builtin_amdgcn_mfma_f32_16x16x32_bf16(a1f1, bf, z4, 0, 0, 0);
            if (isTs) {
                int gcol = ctn * 16 + lr;
                float bias = b_ts1[gcol];
#pragma unroll
                for (int r = 0; r < 4; ++r) {
                    hts[(crow0 + r) * HTS_S + gcol] = (__bf16)fmaxf(c0[r] + bias, 0.f);
                    hts[(16 + crow0 + r) * HTS_S + gcol] = (__bf16)fmaxf(c1[r] + bias, 0.f);
                }
            } else {
                int acol = (ctn - 12) * 16 + lr;
                float bias = b_a1[acol];
#pragma unroll
                for (int r = 0; r < 4; ++r) {
                    haux[(crow0 + r) * HAUX_S + acol] = (__bf16)fmaxf(c0[r] + bias, 0.f);
                    haux[(16 + crow0 + r) * HAUX_S + acol] = (__bf16)fmaxf(c1[r] + bias, 0.f);
                }
            }
        }
#pragma unroll
        for (int i = 0; i < 4; ++i) {
            int cte = wq * 4 + i;
            bf16x8 bf = *(const bf16x8*)(e1P + cte * 512 + foff);
            f32x4 c0 = __builtin_amdgcn_mfma_f32_16x16x32_bf16(a1f0, bf, z4, 0, 0, 0);
            f32x4 c1 = __builtin_amdgcn_mfma_f32_16x16x32_bf16(a1f1, bf, z4, 0, 0, 0);
            int gcol = cte * 16 + lr;
            float bias = b_e1[gcol];
#pragma unroll
            for (int r = 0; r < 4; ++r) {
                hedge[(crow0 + r) * HED_S + gcol] = (__bf16)fmaxf(c0[r] + bias, 0.f);
                hedge[(16 + crow0 + r) * HED_S + gcol] = (__bf16)fmaxf(c1[r] + bias, 0.f);
            }
        }
    }
    __syncthreads();

    // ---- phase 3a: edge second layer (K=256, 8 ks), B-prefetch pipeline
    f32x4 eacc[2][4];
#pragma unroll
    for (int i = 0; i < 4; ++i) { eacc[0][i] = z4; eacc[1][i] = z4; }
    {
        const __bf16* ebase = e2T + (size_t)(wq * 4) * 8 * 512 + foff;
        bf16x8 bcur[4];
#pragma unroll
        for (int i = 0; i < 4; ++i) bcur[i] = *(const bf16x8*)(ebase + i * 4096);
#pragma unroll 1
        for (int ks = 0; ks < 8; ++ks) {
            bf16x8 bnext[4];
            if (ks < 7) {
#pragma unroll
                for (int i = 0; i < 4; ++i)
                    bnext[i] = *(const bf16x8*)(ebase + i * 4096 + (ks + 1) * 512);
            }
            __builtin_amdgcn_sched_barrier(0);
            bf16x8 af0 = *(const bf16x8*)(hedge + lr * HED_S + ks * 32 + lg * 8);
            bf16x8 af1 = *(const bf16x8*)(hedge + (16 + lr) * HED_S + ks * 32 + lg * 8);
#pragma unroll
            for (int i = 0; i < 4; ++i) {
                eacc[0][i] = __builtin_amdgcn_mfma_f32_16x16x32_bf16(af0, bcur[i], eacc[0][i], 0, 0, 0);
                eacc[1][i] = __builtin_amdgcn_mfma_f32_16x16x32_bf16(af1, bcur[i], eacc[1][i], 0, 0, 0);
            }
            if (ks < 7) {
#pragma unroll
                for (int i = 0; i < 4; ++i) bcur[i] = bnext[i];
            }
        }
    }

    // ---- phase 3b-compute: nbr second layer (ts2 for wq<3, a2 for wq==3)
    f32x4 nacc[2][4];
#pragma unroll
    for (int i = 0; i < 4; ++i) { nacc[0][i] = z4; nacc[1][i] = z4; }
    if (wq < 3) {
        const __bf16* nbase = ts2T + (size_t)(wq * 4) * 6 * 512 + foff;
        bf16x8 bcur[4];
#pragma unroll
        for (int i = 0; i < 4; ++i) bcur[i] = *(const bf16x8*)(nbase + i * 3072);
#pragma unroll 1
        for (int ks = 0; ks < 6; ++ks) {
            bf16x8 bnext[4];
            if (ks < 5) {
#pragma unroll
                for (int i = 0; i < 4; ++i)
                    bnext[i] = *(const bf16x8*)(nbase + i * 3072 + (ks + 1) * 512);
            }
            __builtin_amdgcn_sched_barrier(0);
            bf16x8 af0 = *(const bf16x8*)(hts + lr * HTS_S + ks * 32 + lg * 8);
            bf16x8 af1 = *(const bf16x8*)(hts + (16 + lr) * HTS_S + ks * 32 + lg * 8);
#pragma unroll
            for (int i = 0; i < 4; ++i) {
                nacc[0][i] = __builtin_amdgcn_mfma_f32_16x16x32_bf16(af0, bcur[i], nacc[0][i], 0, 0, 0);
                nacc[1][i] = __builtin_amdgcn_mfma_f32_16x16x32_bf16(af1, bcur[i], nacc[1][i], 0, 0, 0);
            }
            if (ks < 5) {
#pragma unroll
                for (int i = 0; i < 4; ++i) bcur[i] = bnext[i];
            }
        }
    } else {
#pragma unroll
        for (int ks = 0; ks < 2; ++ks) {
            bf16x8 af0 = *(const bf16x8*)(haux + lr * HAUX_S + ks * 32 + lg * 8);
            bf16x8 af1 = *(const bf16x8*)(haux + (16 + lr) * HAUX_S + ks * 32 + lg * 8);
#pragma unroll
            for (int i = 0; i < 4; ++i) {
                bf16x8 bf = *(const bf16x8*)(a2T + (i * 2 + ks) * 512 + foff);
                nacc[0][i] = __builtin_amdgcn_mfma_f32_16x16x32_bf16(af0, bf, nacc[0][i], 0, 0, 0);
                nacc[1][i] = __builtin_amdgcn_mfma_f32_16x16x32_bf16(af1, bf, nacc[1][i], 0, 0, 0);
            }
        }
    }
    __syncthreads();   // hidden reads done; safe to overwrite union

    // ---- phase 3c: key = nbr*edg + pe, val = nbr + pe (bf16 into LDS)
#pragma unroll
    for (int i = 0; i < 4; ++i) {
        int gcol = wq * 64 + i * 16 + lr;
        float nb_bias = (wq < 3) ? b_ts2[gcol] : b_a2[gcol - 192];
        float ed_bias = b_e2[gcol];
#pragma unroll
        for (int rf = 0; rf < 2; ++rf)
#pragma unroll
            for (int r = 0; r < 4; ++r) {
                int row = rf * 16 + crow0 + r;
                float p = pe[(t0 + row) * D_ + gcol];
                float nb = nacc[rf][i][r] + nb_bias;
                float ed = eacc[rf][i][r] + ed_bias;
                skey[row * SK_S + gcol] = (__bf16)(nb * ed + p);
                sval[row * SK_S + gcol] = (__bf16)(nb + p);
            }
    }
    __syncthreads();

    size_t key0 = (size_t)n * T_ + t0;

    // ---- phase 4a: K projection (K=256, 8 ks), B-prefetch pipeline
    {
        const __bf16* kbse = WkT + (size_t)(wq * 4) * 8 * 512 + foff;
        f32x4 ka[2][4];
#pragma unroll
        for (int i = 0; i < 4; ++i) { ka[0][i] = z4; ka[1][i] = z4; }
        bf16x8 bcur[4];
#pragma unroll
        for (int i = 0; i < 4; ++i) bcur[i] = *(const bf16x8*)(kbse + i * 4096);
#pragma unroll 1
        for (int ks = 0; ks < 8; ++ks) {
            bf16x8 bnext[4];
            if (ks < 7) {
#pragma unroll
                for (int i = 0; i < 4; ++i)
                    bnext[i] = *(const bf16x8*)(kbse + i * 4096 + (ks + 1) * 512);
            }
            __builtin_amdgcn_sched_barrier(0);
            bf16x8 af0 = *(const bf16x8*)(skey + lr * SK_S + ks * 32 + lg * 8);
            bf16x8 af1 = *(const bf16x8*)(skey + (16 + lr) * SK_S + ks * 32 + lg * 8);
#pragma unroll
            for (int i = 0; i < 4; ++i) {
                ka[0][i] = __builtin_amdgcn_mfma_f32_16x16x32_bf16(af0, bcur[i], ka[0][i], 0, 0, 0);
                ka[1][i] = __builtin_amdgcn_mfma_f32_16x16x32_bf16(af1, bcur[i], ka[1][i], 0, 0, 0);
            }
            if (ks < 7) {
#pragma unroll
                for (int i = 0; i < 4; ++i) bcur[i] = bnext[i];
            }
        }
#pragma unroll
        for (int i = 0; i < 4; ++i) {
            int gcol = wq * 64 + i * 16 + lr;
            float kbias = bk[gcol];
            int h = gcol >> 5, dd = gcol & 31;
            size_t bh = (size_t)b * H_ + h;
#pragma unroll
            for (int rf = 0; rf < 2; ++rf) {
                int crow = rf * 16 + crow0;
#pragma unroll
                for (int r = 0; r < 4; ++r)
                    Kb[(bh * NT_ + key0 + crow + r) * DK_ + dd] = (__bf16)(ka[rf][i][r] + kbias);
            }
        }
    }

    // ---- phase 4b: V projection (K=256, 8 ks), B-prefetch pipeline
    {
        const __bf16* vbse = WvT + (size_t)(wq * 4) * 8 * 512 + foff;
        f32x4 va[2][4];
#pragma unroll
        for (int i = 0; i < 4; ++i) { va[0][i] = z4; va[1][i] = z4; }
        bf16x8 bcur[4];
#pragma unroll
        for (int i = 0; i < 4; ++i) bcur[i] = *(const bf16x8*)(vbse + i * 4096);
#pragma unroll 1
        for (int ks = 0; ks < 8; ++ks) {
            bf16x8 bnext[4];
            if (ks < 7) {
#pragma unroll
                for (int i = 0; i < 4; ++i)
                    bnext[i] = *(const bf16x8*)(vbse + i * 4096 + (ks + 1) * 512);
            }
            __builtin_amdgcn_sched_barrier(0);
            bf16x8 af0 = *(const bf16x8*)(sval + lr * SK_S + ks * 32 + lg * 8);
            bf16x8 af1 = *(const bf16x8*)(sval + (16 + lr) * SK_S + ks * 32 + lg * 8);
#pragma unroll
            for (int i = 0; i < 4; ++i) {
                va[0][i] = __builtin_amdgcn_mfma_f32_16x16x32_bf16(af0, bcur[i], va[0][i], 0, 0, 0);
                va[1][i] = __builtin_amdgcn_mfma_f32_16x16x32_bf16(af1, bcur[i], va[1][i], 0, 0, 0);
            }
            if (ks < 7) {
#pragma unroll
                for (int i = 0; i < 4; ++i) bcur[i] = bnext[i];
            }
        }
#pragma unroll
        for (int i = 0; i < 4; ++i) {
            int gcol = wq * 64 + i * 16 + lr;
            float vbias = bv[gcol];
            int h = gcol >> 5, dd = gcol & 31;
            size_t bh = (size_t)b * H_ + h;
#pragma unroll
            for (int rf = 0; rf < 2; ++rf) {
                int crow = rf * 16 + crow0;
                __bf16 tmp[4];
#pragma unroll
                for (int r = 0; r < 4; ++r) tmp[r] = (__bf16)(va[rf][i][r] + vbias);
                size_t kg = key0 + crow;
                int within = (int)(kg & 63);
                int vks = within >> 4, vl5 = (within >> 3) & 1, j0 = within & 7;
                size_t tile = kg >> 6;
                size_t vaddr = ((bh * (NT_ / 64) + tile) * 4 + vks) * 512 +
                               (size_t)(vl5 * 32 + dd) * 8 + j0;
                *(ushort4*)(Vf + vaddr) = *(ushort4*)tmp;
            }
        }
    }
}

// -------------------------- xq = x + pe, LayerNorm, Q proj -> bf16 Qb (pre-scaled)
__global__ __launch_bounds__(256) void q_kernel(
    const float* __restrict__ x, const float* __restrict__ pe,
    const float* __restrict__ Wq, const float* __restrict__ bq,
    const float* __restrict__ ln_g, const float* __restrict__ ln_b,
    float* __restrict__ xq, __bf16* __restrict__ Qb) {
    int blk = blockIdx.x;
    int t0 = (blk & 31) * 16;
    int b = blk >> 5;
    int tid = threadIdx.x;

    __shared__ float s_xn[16][D_];
    __shared__ float s_red[8];

    for (int r = 0; r < 16; ++r) {
        int t = t0 + r;
        size_t off = ((size_t)b * T_ + t) * D_ + tid;
        float v = x[off] + pe[t * D_ + tid];
        xq[off] = v;
        float s1 = v, s2 = v * v;
#pragma unroll
        for (int o = 32; o; o >>= 1) {
            s1 += __shfl_down(s1, o, 64);
            s2 += __shfl_down(s2, o, 64);
        }
        if ((tid & 63) == 0) {
            s_red[tid >> 6] = s1;
            s_red[4 + (tid >> 6)] = s2;
        }
        __syncthreads();
        float t1 = s_red[0] + s_red[1] + s_red[2] + s_red[3];
        float t2 = s_red[4] + s_red[5] + s_red[6] + s_red[7];
        float mu = t1 * (1.f / D_);
        float var = t2 * (1.f / D_) - mu * mu;
        float rs = rsqrtf(var + 1e-6f);
        s_xn[r][tid] = (v - mu) * rs * ln_g[tid] + ln_b[tid];
        __syncthreads();
    }

    float acc[16];
#pragma unroll
    for (int r = 0; r < 16; ++r) acc[r] = bq[tid];
    for (int e = 0; e < D_; ++e) {
        float w = Wq[e * D_ + tid];
#pragma unroll
        for (int r = 0; r < 16; ++r) acc[r] += s_xn[r][e] * w;
    }
    for (int r = 0; r < 16; ++r) {
        Qb[((size_t)b * T_ + t0 + r) * D_ + tid] = (__bf16)(acc[r] * QSCALE_);
    }
}

// ------- 32x32 MFMA attention: swapped QK^T, permlane32_swap P-transpose, no LDS
// grid: B*H*(T/128)*SPLIT = 1024 blocks, 256 threads (4 waves x 32 queries each)
__global__ __launch_bounds__(256, 4) void attn_mfma_kernel(
    const __bf16* __restrict__ Qb, const __bf16* __restrict__ Kb,
    const __bf16* __restrict__ Vf, const ull* __restrict__ bitsT,
    float* __restrict__ Opart, float* __restrict__ Lpart) {
    int blk = blockIdx.x;
    int kh = blk & (SPLIT_ - 1);
    int qt = (blk >> 3) & 3;
    int h = (blk >> 5) & 7;
    int b = blk >> 8;
    int tid = threadIdx.x, lane = tid & 63, w = tid >> 6;
    int lq = lane & 31, l5 = lane >> 5;

    const size_t bh = (size_t)b * H_ + h;
    const int TILES = KWORDS_ / SPLIT_;   // 16

    int qglob = qt * 128 + w * 32 + lq;
    const __bf16* qbase = Qb + ((size_t)b * T_ + qglob) * D_ + h * DK_ + l5 * 8;
    bf16x8 qf0 = *(const bf16x8*)(qbase);
    bf16x8 qf1 = *(const bf16x8*)(qbase + 16);

    const __bf16* kp = Kb + bh * NT_ * DK_ + (size_t)(kh * TILES) * 64 * DK_;
    const __bf16* vp = Vf + (bh * (NT_ / 64) + (size_t)(kh * TILES)) * 2048;
    const ull* mp = bitsT + (size_t)b * KWORDS_ * T_ + (size_t)(kh * TILES) * T_ + qglob;

    int k00 = lq * DK_ + l5 * 8;
    int k01 = k00 + 16;
    int k10 = (32 + lq) * DK_ + l5 * 8;
    int k11 = k10 + 16;
    int shamt = 4 * l5;

    f32x16 acc;
    f32x16 zv;
#pragma unroll
    for (int i = 0; i < 16; ++i) { acc[i] = 0.f; zv[i] = 0.f; }
    float l_lane = 0.f;

    bf16x8 kc0 = *(const bf16x8*)(kp + k00);
    bf16x8 kc1 = *(const bf16x8*)(kp + k01);
    bf16x8 kc2 = *(const bf16x8*)(kp + k10);
    bf16x8 kc3 = *(const bf16x8*)(kp + k11);
    ull mw = *mp;

#pragma unroll 1
    for (int kt = 0; kt < TILES; ++kt) {
        bf16x8 vc0 = *(const bf16x8*)(vp + 0 * 512 + lane * 8);
        bf16x8 vc1 = *(const bf16x8*)(vp + 1 * 512 + lane * 8);
        bf16x8 vc2 = *(const bf16x8*)(vp + 2 * 512 + lane * 8);
        bf16x8 vc3 = *(const bf16x8*)(vp + 3 * 512 + lane * 8);
        bf16x8 kn0, kn1, kn2, kn3;
        ull mn = 0;
        if (kt + 1 < TILES) {
            kn0 = *(const bf16x8*)(kp + 2048 + k00);
            kn1 = *(const bf16x8*)(kp + 2048 + k01);
            kn2 = *(const bf16x8*)(kp + 2048 + k10);
            kn3 = *(const bf16x8*)(kp + 2048 + k11);
            mn = mp[T_];
        }
        __builtin_amdgcn_sched_barrier(0);

        ull sh = mw >> shamt;

#pragma unroll
        for (int s = 0; s < 2; ++s) {
            f32x16 sc = __builtin_amdgcn_mfma_f32_32x32x16_bf16(
                s ? kc2 : kc0, qf0, zv, 0, 0, 0);
            sc = __builtin_amdgcn_mfma_f32_32x32x16_bf16(
                s ? kc3 : kc1, qf1, sc, 0, 0, 0);

            uint ms = (uint)(sh >> (32 * s));
            float p[16];
#pragma unroll
            for (int r = 0; r < 16; ++r) {
                int pos = (r & 3) + 8 * (r >> 2);
                float t = sc[r] - C2_;
                t = (ms & (1u << pos)) ? t : -1e30f;
                p[r] = exp2f(t);
                l_lane += p[r];
            }

#pragma unroll
            for (int h2 = 0; h2 < 2; ++h2) {
                uint w0, w1, w2, w3;
                asm("v_cvt_pk_bf16_f32 %0, %1, %2" : "=v"(w0) : "v"(p[8 * h2 + 0]), "v"(p[8 * h2 + 1]));
                asm("v_cvt_pk_bf16_f32 %0, %1, %2" : "=v"(w1) : "v"(p[8 * h2 + 2]), "v"(p[8 * h2 + 3]));
                asm("v_cvt_pk_bf16_f32 %0, %1, %2" : "=v"(w2) : "v"(p[8 * h2 + 4]), "v"(p[8 * h2 + 5]));
                asm("v_cvt_pk_bf16_f32 %0, %1, %2" : "=v"(w3) : "v"(p[8 * h2 + 6]), "v"(p[8 * h2 + 7]));
                asm volatile("v_permlane32_swap_b32 %0, %1" : "+v"(w0), "+v"(w2));
                asm volatile("v_permlane32_swap_b32 %0, %1" : "+v"(w1), "+v"(w3));
                union { uint u[4]; bf16x8 v; } pa;
                pa.u[0] = w0; pa.u[1] = w1; pa.u[2] = w2; pa.u[3] = w3;
                bf16x8 vfr = (s == 0) ? (h2 == 0 ? vc0 : vc1) : (h2 == 0 ? vc2 : vc3);
                acc = __builtin_amdgcn_mfma_f32_32x32x16_bf16(pa.v, vfr, acc, 0, 0, 0);
            }
        }

        kp += 2048;
        vp += 2048;
        mp += T_;
        if (kt + 1 < TILES) {
            kc0 = kn0; kc1 = kn1; kc2 = kn2; kc3 = kn3;
            mw = mn;
        }
    }

    l_lane += __shfl_xor(l_lane, 32, 64);

    size_t obase = (((size_t)kh * B_ + b) * H_ + h) * T_ + qt * 128 + w * 32;
#pragma unroll
    for (int r = 0; r < 16; ++r) {
        int q = (r & 3) + 8 * (r >> 2) + 4 * l5;
        Opart[(obase + q) * DK_ + lq] = acc[r];
    }
    if (l5 == 0) Lpart[obase + lq] = l_lane;
}

// ------------------------------------ merge split-K partials (plain sums) -> ctx
__global__ __launch_bounds__(256) void merge_kernel(
    const float* __restrict__ Opart, const float* __restrict__ Lpart,
    float* __restrict__ ctx) {
    int idx = blockIdx.x * 256 + threadIdx.x;  // B*H*T*32 total
    int d = idx & 31;
    int t = (idx >> 5) & (T_ - 1);
    int bh = idx >> 14;
    int h = bh & 7, b = bh >> 3;
    size_t ps = (size_t)B_ * H_ * T_;
    size_t base = (size_t)bh * T_ + t;
    float L = 0.f, o = 0.f;
#pragma unroll
    for (int s = 0; s < SPLIT_; ++s) {
        L += Lpart[s * ps + base];
        o += Opart[(s * ps + base) * DK_ + d];
    }
    ctx[((size_t)b * T_ + t) * D_ + h * DK_ + d] = o / L;
}

// ------------------------------------------------ out = xq + ctx@Wo + bo
__global__ __launch_bounds__(256) void out_kernel(
    const float* __restrict__ ctx, const float* __restrict__ xq,
    const float* __restrict__ Wo, const float* __restrict__ bo, float* __restrict__ out) {
    int blk = blockIdx.x;
    int t0 = (blk & 31) * 16;
    int b = blk >> 5;
    int tid = threadIdx.x;
    __shared__ float s_c[16][D_];
    for (int r = 0; r < 16; ++r)
        s_c[r][tid] = ctx[((size_t)b * T_ + t0 + r) * D_ + tid];
    __syncthreads();
    float acc[16];
#pragma unroll
    for (int r = 0; r < 16; ++r) acc[r] = bo[tid];
    for (int e = 0; e < D_; ++e) {
        float w = Wo[e * D_ + tid];
#pragma unroll
        for (int r = 0; r < 16; ++r) acc[r] += s_c[r][e] * w;
    }
    for (int r = 0; r < 16; ++r) {
        size_t off = ((size_t)b * T_ + t0 + r) * D_ + tid;
        out[off] = xq[off] + acc[r];
    }
}

// ---------------------------------------------------------------- launcher
extern "C" void kernel_launch(void* const* d_in, const int* in_sizes, int n_in,
                              void* d_out, int out_size, void* d_ws, size_t ws_size,
                              hipStream_t stream) {
    const float* x = (const float*)d_in[0];
    const float* md = (const float*)d_in[1];
    const float* na = (const float*)d_in[2];
    const float* ea = (const float*)d_in[3];
    const int* mask = (const int*)d_in[4];
    const float* W_ts1 = (const float*)d_in[5];
    const float* b_ts1 = (const float*)d_in[6];
    const float* W_ts2 = (const float*)d_in[7];
    const float* b_ts2 = (const float*)d_in[8];
    const float* W_a1 = (const float*)d_in[9];
    const float* b_a1 = (const float*)d_in[10];
    const float* W_a2 = (const float*)d_in[11];
    const float* b_a2 = (const float*)d_in[12];
    const float* W_e1 = (const float*)d_in[13];
    const float* b_e1 = (const float*)d_in[14];
    const float* W_e2 = (const float*)d_in[15];
    const float* b_e2 = (const float*)d_in[16];
    const float* Wq = (const float*)d_in[17];
    const float* bq = (const float*)d_in[18];
    const float* Wk = (const float*)d_in[19];
    const float* bk = (const float*)d_in[20];
    const float* Wv = (const float*)d_in[21];
    const float* bv = (const float*)d_in[22];
    const float* Wo = (const float*)d_in[23];
    const float* bo = (const float*)d_in[24];
    const float* ln_g = (const float*)d_in[25];
    const float* ln_b = (const float*)d_in[26];
    float* out = (float*)d_out;

    char* ws = (char*)d_ws;
    float* pe = (float*)ws;    ws += (size_t)T_ * D_ * 4;
    ull* bitsT = (ull*)ws;     ws += (size_t)B_ * KWORDS_ * T_ * 8;
    __bf16* Kb = (__bf16*)ws;  ws += (size_t)B_ * H_ * NT_ * DK_ * 2;
    __bf16* Vf = (__bf16*)ws;  ws += (size_t)B_ * H_ * NT_ * DK_ * 2;
    float* xq = (float*)ws;    ws += (size_t)B_ * T_ * D_ * 4;
    __bf16* Qb = (__bf16*)ws;  ws += (size_t)B_ * T_ * D_ * 2;
    float* ctx = (float*)ws;   ws += (size_t)B_ * T_ * D_ * 4;
    float* Opart = (float*)ws; ws += (size_t)SPLIT_ * B_ * H_ * T_ * DK_ * 4;
    float* Lpart = (float*)ws; ws += (size_t)SPLIT_ * B_ * H_ * T_ * 4;
    // bf16 prepped weights
    __bf16* ts1P = (__bf16*)ws; ws += 6144 * 2;
    __bf16* a1P = (__bf16*)ws;  ws += 2048 * 2;
    __bf16* e1P = (__bf16*)ws;  ws += 8192 * 2;
    __bf16* ts2T = (__bf16*)ws; ws += 36864 * 2;
    __bf16* a2T = (__bf16*)ws;  ws += 4096 * 2;
    __bf16* e2T = (__bf16*)ws;  ws += 65536 * 2;
    __bf16* WkT = (__bf16*)ws;  ws += 65536 * 2;
    __bf16* WvT = (__bf16*)ws;  ws += 65536 * 2;

    pe_kernel<<<T_, 256, 0, stream>>>(pe);
    maskbits_kernel<<<B_ * T_, 256, 0, stream>>>(mask, bitsT);
    wprep_kernel<<<992, 256, 0, stream>>>(W_ts1, W_a1, W_e1, W_ts2, W_a2, W_e2, Wk, Wv,
                                          ts1P, a1P, e1P, ts2T, a2T, e2T, WkT, WvT);
    kv_mfma_kernel<<<B_ * N_ * (T_ / 32), 256, 0, stream>>>(
        md, na, ea, ts1P, a1P, e1P, b_ts1, b_a1, b_e1,
        ts2T, a2T, e2T, b_ts2, b_a2, b_e2, WkT, bk, WvT, bv, pe, Kb, Vf);
    q_kernel<<<B_ * (T_ / 16), 256, 0, stream>>>(x, pe, Wq, bq, ln_g, ln_b, xq, Qb);
    attn_mfma_kernel<<<B_ * H_ * (T_ / 128) * SPLIT_, 256, 0, stream>>>(
        Qb, Kb, Vf, bitsT, Opart, Lpart);
    merge_kernel<<<(B_ * H_ * T_ * DK_) / 256, 256, 0, stream>>>(Opart, Lpart, ctx);
    out_kernel<<<B_ * (T_ / 16), 256, 0, stream>>>(ctx, xq, Wo, bo, out);
}

// Round 11
// 138.801 us; speedup vs baseline: 1.9615x; 1.2877x over previous
//
#include <hip/hip_runtime.h>
#include <hip/hip_bf16.h>

#define B_ 4
#define T_ 512
#define N_ 16
#define D_ 256
#define H_ 8
#define DK_ 32
#define NT_ (N_ * T_)
#define CTS_ 6
#define CN_ 4
#define CE_ 3
#define TSE_ 192
#define AUXE_ 64
#define SPLIT_ 8
#define KWORDS_ (NT_ / 64)   // 128 mask words per row

// Q pre-scale: (1/sqrt(32)) * log2(e)  -> MFMA output is already in exp2 domain
#define QSCALE_ 0.2550689747f

// padded LDS strides (elements): stride/2 dwords ≡ 6 mod 32 -> conflict-free b128
#define HTS_S 204
#define HAUX_S 76
#define HED_S 268
#define SK_S 268

typedef unsigned long long ull;
typedef unsigned int uint;
typedef __bf16 bf16x8 __attribute__((ext_vector_type(8)));
typedef float f32x4 __attribute__((ext_vector_type(4)));
typedef float f32x16 __attribute__((ext_vector_type(16)));

// ---------------------------------------------------------------- PE table
__global__ __launch_bounds__(256) void pe_kernel(float* pe) {
    int t = blockIdx.x;
    int d = threadIdx.x;
    int j = d >> 1;
    float div = expf((float)(2 * j) * (-9.210340371976184f / 256.0f)); // -ln(10000)/D
    float a = (float)t * div;
    pe[t * D_ + d] = (d & 1) ? cosf(a) : sinf(a);
}

// ------------------------------------- mask -> transposed bitmask [B][128][T]
__global__ __launch_bounds__(256) void maskbits_kernel(const int* __restrict__ mask,
                                                       ull* __restrict__ bitsT) {
    int row = blockIdx.x;  // b*T + t
    int b = row >> 9, t = row & (T_ - 1);
    const int* mrow = mask + (size_t)row * NT_;
    int lane = threadIdx.x & 63, wave = threadIdx.x >> 6;
    for (int it = 0; it < NT_ / 256; ++it) {
        int k = it * 256 + wave * 64 + lane;
        ull bal = __ballot(mrow[k] != 0);
        if (lane == 0) bitsT[((size_t)b * KWORDS_ + (k >> 6)) * T_ + t] = bal;
    }
}

// -------------------------------- weight prep: bf16, fragment-tiled layouts
// total elems: 6144+2048+8192+36864+4096+65536*5 = 385024 -> grid 1504
__global__ __launch_bounds__(256) void wprep_kernel(
    const float* __restrict__ W_ts1, const float* __restrict__ W_a1,
    const float* __restrict__ W_e1, const float* __restrict__ W_ts2,
    const float* __restrict__ W_a2, const float* __restrict__ W_e2,
    const float* __restrict__ Wk, const float* __restrict__ Wv,
    const float* __restrict__ Wq, const float* __restrict__ Wo,
    __bf16* __restrict__ ts1P, __bf16* __restrict__ a1P, __bf16* __restrict__ e1P,
    __bf16* __restrict__ ts2T, __bf16* __restrict__ a2T, __bf16* __restrict__ e2T,
    __bf16* __restrict__ WkT, __bf16* __restrict__ WvT,
    __bf16* __restrict__ WqT, __bf16* __restrict__ WoT) {
    int i = blockIdx.x * 256 + threadIdx.x;
    if (i < 6144) { int col = i >> 5, k = i & 31;
        ts1P[i] = (__bf16)(k < 6 ? W_ts1[k * TSE_ + col] : 0.f); return; }
    i -= 6144;
    if (i < 2048) { int col = i >> 5, k = i & 31;
        a1P[i] = (__bf16)((k >= 6 && k < 10) ? W_a1[(k - 6) * AUXE_ + col] : 0.f); return; }
    i -= 2048;
    if (i < 8192) { int col = i >> 5, k = i & 31;
        e1P[i] = (__bf16)((k >= 10 && k < 13) ? W_e1[(k - 10) * D_ + col] : 0.f); return; }
    i -= 8192;
    if (i < 36864) {  // ts2: COLS=192, KS=6
        int tile = i >> 9, lr = (i >> 5) & 15, kk = i & 31;
        int ct = tile / 6, ks = tile % 6;
        ts2T[i] = (__bf16)W_ts2[(ks * 32 + kk) * TSE_ + ct * 16 + lr]; return; }
    i -= 36864;
    if (i < 4096) {   // a2: COLS=64, KS=2
        int tile = i >> 9, lr = (i >> 5) & 15, kk = i & 31;
        int ct = tile / 2, ks = tile % 2;
        a2T[i] = (__bf16)W_a2[(ks * 32 + kk) * AUXE_ + ct * 16 + lr]; return; }
    i -= 4096;
    if (i < 65536) {  // e2: COLS=256, KS=8
        int tile = i >> 9, lr = (i >> 5) & 15, kk = i & 31;
        int ct = tile >> 3, ks = tile & 7;
        e2T[i] = (__bf16)W_e2[(ks * 32 + kk) * D_ + ct * 16 + lr]; return; }
    i -= 65536;
    if (i < 65536) {  // Wk
        int tile = i >> 9, lr = (i >> 5) & 15, kk = i & 31;
        int ct = tile >> 3, ks = tile & 7;
        WkT[i] = (__bf16)Wk[(ks * 32 + kk) * D_ + ct * 16 + lr]; return; }
    i -= 65536;
    if (i < 65536) {  // Wv
        int tile = i >> 9, lr = (i >> 5) & 15, kk = i & 31;
        int ct = tile >> 3, ks = tile & 7;
        WvT[i] = (__bf16)Wv[(ks * 32 + kk) * D_ + ct * 16 + lr]; return; }
    i -= 65536;
    if (i < 65536) {  // Wq (QSCALE pre-folded)
        int tile = i >> 9, lr = (i >> 5) & 15, kk = i & 31;
        int ct = tile >> 3, ks = tile & 7;
        WqT[i] = (__bf16)(Wq[(ks * 32 + kk) * D_ + ct * 16 + lr] * QSCALE_); return; }
    i -= 65536;
    {                 // Wo
        int tile = i >> 9, lr = (i >> 5) & 15, kk = i & 31;
        int ct = tile >> 3, ks = tile & 7;
        WoT[i] = (__bf16)Wo[(ks * 32 + kk) * D_ + ct * 16 + lr]; }
}

// --------- MFMA kv chain: 32 rows/block, wave = 64-col quarter x ALL 32 rows
__global__ __launch_bounds__(256, 4) void kv_mfma_kernel(
    const float* __restrict__ md, const float* __restrict__ na, const float* __restrict__ ea,
    const __bf16* __restrict__ ts1P, const __bf16* __restrict__ a1P,
    const __bf16* __restrict__ e1P,
    const float* __restrict__ b_ts1, const float* __restrict__ b_a1,
    const float* __restrict__ b_e1,
    const __bf16* __restrict__ ts2T, const __bf16* __restrict__ a2T,
    const __bf16* __restrict__ e2T,
    const float* __restrict__ b_ts2, const float* __restrict__ b_a2,
    const float* __restrict__ b_e2,
    const __bf16* __restrict__ WkT, const float* __restrict__ bk,
    const __bf16* __restrict__ WvT, const float* __restrict__ bv,
    const float* __restrict__ pe, __bf16* __restrict__ Kb, __bf16* __restrict__ Vf) {
    int blk = blockIdx.x;          // 4b * 16n * 16t = 1024
    int t0 = (blk & 15) * 32;
    int n = (blk >> 4) & 15;
    int b = blk >> 8;
    int tid = threadIdx.x, lane = tid & 63;
    int wq = tid >> 6;             // wave = col quarter
    int lr = lane & 15, lg = lane >> 4;

    __shared__ __bf16 sA[32 * 40];
    __shared__ __bf16 sU[17536];
    __bf16* hts = sU;                   // [32][204]
    __bf16* haux = sU + 6528;           // [32][76]
    __bf16* hedge = sU + 8960;          // [32][268]
    __bf16* skey = sU;                  // [32][268]
    __bf16* sval = sU + 8576;           // [32][268]

    for (int i = tid; i < 32 * 40; i += 256) sA[i] = (__bf16)0.f;
    __syncthreads();
    {
        int t = tid & 31, c0 = tid >> 5;
        size_t bn = (size_t)b * N_ + n;
        for (int c = c0; c < 13; c += 8) {
            float v;
            if (c < 6) v = md[(bn * CTS_ + c) * T_ + t0 + t];
            else if (c < 10) v = na[(bn * CN_ + (c - 6)) * T_ + t0 + t];
            else v = ea[(bn * CE_ + (c - 10)) * T_ + t0 + t];
            sA[t * 40 + c] = (__bf16)v;
        }
    }
    __syncthreads();

    int foff = lr * 32 + lg * 8;
    f32x4 z4 = {0.f, 0.f, 0.f, 0.f};
    bf16x8 a1f0 = *(const bf16x8*)(sA + lr * 40 + lg * 8);
    bf16x8 a1f1 = *(const bf16x8*)(sA + (16 + lr) * 40 + lg * 8);
    int crow0 = lg * 4;

    // ---- phase 2: first layers (K=32)
    {
        bool isTs = (wq < 3);
#pragma unroll
        for (int i = 0; i < 4; ++i) {
            int ctn = wq * 4 + i;
            const __bf16* src = isTs ? (ts1P + ctn * 512) : (a1P + (ctn - 12) * 512);
            bf16x8 bf = *(const bf16x8*)(src + foff);
            f32x4 c0 = __builtin_amdgcn_mfma_f32_16x16x32_bf16(a1f0, bf, z4, 0, 0, 0);
            f32x4 c1 = __builtin_amdgcn_mfma_f32_16x16x32_bf16(a1f1, bf, z4, 0, 0, 0);
            if (isTs) {
                int gcol = ctn * 16 + lr;
                float bias = b_ts1[gcol];
#pragma unroll
                for (int r = 0; r < 4; ++r) {
                    hts[(crow0 + r) * HTS_S + gcol] = (__bf16)fmaxf(c0[r] + bias, 0.f);
                    hts[(16 + crow0 + r) * HTS_S + gcol] = (__bf16)fmaxf(c1[r] + bias, 0.f);
                }
            } else {
                int acol = (ctn - 12) * 16 + lr;
                float bias = b_a1[acol];
#pragma unroll
                for (int r = 0; r < 4; ++r) {
                    haux[(crow0 + r) * HAUX_S + acol] = (__bf16)fmaxf(c0[r] + bias, 0.f);
                    haux[(16 + crow0 + r) * HAUX_S + acol] = (__bf16)fmaxf(c1[r] + bias, 0.f);
                }
            }
        }
#pragma unroll
        for (int i = 0; i < 4; ++i) {
            int cte = wq * 4 + i;
            bf16x8 bf = *(const bf16x8*)(e1P + cte * 512 + foff);
            f32x4 c0 = __builtin_amdgcn_mfma_f32_16x16x32_bf16(a1f0, bf, z4, 0, 0, 0);
            f32x4 c1 = __builtin_amdgcn_mfma_f32_16x16x32_bf16(a1f1, bf, z4, 0, 0, 0);
            int gcol = cte * 16 + lr;
            float bias = b_e1[gcol];
#pragma unroll
            for (int r = 0; r < 4; ++r) {
                hedge[(crow0 + r) * HED_S + gcol] = (__bf16)fmaxf(c0[r] + bias, 0.f);
                hedge[(16 + crow0 + r) * HED_S + gcol] = (__bf16)fmaxf(c1[r] + bias, 0.f);
            }
        }
    }
    __syncthreads();

    // ---- phase 3a: edge second layer
    f32x4 eacc[2][4];
#pragma unroll
    for (int i = 0; i < 4; ++i) { eacc[0][i] = z4; eacc[1][i] = z4; }
    {
        const __bf16* ebase = e2T + (size_t)(wq * 4) * 8 * 512 + foff;
        bf16x8 bcur[4];
#pragma unroll
        for (int i = 0; i < 4; ++i) bcur[i] = *(const bf16x8*)(ebase + i * 4096);
#pragma unroll 1
        for (int ks = 0; ks < 8; ++ks) {
            bf16x8 bnext[4];
            if (ks < 7) {
#pragma unroll
                for (int i = 0; i < 4; ++i)
                    bnext[i] = *(const bf16x8*)(ebase + i * 4096 + (ks + 1) * 512);
            }
            __builtin_amdgcn_sched_barrier(0);
            bf16x8 af0 = *(const bf16x8*)(hedge + lr * HED_S + ks * 32 + lg * 8);
            bf16x8 af1 = *(const bf16x8*)(hedge + (16 + lr) * HED_S + ks * 32 + lg * 8);
#pragma unroll
            for (int i = 0; i < 4; ++i) {
                eacc[0][i] = __builtin_amdgcn_mfma_f32_16x16x32_bf16(af0, bcur[i], eacc[0][i], 0, 0, 0);
                eacc[1][i] = __builtin_amdgcn_mfma_f32_16x16x32_bf16(af1, bcur[i], eacc[1][i], 0, 0, 0);
            }
            if (ks < 7) {
#pragma unroll
                for (int i = 0; i < 4; ++i) bcur[i] = bnext[i];
            }
        }
    }

    // ---- phase 3b: nbr second layer
    f32x4 nacc[2][4];
#pragma unroll
    for (int i = 0; i < 4; ++i) { nacc[0][i] = z4; nacc[1][i] = z4; }
    if (wq < 3) {
        const __bf16* nbase = ts2T + (size_t)(wq * 4) * 6 * 512 + foff;
        bf16x8 bcur[4];
#pragma unroll
        for (int i = 0; i < 4; ++i) bcur[i] = *(const bf16x8*)(nbase + i * 3072);
#pragma unroll 1
        for (int ks = 0; ks < 6; ++ks) {
            bf16x8 bnext[4];
            if (ks < 5) {
#pragma unroll
                for (int i = 0; i < 4; ++i)
                    bnext[i] = *(const bf16x8*)(nbase + i * 3072 + (ks + 1) * 512);
            }
            __builtin_amdgcn_sched_barrier(0);
            bf16x8 af0 = *(const bf16x8*)(hts + lr * HTS_S + ks * 32 + lg * 8);
            bf16x8 af1 = *(const bf16x8*)(hts + (16 + lr) * HTS_S + ks * 32 + lg * 8);
#pragma unroll
            for (int i = 0; i < 4; ++i) {
                nacc[0][i] = __builtin_amdgcn_mfma_f32_16x16x32_bf16(af0, bcur[i], nacc[0][i], 0, 0, 0);
                nacc[1][i] = __builtin_amdgcn_mfma_f32_16x16x32_bf16(af1, bcur[i], nacc[1][i], 0, 0, 0);
            }
            if (ks < 5) {
#pragma unroll
                for (int i = 0; i < 4; ++i) bcur[i] = bnext[i];
            }
        }
    } else {
#pragma unroll
        for (int ks = 0; ks < 2; ++ks) {
            bf16x8 af0 = *(const bf16x8*)(haux + lr * HAUX_S + ks * 32 + lg * 8);
            bf16x8 af1 = *(const bf16x8*)(haux + (16 + lr) * HAUX_S + ks * 32 + lg * 8);
#pragma unroll
            for (int i = 0; i < 4; ++i) {
                bf16x8 bf = *(const bf16x8*)(a2T + (i * 2 + ks) * 512 + foff);
                nacc[0][i] = __builtin_amdgcn_mfma_f32_16x16x32_bf16(af0, bf, nacc[0][i], 0, 0, 0);
                nacc[1][i] = __builtin_amdgcn_mfma_f32_16x16x32_bf16(af1, bf, nacc[1][i], 0, 0, 0);
            }
        }
    }
    __syncthreads();

    // ---- phase 3c: key/val assembly
#pragma unroll
    for (int i = 0; i < 4; ++i) {
        int gcol = wq * 64 + i * 16 + lr;
        float nb_bias = (wq < 3) ? b_ts2[gcol] : b_a2[gcol - 192];
        float ed_bias = b_e2[gcol];
#pragma unroll
        for (int rf = 0; rf < 2; ++rf)
#pragma unroll
            for (int r = 0; r < 4; ++r) {
                int row = rf * 16 + crow0 + r;
                float p = pe[(t0 + row) * D_ + gcol];
                float nb = nacc[rf][i][r] + nb_bias;
                float ed = eacc[rf][i][r] + ed_bias;
                skey[row * SK_S + gcol] = (__bf16)(nb * ed + p);
                sval[row * SK_S + gcol] = (__bf16)(nb + p);
            }
    }
    __syncthreads();

    size_t key0 = (size_t)n * T_ + t0;

    // ---- phase 4a: K projection
    {
        const __bf16* kbse = WkT + (size_t)(wq * 4) * 8 * 512 + foff;
        f32x4 ka[2][4];
#pragma unroll
        for (int i = 0; i < 4; ++i) { ka[0][i] = z4; ka[1][i] = z4; }
        bf16x8 bcur[4];
#pragma unroll
        for (int i = 0; i < 4; ++i) bcur[i] = *(const bf16x8*)(kbse + i * 4096);
#pragma unroll 1
        for (int ks = 0; ks < 8; ++ks) {
            bf16x8 bnext[4];
            if (ks < 7) {
#pragma unroll
                for (int i = 0; i < 4; ++i)
                    bnext[i] = *(const bf16x8*)(kbse + i * 4096 + (ks + 1) * 512);
            }
            __builtin_amdgcn_sched_barrier(0);
            bf16x8 af0 = *(const bf16x8*)(skey + lr * SK_S + ks * 32 + lg * 8);
            bf16x8 af1 = *(const bf16x8*)(skey + (16 + lr) * SK_S + ks * 32 + lg * 8);
#pragma unroll
            for (int i = 0; i < 4; ++i) {
                ka[0][i] = __builtin_amdgcn_mfma_f32_16x16x32_bf16(af0, bcur[i], ka[0][i], 0, 0, 0);
                ka[1][i] = __builtin_amdgcn_mfma_f32_16x16x32_bf16(af1, bcur[i], ka[1][i], 0, 0, 0);
            }
            if (ks < 7) {
#pragma unroll
                for (int i = 0; i < 4; ++i) bcur[i] = bnext[i];
            }
        }
#pragma unroll
        for (int i = 0; i < 4; ++i) {
            int gcol = wq * 64 + i * 16 + lr;
            float kbias = bk[gcol];
            int h = gcol >> 5, dd = gcol & 31;
            size_t bh = (size_t)b * H_ + h;
#pragma unroll
            for (int rf = 0; rf < 2; ++rf) {
                int crow = rf * 16 + crow0;
#pragma unroll
                for (int r = 0; r < 4; ++r)
                    Kb[(bh * NT_ + key0 + crow + r) * DK_ + dd] = (__bf16)(ka[rf][i][r] + kbias);
            }
        }
    }

    // ---- phase 4b: V projection
    {
        const __bf16* vbse = WvT + (size_t)(wq * 4) * 8 * 512 + foff;
        f32x4 va[2][4];
#pragma unroll
        for (int i = 0; i < 4; ++i) { va[0][i] = z4; va[1][i] = z4; }
        bf16x8 bcur[4];
#pragma unroll
        for (int i = 0; i < 4; ++i) bcur[i] = *(const bf16x8*)(vbse + i * 4096);
#pragma unroll 1
        for (int ks = 0; ks < 8; ++ks) {
            bf16x8 bnext[4];
            if (ks < 7) {
#pragma unroll
                for (int i = 0; i < 4; ++i)
                    bnext[i] = *(const bf16x8*)(vbse + i * 4096 + (ks + 1) * 512);
            }
            __builtin_amdgcn_sched_barrier(0);
            bf16x8 af0 = *(const bf16x8*)(sval + lr * SK_S + ks * 32 + lg * 8);
            bf16x8 af1 = *(const bf16x8*)(sval + (16 + lr) * SK_S + ks * 32 + lg * 8);
#pragma unroll
            for (int i = 0; i < 4; ++i) {
                va[0][i] = __builtin_amdgcn_mfma_f32_16x16x32_bf16(af0, bcur[i], va[0][i], 0, 0, 0);
                va[1][i] = __builtin_amdgcn_mfma_f32_16x16x32_bf16(af1, bcur[i], va[1][i], 0, 0, 0);
            }
            if (ks < 7) {
#pragma unroll
                for (int i = 0; i < 4; ++i) bcur[i] = bnext[i];
            }
        }
#pragma unroll
        for (int i = 0; i < 4; ++i) {
            int gcol = wq * 64 + i * 16 + lr;
            float vbias = bv[gcol];
            int h = gcol >> 5, dd = gcol & 31;
            size_t bh = (size_t)b * H_ + h;
#pragma unroll
            for (int rf = 0; rf < 2; ++rf) {
                int crow = rf * 16 + crow0;
                __bf16 tmp[4];
#pragma unroll
                for (int r = 0; r < 4; ++r) tmp[r] = (__bf16)(va[rf][i][r] + vbias);
                size_t kg = key0 + crow;
                int within = (int)(kg & 63);
                int vks = within >> 4, vl5 = (within >> 3) & 1, j0 = within & 7;
                size_t tile = kg >> 6;
                size_t vaddr = ((bh * (NT_ / 64) + tile) * 4 + vks) * 512 +
                               (size_t)(vl5 * 32 + dd) * 8 + j0;
                *(ushort4*)(Vf + vaddr) = *(ushort4*)tmp;
            }
        }
    }
}

// ------- xq = x + pe, row-parallel LayerNorm, MFMA Q proj (QSCALE in WqT)
// grid: B*(T/32) = 64 blocks
__global__ __launch_bounds__(256) void q_mfma_kernel(
    const float* __restrict__ x, const float* __restrict__ pe,
    const __bf16* __restrict__ WqT, const float* __restrict__ bq,
    const float* __restrict__ ln_g, const float* __restrict__ ln_b,
    float* __restrict__ xq, __bf16* __restrict__ Qb) {
    int blk = blockIdx.x;
    int t0 = (blk & 15) * 32;
    int b = blk >> 4;
    int tid = threadIdx.x, lane = tid & 63;
    int wq = tid >> 6, lr = lane & 15, lg = lane >> 4;

    __shared__ __bf16 s_xn[32 * SK_S];

    // ---- LN: 8 threads per row, all 32 rows in parallel
    {
        int row = tid >> 3, sub = tid & 7;
        size_t roff = ((size_t)b * T_ + t0 + row) * D_;
        const float* pr = pe + (t0 + row) * D_;
        f32x4 vv[8];
        float s1 = 0.f, s2 = 0.f;
#pragma unroll
        for (int q4 = 0; q4 < 8; ++q4) {
            int c = q4 * 32 + sub * 4;
            f32x4 xv = *(const f32x4*)(x + roff + c);
            f32x4 pv = *(const f32x4*)(pr + c);
            f32x4 t4;
#pragma unroll
            for (int j = 0; j < 4; ++j) {
                t4[j] = xv[j] + pv[j];
                s1 += t4[j];
                s2 += t4[j] * t4[j];
            }
            *(f32x4*)(xq + roff + c) = t4;
            vv[q4] = t4;
        }
#pragma unroll
        for (int o = 1; o <= 4; o <<= 1) {
            s1 += __shfl_xor(s1, o, 64);
            s2 += __shfl_xor(s2, o, 64);
        }
        float mu = s1 * (1.f / D_);
        float var = s2 * (1.f / D_) - mu * mu;
        float rs = rsqrtf(var + 1e-6f);
#pragma unroll
        for (int q4 = 0; q4 < 8; ++q4) {
            int c = q4 * 32 + sub * 4;
            f32x4 g4 = *(const f32x4*)(ln_g + c);
            f32x4 b4 = *(const f32x4*)(ln_b + c);
#pragma unroll
            for (int j = 0; j < 4; ++j)
                s_xn[row * SK_S + c + j] = (__bf16)((vv[q4][j] - mu) * rs * g4[j] + b4[j]);
        }
    }
    __syncthreads();

    // ---- MFMA projection (kv phase-4 pattern)
    int foff = lr * 32 + lg * 8;
    int crow0 = lg * 4;
    f32x4 z4 = {0.f, 0.f, 0.f, 0.f};
    f32x4 qa[2][4];
#pragma unroll
    for (int i = 0; i < 4; ++i) { qa[0][i] = z4; qa[1][i] = z4; }
    const __bf16* qbse = WqT + (size_t)(wq * 4) * 8 * 512 + foff;
#pragma unroll
    for (int ks = 0; ks < 8; ++ks) {
        bf16x8 af0 = *(const bf16x8*)(s_xn + lr * SK_S + ks * 32 + lg * 8);
        bf16x8 af1 = *(const bf16x8*)(s_xn + (16 + lr) * SK_S + ks * 32 + lg * 8);
#pragma unroll
        for (int i = 0; i < 4; ++i) {
            bf16x8 b8 = *(const bf16x8*)(qbse + i * 4096 + ks * 512);
            qa[0][i] = __builtin_amdgcn_mfma_f32_16x16x32_bf16(af0, b8, qa[0][i], 0, 0, 0);
            qa[1][i] = __builtin_amdgcn_mfma_f32_16x16x32_bf16(af1, b8, qa[1][i], 0, 0, 0);
        }
    }
#pragma unroll
    for (int i = 0; i < 4; ++i) {
        int gcol = wq * 64 + i * 16 + lr;
        float bias = bq[gcol] * QSCALE_;
#pragma unroll
        for (int rf = 0; rf < 2; ++rf)
#pragma unroll
            for (int r = 0; r < 4; ++r)
                Qb[((size_t)b * T_ + t0 + rf * 16 + crow0 + r) * D_ + gcol] =
                    (__bf16)(qa[rf][i][r] + bias);
    }
}

// ------- 32x32 MFMA attention: no C2, sign-mask AND, l via ones-MFMA, no LDS
__global__ __launch_bounds__(256, 4) void attn_mfma_kernel(
    const __bf16* __restrict__ Qb, const __bf16* __restrict__ Kb,
    const __bf16* __restrict__ Vf, const ull* __restrict__ bitsT,
    float* __restrict__ Opart, float* __restrict__ Lpart) {
    int blk = blockIdx.x;
    int kh = blk & (SPLIT_ - 1);
    int qt = (blk >> 3) & 3;
    int h = (blk >> 5) & 7;
    int b = blk >> 8;
    int tid = threadIdx.x, lane = tid & 63, w = tid >> 6;
    int lq = lane & 31, l5 = lane >> 5;

    const size_t bh = (size_t)b * H_ + h;
    const int TILES = KWORDS_ / SPLIT_;   // 16

    int qglob = qt * 128 + w * 32 + lq;
    const __bf16* qbase = Qb + ((size_t)b * T_ + qglob) * D_ + h * DK_ + l5 * 8;
    bf16x8 qf0 = *(const bf16x8*)(qbase);
    bf16x8 qf1 = *(const bf16x8*)(qbase + 16);

    const __bf16* kp = Kb + bh * NT_ * DK_ + (size_t)(kh * TILES) * 64 * DK_;
    const __bf16* vp = Vf + (bh * (NT_ / 64) + (size_t)(kh * TILES)) * 2048;
    const ull* mp = bitsT + (size_t)b * KWORDS_ * T_ + (size_t)(kh * TILES) * T_ + qglob;

    int k00 = lq * DK_ + l5 * 8;
    int k01 = k00 + 16;
    int k10 = (32 + lq) * DK_ + l5 * 8;
    int k11 = k10 + 16;
    int shamt = 4 * l5;

    f32x16 acc, acc_l, zv;
#pragma unroll
    for (int i = 0; i < 16; ++i) { acc[i] = 0.f; acc_l[i] = 0.f; zv[i] = 0.f; }
    union { uint u[4]; bf16x8 v; } onesf;
    onesf.u[0] = 0x3F803F80u; onesf.u[1] = 0x3F803F80u;
    onesf.u[2] = 0x3F803F80u; onesf.u[3] = 0x3F803F80u;

    bf16x8 kc0 = *(const bf16x8*)(kp + k00);
    bf16x8 kc1 = *(const bf16x8*)(kp + k01);
    bf16x8 kc2 = *(const bf16x8*)(kp + k10);
    bf16x8 kc3 = *(const bf16x8*)(kp + k11);
    ull mw = *mp;

#pragma unroll 1
    for (int kt = 0; kt < TILES; ++kt) {
        bf16x8 vc0 = *(const bf16x8*)(vp + 0 * 512 + lane * 8);
        bf16x8 vc1 = *(const bf16x8*)(vp + 1 * 512 + lane * 8);
        bf16x8 vc2 = *(const bf16x8*)(vp + 2 * 512 + lane * 8);
        bf16x8 vc3 = *(const bf16x8*)(vp + 3 * 512 + lane * 8);
        bf16x8 kn0, kn1, kn2, kn3;
        ull mn = 0;
        if (kt + 1 < TILES) {
            kn0 = *(const bf16x8*)(kp + 2048 + k00);
            kn1 = *(const bf16x8*)(kp + 2048 + k01);
            kn2 = *(const bf16x8*)(kp + 2048 + k10);
            kn3 = *(const bf16x8*)(kp + 2048 + k11);
            mn = mp[T_];
        }
        __builtin_amdgcn_sched_barrier(0);

        ull sh = mw >> shamt;

#pragma unroll
        for (int s = 0; s < 2; ++s) {
            f32x16 sc = __builtin_amdgcn_mfma_f32_32x32x16_bf16(
                s ? kc2 : kc0, qf0, zv, 0, 0, 0);
            sc = __builtin_amdgcn_mfma_f32_32x32x16_bf16(
                s ? kc3 : kc1, qf1, sc, 0, 0, 0);

            uint ms = (uint)(sh >> (32 * s));
            float p[16];
#pragma unroll
            for (int r = 0; r < 16; ++r) {
                int pos = (r & 3) + 8 * (r >> 2);
                float e = exp2f(sc[r]);
                uint mb = (uint)(((int)(ms << (31 - pos))) >> 31);  // 0 or all-ones
                p[r] = __uint_as_float(__float_as_uint(e) & mb);
            }

#pragma unroll
            for (int h2 = 0; h2 < 2; ++h2) {
                uint w0, w1, w2, w3;
                asm("v_cvt_pk_bf16_f32 %0, %1, %2" : "=v"(w0) : "v"(p[8 * h2 + 0]), "v"(p[8 * h2 + 1]));
                asm("v_cvt_pk_bf16_f32 %0, %1, %2" : "=v"(w1) : "v"(p[8 * h2 + 2]), "v"(p[8 * h2 + 3]));
                asm("v_cvt_pk_bf16_f32 %0, %1, %2" : "=v"(w2) : "v"(p[8 * h2 + 4]), "v"(p[8 * h2 + 5]));
                asm("v_cvt_pk_bf16_f32 %0, %1, %2" : "=v"(w3) : "v"(p[8 * h2 + 6]), "v"(p[8 * h2 + 7]));
                asm volatile("v_permlane32_swap_b32 %0, %1" : "+v"(w0), "+v"(w2));
                asm volatile("v_permlane32_swap_b32 %0, %1" : "+v"(w1), "+v"(w3));
                union { uint u[4]; bf16x8 v; } pa;
                pa.u[0] = w0; pa.u[1] = w1; pa.u[2] = w2; pa.u[3] = w3;
                bf16x8 vfr = (s == 0) ? (h2 == 0 ? vc0 : vc1) : (h2 == 0 ? vc2 : vc3);
                acc = __builtin_amdgcn_mfma_f32_32x32x16_bf16(pa.v, vfr, acc, 0, 0, 0);
                acc_l = __builtin_amdgcn_mfma_f32_32x32x16_bf16(pa.v, onesf.v, acc_l, 0, 0, 0);
            }
        }

        kp += 2048;
        vp += 2048;
        mp += T_;
        if (kt + 1 < TILES) {
            kc0 = kn0; kc1 = kn1; kc2 = kn2; kc3 = kn3;
            mw = mn;
        }
    }

    size_t obase = (((size_t)kh * B_ + b) * H_ + h) * T_ + qt * 128 + w * 32;
#pragma unroll
    for (int r = 0; r < 16; ++r) {
        int q = (r & 3) + 8 * (r >> 2) + 4 * l5;
        Opart[(obase + q) * DK_ + lq] = acc[r];
    }
    if (lq == 0) {
#pragma unroll
        for (int r = 0; r < 16; ++r) {
            int q = (r & 3) + 8 * (r >> 2) + 4 * l5;
            Lpart[obase + q] = acc_l[r];
        }
    }
}

// ------------------------------ merge split-K partials -> ctx bf16
__global__ __launch_bounds__(256) void merge_kernel(
    const float* __restrict__ Opart, const float* __restrict__ Lpart,
    __bf16* __restrict__ ctxb) {
    int idx = blockIdx.x * 256 + threadIdx.x;  // B*H*T*32 total
    int d = idx & 31;
    int t = (idx >> 5) & (T_ - 1);
    int bh = idx >> 14;
    int h = bh & 7, b = bh >> 3;
    size_t ps = (size_t)B_ * H_ * T_;
    size_t base = (size_t)bh * T_ + t;
    float L = 0.f, o = 0.f;
#pragma unroll
    for (int s = 0; s < SPLIT_; ++s) {
        L += Lpart[s * ps + base];
        o += Opart[(s * ps + base) * DK_ + d];
    }
    ctxb[((size_t)b * T_ + t) * D_ + h * DK_ + d] = (__bf16)(o / L);
}

// ------------------------------ out = xq + ctx@Wo + bo (MFMA), grid 64
__global__ __launch_bounds__(256) void out_mfma_kernel(
    const __bf16* __restrict__ ctxb, const float* __restrict__ xq,
    const __bf16* __restrict__ WoT, const float* __restrict__ bo,
    float* __restrict__ out) {
    int blk = blockIdx.x;
    int t0 = (blk & 15) * 32;
    int b = blk >> 4;
    int tid = threadIdx.x, lane = tid & 63;
    int wq = tid >> 6, lr = lane & 15, lg = lane >> 4;

    __shared__ __bf16 sc_[32 * SK_S];
    for (int idx = tid; idx < 32 * 64; idx += 256) {
        int r = idx >> 6, c4 = (idx & 63) * 4;
        *(ushort4*)(sc_ + r * SK_S + c4) =
            *(const ushort4*)(ctxb + ((size_t)b * T_ + t0 + r) * D_ + c4);
    }
    __syncthreads();

    int foff = lr * 32 + lg * 8;
    int crow0 = lg * 4;
    f32x4 z4 = {0.f, 0.f, 0.f, 0.f};
    f32x4 oa[2][4];
#pragma unroll
    for (int i = 0; i < 4; ++i) { oa[0][i] = z4; oa[1][i] = z4; }
    const __bf16* obse = WoT + (size_t)(wq * 4) * 8 * 512 + foff;
#pragma unroll
    for (int ks = 0; ks < 8; ++ks) {
        bf16x8 af0 = *(const bf16x8*)(sc_ + lr * SK_S + ks * 32 + lg * 8);
        bf16x8 af1 = *(const bf16x8*)(sc_ + (16 + lr) * SK_S + ks * 32 + lg * 8);
#pragma unroll
        for (int i = 0; i < 4; ++i) {
            bf16x8 b8 = *(const bf16x8*)(obse + i * 4096 + ks * 512);
            oa[0][i] = __builtin_amdgcn_mfma_f32_16x16x32_bf16(af0, b8, oa[0][i], 0, 0, 0);
            oa[1][i] = __builtin_amdgcn_mfma_f32_16x16x32_bf16(af1, b8, oa[1][i], 0, 0, 0);
        }
    }
#pragma unroll
    for (int i = 0; i < 4; ++i) {
        int gcol = wq * 64 + i * 16 + lr;
        float bias = bo[gcol];
#pragma unroll
        for (int rf = 0; rf < 2; ++rf)
#pragma unroll
            for (int r = 0; r < 4; ++r) {
                size_t off = ((size_t)b * T_ + t0 + rf * 16 + crow0 + r) * D_ + gcol;
                out[off] = xq[off] + oa[rf][i][r] + bias;
            }
    }
}

// ---------------------------------------------------------------- launcher
extern "C" void kernel_launch(void* const* d_in, const int* in_sizes, int n_in,
                              void* d_out, int out_size, void* d_ws, size_t ws_size,
                              hipStream_t stream) {
    const float* x = (const float*)d_in[0];
    const float* md = (const float*)d_in[1];
    const float* na = (const float*)d_in[2];
    const float* ea = (const float*)d_in[3];
    const int* mask = (const int*)d_in[4];
    const float* W_ts1 = (const float*)d_in[5];
    const float* b_ts1 = (const float*)d_in[6];
    const float* W_ts2 = (const float*)d_in[7];
    const float* b_ts2 = (const float*)d_in[8];
    const float* W_a1 = (const float*)d_in[9];
    const float* b_a1 = (const float*)d_in[10];
    const float* W_a2 = (const float*)d_in[11];
    const float* b_a2 = (const float*)d_in[12];
    const float* W_e1 = (const float*)d_in[13];
    const float* b_e1 = (const float*)d_in[14];
    const float* W_e2 = (const float*)d_in[15];
    const float* b_e2 = (const float*)d_in[16];
    const float* Wq = (const float*)d_in[17];
    const float* bq = (const float*)d_in[18];
    const float* Wk = (const float*)d_in[19];
    const float* bk = (const float*)d_in[20];
    const float* Wv = (const float*)d_in[21];
    const float* bv = (const float*)d_in[22];
    const float* Wo = (const float*)d_in[23];
    const float* bo = (const float*)d_in[24];
    const float* ln_g = (const float*)d_in[25];
    const float* ln_b = (const float*)d_in[26];
    float* out = (float*)d_out;

    char* ws = (char*)d_ws;
    float* pe = (float*)ws;     ws += (size_t)T_ * D_ * 4;
    ull* bitsT = (ull*)ws;      ws += (size_t)B_ * KWORDS_ * T_ * 8;
    __bf16* Kb = (__bf16*)ws;   ws += (size_t)B_ * H_ * NT_ * DK_ * 2;
    __bf16* Vf = (__bf16*)ws;   ws += (size_t)B_ * H_ * NT_ * DK_ * 2;
    float* xq = (float*)ws;     ws += (size_t)B_ * T_ * D_ * 4;
    __bf16* Qb = (__bf16*)ws;   ws += (size_t)B_ * T_ * D_ * 2;
    __bf16* ctxb = (__bf16*)ws; ws += (size_t)B_ * T_ * D_ * 2;
    float* Opart = (float*)ws;  ws += (size_t)SPLIT_ * B_ * H_ * T_ * DK_ * 4;
    float* Lpart = (float*)ws;  ws += (size_t)SPLIT_ * B_ * H_ * T_ * 4;
    // bf16 prepped weights
    __bf16* ts1P = (__bf16*)ws; ws += 6144 * 2;
    __bf16* a1P = (__bf16*)ws;  ws += 2048 * 2;
    __bf16* e1P = (__bf16*)ws;  ws += 8192 * 2;
    __bf16* ts2T = (__bf16*)ws; ws += 36864 * 2;
    __bf16* a2T = (__bf16*)ws;  ws += 4096 * 2;
    __bf16* e2T = (__bf16*)ws;  ws += 65536 * 2;
    __bf16* WkT = (__bf16*)ws;  ws += 65536 * 2;
    __bf16* WvT = (__bf16*)ws;  ws += 65536 * 2;
    __bf16* WqT = (__bf16*)ws;  ws += 65536 * 2;
    __bf16* WoT = (__bf16*)ws;  ws += 65536 * 2;

    pe_kernel<<<T_, 256, 0, stream>>>(pe);
    maskbits_kernel<<<B_ * T_, 256, 0, stream>>>(mask, bitsT);
    wprep_kernel<<<1504, 256, 0, stream>>>(W_ts1, W_a1, W_e1, W_ts2, W_a2, W_e2,
                                           Wk, Wv, Wq, Wo,
                                           ts1P, a1P, e1P, ts2T, a2T, e2T,
                                           WkT, WvT, WqT, WoT);
    kv_mfma_kernel<<<B_ * N_ * (T_ / 32), 256, 0, stream>>>(
        md, na, ea, ts1P, a1P, e1P, b_ts1, b_a1, b_e1,
        ts2T, a2T, e2T, b_ts2, b_a2, b_e2, WkT, bk, WvT, bv, pe, Kb, Vf);
    q_mfma_kernel<<<B_ * (T_ / 32), 256, 0, stream>>>(x, pe, WqT, bq, ln_g, ln_b, xq, Qb);
    attn_mfma_kernel<<<B_ * H_ * (T_ / 128) * SPLIT_, 256, 0, stream>>>(
        Qb, Kb, Vf, bitsT, Opart, Lpart);
    merge_kernel<<<(B_ * H_ * T_ * DK_) / 256, 256, 0, stream>>>(Opart, Lpart, ctxb);
    out_mfma_kernel<<<B_ * (T_ / 32), 256, 0, stream>>>(ctxb, xq, WoT, bo, out);
}

// Round 12
// 125.345 us; speedup vs baseline: 2.1720x; 1.1073x over previous
//
#include <hip/hip_runtime.h>
#include <hip/hip_bf16.h>

#define B_ 4
#define T_ 512
#define N_ 16
#define D_ 256
#define H_ 8
#define DK_ 32
#define NT_ (N_ * T_)
#define CTS_ 6
#define CN_ 4
#define CE_ 3
#define TSE_ 192
#define AUXE_ 64
#define SPLIT_ 8
#define KWORDS_ (NT_ / 64)   // 128 mask words per row

// Q pre-scale: 1/sqrt(32) (natural-exp domain; __expf is native v_exp)
#define QSCALE_ 0.1767766952966369f

// padded LDS strides (elements): stride/2 dwords ≡ 6 mod 32 -> conflict-free b128
#define HTS_S 204
#define HAUX_S 76
#define HED_S 268
#define SK_S 268

typedef unsigned long long ull;
typedef unsigned int uint;
typedef __bf16 bf16x8 __attribute__((ext_vector_type(8)));
typedef float f32x4 __attribute__((ext_vector_type(4)));
typedef float f32x16 __attribute__((ext_vector_type(16)));

// ---------------------------------------------------------------- PE table
__global__ __launch_bounds__(256) void pe_kernel(float* pe) {
    int t = blockIdx.x;
    int d = threadIdx.x;
    int j = d >> 1;
    float div = expf((float)(2 * j) * (-9.210340371976184f / 256.0f)); // -ln(10000)/D
    float a = (float)t * div;
    pe[t * D_ + d] = (d & 1) ? cosf(a) : sinf(a);
}

// ------------------------------------- mask -> transposed bitmask [B][128][T]
__global__ __launch_bounds__(256) void maskbits_kernel(const int* __restrict__ mask,
                                                       ull* __restrict__ bitsT) {
    int row = blockIdx.x;  // b*T + t
    int b = row >> 9, t = row & (T_ - 1);
    const int* mrow = mask + (size_t)row * NT_;
    int lane = threadIdx.x & 63, wave = threadIdx.x >> 6;
    for (int it = 0; it < NT_ / 256; ++it) {
        int k = it * 256 + wave * 64 + lane;
        ull bal = __ballot(mrow[k] != 0);
        if (lane == 0) bitsT[((size_t)b * KWORDS_ + (k >> 6)) * T_ + t] = bal;
    }
}

// -------------------------------- weight prep: bf16, fragment-tiled layouts
// total elems: 6144+2048+8192+36864+4096+65536*5 = 385024 -> grid 1504
__global__ __launch_bounds__(256) void wprep_kernel(
    const float* __restrict__ W_ts1, const float* __restrict__ W_a1,
    const float* __restrict__ W_e1, const float* __restrict__ W_ts2,
    const float* __restrict__ W_a2, const float* __restrict__ W_e2,
    const float* __restrict__ Wk, const float* __restrict__ Wv,
    const float* __restrict__ Wq, const float* __restrict__ Wo,
    __bf16* __restrict__ ts1P, __bf16* __restrict__ a1P, __bf16* __restrict__ e1P,
    __bf16* __restrict__ ts2T, __bf16* __restrict__ a2T, __bf16* __restrict__ e2T,
    __bf16* __restrict__ WkT, __bf16* __restrict__ WvT,
    __bf16* __restrict__ WqT, __bf16* __restrict__ WoT) {
    int i = blockIdx.x * 256 + threadIdx.x;
    if (i < 6144) { int col = i >> 5, k = i & 31;
        ts1P[i] = (__bf16)(k < 6 ? W_ts1[k * TSE_ + col] : 0.f); return; }
    i -= 6144;
    if (i < 2048) { int col = i >> 5, k = i & 31;
        a1P[i] = (__bf16)((k >= 6 && k < 10) ? W_a1[(k - 6) * AUXE_ + col] : 0.f); return; }
    i -= 2048;
    if (i < 8192) { int col = i >> 5, k = i & 31;
        e1P[i] = (__bf16)((k >= 10 && k < 13) ? W_e1[(k - 10) * D_ + col] : 0.f); return; }
    i -= 8192;
    if (i < 36864) {  // ts2: COLS=192, KS=6
        int tile = i >> 9, lr = (i >> 5) & 15, kk = i & 31;
        int ct = tile / 6, ks = tile % 6;
        ts2T[i] = (__bf16)W_ts2[(ks * 32 + kk) * TSE_ + ct * 16 + lr]; return; }
    i -= 36864;
    if (i < 4096) {   // a2: COLS=64, KS=2
        int tile = i >> 9, lr = (i >> 5) & 15, kk = i & 31;
        int ct = tile / 2, ks = tile % 2;
        a2T[i] = (__bf16)W_a2[(ks * 32 + kk) * AUXE_ + ct * 16 + lr]; return; }
    i -= 4096;
    if (i < 65536) {  // e2: COLS=256, KS=8
        int tile = i >> 9, lr = (i >> 5) & 15, kk = i & 31;
        int ct = tile >> 3, ks = tile & 7;
        e2T[i] = (__bf16)W_e2[(ks * 32 + kk) * D_ + ct * 16 + lr]; return; }
    i -= 65536;
    if (i < 65536) {  // Wk
        int tile = i >> 9, lr = (i >> 5) & 15, kk = i & 31;
        int ct = tile >> 3, ks = tile & 7;
        WkT[i] = (__bf16)Wk[(ks * 32 + kk) * D_ + ct * 16 + lr]; return; }
    i -= 65536;
    if (i < 65536) {  // Wv
        int tile = i >> 9, lr = (i >> 5) & 15, kk = i & 31;
        int ct = tile >> 3, ks = tile & 7;
        WvT[i] = (__bf16)Wv[(ks * 32 + kk) * D_ + ct * 16 + lr]; return; }
    i -= 65536;
    if (i < 65536) {  // Wq (QSCALE pre-folded)
        int tile = i >> 9, lr = (i >> 5) & 15, kk = i & 31;
        int ct = tile >> 3, ks = tile & 7;
        WqT[i] = (__bf16)(Wq[(ks * 32 + kk) * D_ + ct * 16 + lr] * QSCALE_); return; }
    i -= 65536;
    {                 // Wo
        int tile = i >> 9, lr = (i >> 5) & 15, kk = i & 31;
        int ct = tile >> 3, ks = tile & 7;
        WoT[i] = (__bf16)Wo[(ks * 32 + kk) * D_ + ct * 16 + lr]; }
}

// --------- MFMA kv chain: 32 rows/block, wave = 64-col quarter x ALL 32 rows
__global__ __launch_bounds__(256, 4) void kv_mfma_kernel(
    const float* __restrict__ md, const float* __restrict__ na, const float* __restrict__ ea,
    const __bf16* __restrict__ ts1P, const __bf16* __restrict__ a1P,
    const __bf16* __restrict__ e1P,
    const float* __restrict__ b_ts1, const float* __restrict__ b_a1,
    const float* __restrict__ b_e1,
    const __bf16* __restrict__ ts2T, const __bf16* __restrict__ a2T,
    const __bf16* __restrict__ e2T,
    const float* __restrict__ b_ts2, const float* __restrict__ b_a2,
    const float* __restrict__ b_e2,
    const __bf16* __restrict__ WkT, const float* __restrict__ bk,
    const __bf16* __restrict__ WvT, const float* __restrict__ bv,
    const float* __restrict__ pe, __bf16* __restrict__ Kb, __bf16* __restrict__ Vf) {
    int blk = blockIdx.x;          // 4b * 16n * 16t = 1024
    int t0 = (blk & 15) * 32;
    int n = (blk >> 4) & 15;
    int b = blk >> 8;
    int tid = threadIdx.x, lane = tid & 63;
    int wq = tid >> 6;             // wave = col quarter
    int lr = lane & 15, lg = lane >> 4;

    __shared__ __bf16 sA[32 * 40];
    __shared__ __bf16 sU[17536];
    __bf16* hts = sU;                   // [32][204]
    __bf16* haux = sU + 6528;           // [32][76]
    __bf16* hedge = sU + 8960;          // [32][268]
    __bf16* skey = sU;                  // [32][268]
    __bf16* sval = sU + 8576;           // [32][268]

    for (int i = tid; i < 32 * 40; i += 256) sA[i] = (__bf16)0.f;
    __syncthreads();
    {
        int t = tid & 31, c0 = tid >> 5;
        size_t bn = (size_t)b * N_ + n;
        for (int c = c0; c < 13; c += 8) {
            float v;
            if (c < 6) v = md[(bn * CTS_ + c) * T_ + t0 + t];
            else if (c < 10) v = na[(bn * CN_ + (c - 6)) * T_ + t0 + t];
            else v = ea[(bn * CE_ + (c - 10)) * T_ + t0 + t];
            sA[t * 40 + c] = (__bf16)v;
        }
    }
    __syncthreads();

    int foff = lr * 32 + lg * 8;
    f32x4 z4 = {0.f, 0.f, 0.f, 0.f};
    bf16x8 a1f0 = *(const bf16x8*)(sA + lr * 40 + lg * 8);
    bf16x8 a1f1 = *(const bf16x8*)(sA + (16 + lr) * 40 + lg * 8);
    int crow0 = lg * 4;

    // ---- phase 2: first layers (K=32)
    {
        bool isTs = (wq < 3);
#pragma unroll
        for (int i = 0; i < 4; ++i) {
            int ctn = wq * 4 + i;
            const __bf16* src = isTs ? (ts1P + ctn * 512) : (a1P + (ctn - 12) * 512);
            bf16x8 bf = *(const bf16x8*)(src + foff);
            f32x4 c0 = __builtin_amdgcn_mfma_f32_16x16x32_bf16(a1f0, bf, z4, 0, 0, 0);
            f32x4 c1 = __builtin_amdgcn_mfma_f32_16x16x32_bf16(a1f1, bf, z4, 0, 0, 0);
            if (isTs) {
                int gcol = ctn * 16 + lr;
                float bias = b_ts1[gcol];
#pragma unroll
                for (int r = 0; r < 4; ++r) {
                    hts[(crow0 + r) * HTS_S + gcol] = (__bf16)fmaxf(c0[r] + bias, 0.f);
                    hts[(16 + crow0 + r) * HTS_S + gcol] = (__bf16)fmaxf(c1[r] + bias, 0.f);
                }
            } else {
                int acol = (ctn - 12) * 16 + lr;
                float bias = b_a1[acol];
#pragma unroll
                for (int r = 0; r < 4; ++r) {
                    haux[(crow0 + r) * HAUX_S + acol] = (__bf16)fmaxf(c0[r] + bias, 0.f);
                    haux[(16 + crow0 + r) * HAUX_S + acol] = (__bf16)fmaxf(c1[r] + bias, 0.f);
                }
            }
        }
#pragma unroll
        for (int i = 0; i < 4; ++i) {
            int cte = wq * 4 + i;
            bf16x8 bf = *(const bf16x8*)(e1P + cte * 512 + foff);
            f32x4 c0 = __builtin_amdgcn_mfma_f32_16x16x32_bf16(a1f0, bf, z4, 0, 0, 0);
            f32x4 c1 = __builtin_amdgcn_mfma_f32_16x16x32_bf16(a1f1, bf, z4, 0, 0, 0);
            int gcol = cte * 16 + lr;
            float bias = b_e1[gcol];
#pragma unroll
            for (int r = 0; r < 4; ++r) {
                hedge[(crow0 + r) * HED_S + gcol] = (__bf16)fmaxf(c0[r] + bias, 0.f);
                hedge[(16 + crow0 + r) * HED_S + gcol] = (__bf16)fmaxf(c1[r] + bias, 0.f);
            }
        }
    }
    __syncthreads();

    // ---- phase 3a: edge second layer
    f32x4 eacc[2][4];
#pragma unroll
    for (int i = 0; i < 4; ++i) { eacc[0][i] = z4; eacc[1][i] = z4; }
    {
        const __bf16* ebase = e2T + (size_t)(wq * 4) * 8 * 512 + foff;
        bf16x8 bcur[4];
#pragma unroll
        for (int i = 0; i < 4; ++i) bcur[i] = *(const bf16x8*)(ebase + i * 4096);
#pragma unroll 1
        for (int ks = 0; ks < 8; ++ks) {
            bf16x8 bnext[4];
            if (ks < 7) {
#pragma unroll
                for (int i = 0; i < 4; ++i)
                    bnext[i] = *(const bf16x8*)(ebase + i * 4096 + (ks + 1) * 512);
            }
            __builtin_amdgcn_sched_barrier(0);
            bf16x8 af0 = *(const bf16x8*)(hedge + lr * HED_S + ks * 32 + lg * 8);
            bf16x8 af1 = *(const bf16x8*)(hedge + (16 + lr) * HED_S + ks * 32 + lg * 8);
#pragma unroll
            for (int i = 0; i < 4; ++i) {
                eacc[0][i] = __builtin_amdgcn_mfma_f32_16x16x32_bf16(af0, bcur[i], eacc[0][i], 0, 0, 0);
                eacc[1][i] = __builtin_amdgcn_mfma_f32_16x16x32_bf16(af1, bcur[i], eacc[1][i], 0, 0, 0);
            }
            if (ks < 7) {
#pragma unroll
                for (int i = 0; i < 4; ++i) bcur[i] = bnext[i];
            }
        }
    }

    // ---- phase 3b: nbr second layer
    f32x4 nacc[2][4];
#pragma unroll
    for (int i = 0; i < 4; ++i) { nacc[0][i] = z4; nacc[1][i] = z4; }
    if (wq < 3) {
        const __bf16* nbase = ts2T + (size_t)(wq * 4) * 6 * 512 + foff;
        bf16x8 bcur[4];
#pragma unroll
        for (int i = 0; i < 4; ++i) bcur[i] = *(const bf16x8*)(nbase + i * 3072);
#pragma unroll 1
        for (int ks = 0; ks < 6; ++ks) {
            bf16x8 bnext[4];
            if (ks < 5) {
#pragma unroll
                for (int i = 0; i < 4; ++i)
                    bnext[i] = *(const bf16x8*)(nbase + i * 3072 + (ks + 1) * 512);
            }
            __builtin_amdgcn_sched_barrier(0);
            bf16x8 af0 = *(const bf16x8*)(hts + lr * HTS_S + ks * 32 + lg * 8);
            bf16x8 af1 = *(const bf16x8*)(hts + (16 + lr) * HTS_S + ks * 32 + lg * 8);
#pragma unroll
            for (int i = 0; i < 4; ++i) {
                nacc[0][i] = __builtin_amdgcn_mfma_f32_16x16x32_bf16(af0, bcur[i], nacc[0][i], 0, 0, 0);
                nacc[1][i] = __builtin_amdgcn_mfma_f32_16x16x32_bf16(af1, bcur[i], nacc[1][i], 0, 0, 0);
            }
            if (ks < 5) {
#pragma unroll
                for (int i = 0; i < 4; ++i) bcur[i] = bnext[i];
            }
        }
    } else {
#pragma unroll
        for (int ks = 0; ks < 2; ++ks) {
            bf16x8 af0 = *(const bf16x8*)(haux + lr * HAUX_S + ks * 32 + lg * 8);
            bf16x8 af1 = *(const bf16x8*)(haux + (16 + lr) * HAUX_S + ks * 32 + lg * 8);
#pragma unroll
            for (int i = 0; i < 4; ++i) {
                bf16x8 bf = *(const bf16x8*)(a2T + (i * 2 + ks) * 512 + foff);
                nacc[0][i] = __builtin_amdgcn_mfma_f32_16x16x32_bf16(af0, bf, nacc[0][i], 0, 0, 0);
                nacc[1][i] = __builtin_amdgcn_mfma_f32_16x16x32_bf16(af1, bf, nacc[1][i], 0, 0, 0);
            }
        }
    }
    __syncthreads();

    // ---- phase 3c: key/val assembly
#pragma unroll
    for (int i = 0; i < 4; ++i) {
        int gcol = wq * 64 + i * 16 + lr;
        float nb_bias = (wq < 3) ? b_ts2[gcol] : b_a2[gcol - 192];
        float ed_bias = b_e2[gcol];
#pragma unroll
        for (int rf = 0; rf < 2; ++rf)
#pragma unroll
            for (int r = 0; r < 4; ++r) {
                int row = rf * 16 + crow0 + r;
                float p = pe[(t0 + row) * D_ + gcol];
                float nb = nacc[rf][i][r] + nb_bias;
                float ed = eacc[rf][i][r] + ed_bias;
                skey[row * SK_S + gcol] = (__bf16)(nb * ed + p);
                sval[row * SK_S + gcol] = (__bf16)(nb + p);
            }
    }
    __syncthreads();

    size_t key0 = (size_t)n * T_ + t0;

    // ---- phase 4a: K projection
    {
        const __bf16* kbse = WkT + (size_t)(wq * 4) * 8 * 512 + foff;
        f32x4 ka[2][4];
#pragma unroll
        for (int i = 0; i < 4; ++i) { ka[0][i] = z4; ka[1][i] = z4; }
        bf16x8 bcur[4];
#pragma unroll
        for (int i = 0; i < 4; ++i) bcur[i] = *(const bf16x8*)(kbse + i * 4096);
#pragma unroll 1
        for (int ks = 0; ks < 8; ++ks) {
            bf16x8 bnext[4];
            if (ks < 7) {
#pragma unroll
                for (int i = 0; i < 4; ++i)
                    bnext[i] = *(const bf16x8*)(kbse + i * 4096 + (ks + 1) * 512);
            }
            __builtin_amdgcn_sched_barrier(0);
            bf16x8 af0 = *(const bf16x8*)(skey + lr * SK_S + ks * 32 + lg * 8);
            bf16x8 af1 = *(const bf16x8*)(skey + (16 + lr) * SK_S + ks * 32 + lg * 8);
#pragma unroll
            for (int i = 0; i < 4; ++i) {
                ka[0][i] = __builtin_amdgcn_mfma_f32_16x16x32_bf16(af0, bcur[i], ka[0][i], 0, 0, 0);
                ka[1][i] = __builtin_amdgcn_mfma_f32_16x16x32_bf16(af1, bcur[i], ka[1][i], 0, 0, 0);
            }
            if (ks < 7) {
#pragma unroll
                for (int i = 0; i < 4; ++i) bcur[i] = bnext[i];
            }
        }
#pragma unroll
        for (int i = 0; i < 4; ++i) {
            int gcol = wq * 64 + i * 16 + lr;
            float kbias = bk[gcol];
            int h = gcol >> 5, dd = gcol & 31;
            size_t bh = (size_t)b * H_ + h;
#pragma unroll
            for (int rf = 0; rf < 2; ++rf) {
                int crow = rf * 16 + crow0;
#pragma unroll
                for (int r = 0; r < 4; ++r)
                    Kb[(bh * NT_ + key0 + crow + r) * DK_ + dd] = (__bf16)(ka[rf][i][r] + kbias);
            }
        }
    }

    // ---- phase 4b: V projection
    {
        const __bf16* vbse = WvT + (size_t)(wq * 4) * 8 * 512 + foff;
        f32x4 va[2][4];
#pragma unroll
        for (int i = 0; i < 4; ++i) { va[0][i] = z4; va[1][i] = z4; }
        bf16x8 bcur[4];
#pragma unroll
        for (int i = 0; i < 4; ++i) bcur[i] = *(const bf16x8*)(vbse + i * 4096);
#pragma unroll 1
        for (int ks = 0; ks < 8; ++ks) {
            bf16x8 bnext[4];
            if (ks < 7) {
#pragma unroll
                for (int i = 0; i < 4; ++i)
                    bnext[i] = *(const bf16x8*)(vbse + i * 4096 + (ks + 1) * 512);
            }
            __builtin_amdgcn_sched_barrier(0);
            bf16x8 af0 = *(const bf16x8*)(sval + lr * SK_S + ks * 32 + lg * 8);
            bf16x8 af1 = *(const bf16x8*)(sval + (16 + lr) * SK_S + ks * 32 + lg * 8);
#pragma unroll
            for (int i = 0; i < 4; ++i) {
                va[0][i] = __builtin_amdgcn_mfma_f32_16x16x32_bf16(af0, bcur[i], va[0][i], 0, 0, 0);
                va[1][i] = __builtin_amdgcn_mfma_f32_16x16x32_bf16(af1, bcur[i], va[1][i], 0, 0, 0);
            }
            if (ks < 7) {
#pragma unroll
                for (int i = 0; i < 4; ++i) bcur[i] = bnext[i];
            }
        }
#pragma unroll
        for (int i = 0; i < 4; ++i) {
            int gcol = wq * 64 + i * 16 + lr;
            float vbias = bv[gcol];
            int h = gcol >> 5, dd = gcol & 31;
            size_t bh = (size_t)b * H_ + h;
#pragma unroll
            for (int rf = 0; rf < 2; ++rf) {
                int crow = rf * 16 + crow0;
                __bf16 tmp[4];
#pragma unroll
                for (int r = 0; r < 4; ++r) tmp[r] = (__bf16)(va[rf][i][r] + vbias);
                size_t kg = key0 + crow;
                int within = (int)(kg & 63);
                int vks = within >> 4, vl5 = (within >> 3) & 1, j0 = within & 7;
                size_t tile = kg >> 6;
                size_t vaddr = ((bh * (NT_ / 64) + tile) * 4 + vks) * 512 +
                               (size_t)(vl5 * 32 + dd) * 8 + j0;
                *(ushort4*)(Vf + vaddr) = *(ushort4*)tmp;
            }
        }
    }
}

// ------- xq = x + pe, row-parallel LayerNorm, MFMA Q proj (QSCALE in WqT)
// grid: B*(T/32) = 64 blocks
__global__ __launch_bounds__(256) void q_mfma_kernel(
    const float* __restrict__ x, const float* __restrict__ pe,
    const __bf16* __restrict__ WqT, const float* __restrict__ bq,
    const float* __restrict__ ln_g, const float* __restrict__ ln_b,
    float* __restrict__ xq, __bf16* __restrict__ Qb) {
    int blk = blockIdx.x;
    int t0 = (blk & 15) * 32;
    int b = blk >> 4;
    int tid = threadIdx.x, lane = tid & 63;
    int wq = tid >> 6, lr = lane & 15, lg = lane >> 4;

    __shared__ __bf16 s_xn[32 * SK_S];

    // ---- LN: 8 threads per row, all 32 rows in parallel
    {
        int row = tid >> 3, sub = tid & 7;
        size_t roff = ((size_t)b * T_ + t0 + row) * D_;
        const float* pr = pe + (t0 + row) * D_;
        f32x4 vv[8];
        float s1 = 0.f, s2 = 0.f;
#pragma unroll
        for (int q4 = 0; q4 < 8; ++q4) {
            int c = q4 * 32 + sub * 4;
            f32x4 xv = *(const f32x4*)(x + roff + c);
            f32x4 pv = *(const f32x4*)(pr + c);
            f32x4 t4;
#pragma unroll
            for (int j = 0; j < 4; ++j) {
                t4[j] = xv[j] + pv[j];
                s1 += t4[j];
                s2 += t4[j] * t4[j];
            }
            *(f32x4*)(xq + roff + c) = t4;
            vv[q4] = t4;
        }
#pragma unroll
        for (int o = 1; o <= 4; o <<= 1) {
            s1 += __shfl_xor(s1, o, 64);
            s2 += __shfl_xor(s2, o, 64);
        }
        float mu = s1 * (1.f / D_);
        float var = s2 * (1.f / D_) - mu * mu;
        float rs = rsqrtf(var + 1e-6f);
#pragma unroll
        for (int q4 = 0; q4 < 8; ++q4) {
            int c = q4 * 32 + sub * 4;
            f32x4 g4 = *(const f32x4*)(ln_g + c);
            f32x4 b4 = *(const f32x4*)(ln_b + c);
#pragma unroll
            for (int j = 0; j < 4; ++j)
                s_xn[row * SK_S + c + j] = (__bf16)((vv[q4][j] - mu) * rs * g4[j] + b4[j]);
        }
    }
    __syncthreads();

    // ---- MFMA projection (kv phase-4 pattern)
    int foff = lr * 32 + lg * 8;
    int crow0 = lg * 4;
    f32x4 z4 = {0.f, 0.f, 0.f, 0.f};
    f32x4 qa[2][4];
#pragma unroll
    for (int i = 0; i < 4; ++i) { qa[0][i] = z4; qa[1][i] = z4; }
    const __bf16* qbse = WqT + (size_t)(wq * 4) * 8 * 512 + foff;
#pragma unroll
    for (int ks = 0; ks < 8; ++ks) {
        bf16x8 af0 = *(const bf16x8*)(s_xn + lr * SK_S + ks * 32 + lg * 8);
        bf16x8 af1 = *(const bf16x8*)(s_xn + (16 + lr) * SK_S + ks * 32 + lg * 8);
#pragma unroll
        for (int i = 0; i < 4; ++i) {
            bf16x8 b8 = *(const bf16x8*)(qbse + i * 4096 + ks * 512);
            qa[0][i] = __builtin_amdgcn_mfma_f32_16x16x32_bf16(af0, b8, qa[0][i], 0, 0, 0);
            qa[1][i] = __builtin_amdgcn_mfma_f32_16x16x32_bf16(af1, b8, qa[1][i], 0, 0, 0);
        }
    }
#pragma unroll
    for (int i = 0; i < 4; ++i) {
        int gcol = wq * 64 + i * 16 + lr;
        float bias = bq[gcol] * QSCALE_;
#pragma unroll
        for (int rf = 0; rf < 2; ++rf)
#pragma unroll
            for (int r = 0; r < 4; ++r)
                Qb[((size_t)b * T_ + t0 + rf * 16 + crow0 + r) * D_ + gcol] =
                    (__bf16)(qa[rf][i][r] + bias);
    }
}

// ------- 32x32 MFMA attention: native __expf, sbfe mask, l via ones-MFMA
__global__ __launch_bounds__(256, 4) void attn_mfma_kernel(
    const __bf16* __restrict__ Qb, const __bf16* __restrict__ Kb,
    const __bf16* __restrict__ Vf, const ull* __restrict__ bitsT,
    float* __restrict__ Opart, float* __restrict__ Lpart) {
    int blk = blockIdx.x;
    int kh = blk & (SPLIT_ - 1);
    int qt = (blk >> 3) & 3;
    int h = (blk >> 5) & 7;
    int b = blk >> 8;
    int tid = threadIdx.x, lane = tid & 63, w = tid >> 6;
    int lq = lane & 31, l5 = lane >> 5;

    const size_t bh = (size_t)b * H_ + h;
    const int TILES = KWORDS_ / SPLIT_;   // 16

    int qglob = qt * 128 + w * 32 + lq;
    const __bf16* qbase = Qb + ((size_t)b * T_ + qglob) * D_ + h * DK_ + l5 * 8;
    bf16x8 qf0 = *(const bf16x8*)(qbase);
    bf16x8 qf1 = *(const bf16x8*)(qbase + 16);

    const __bf16* kp = Kb + bh * NT_ * DK_ + (size_t)(kh * TILES) * 64 * DK_;
    const __bf16* vp = Vf + (bh * (NT_ / 64) + (size_t)(kh * TILES)) * 2048;
    const ull* mp = bitsT + (size_t)b * KWORDS_ * T_ + (size_t)(kh * TILES) * T_ + qglob;

    int k00 = lq * DK_ + l5 * 8;
    int k01 = k00 + 16;
    int k10 = (32 + lq) * DK_ + l5 * 8;
    int k11 = k10 + 16;
    int shamt = 4 * l5;

    f32x16 acc, acc_l, zv;
#pragma unroll
    for (int i = 0; i < 16; ++i) { acc[i] = 0.f; acc_l[i] = 0.f; zv[i] = 0.f; }
    union { uint u[4]; bf16x8 v; } onesf;
    onesf.u[0] = 0x3F803F80u; onesf.u[1] = 0x3F803F80u;
    onesf.u[2] = 0x3F803F80u; onesf.u[3] = 0x3F803F80u;

    bf16x8 kc0 = *(const bf16x8*)(kp + k00);
    bf16x8 kc1 = *(const bf16x8*)(kp + k01);
    bf16x8 kc2 = *(const bf16x8*)(kp + k10);
    bf16x8 kc3 = *(const bf16x8*)(kp + k11);
    ull mw = *mp;

#pragma unroll 1
    for (int kt = 0; kt < TILES; ++kt) {
        bf16x8 vc0 = *(const bf16x8*)(vp + 0 * 512 + lane * 8);
        bf16x8 vc1 = *(const bf16x8*)(vp + 1 * 512 + lane * 8);
        bf16x8 vc2 = *(const bf16x8*)(vp + 2 * 512 + lane * 8);
        bf16x8 vc3 = *(const bf16x8*)(vp + 3 * 512 + lane * 8);
        bf16x8 kn0, kn1, kn2, kn3;
        ull mn = 0;
        if (kt + 1 < TILES) {
            kn0 = *(const bf16x8*)(kp + 2048 + k00);
            kn1 = *(const bf16x8*)(kp + 2048 + k01);
            kn2 = *(const bf16x8*)(kp + 2048 + k10);
            kn3 = *(const bf16x8*)(kp + 2048 + k11);
            mn = mp[T_];
        }
        __builtin_amdgcn_sched_barrier(0);

        ull sh = mw >> shamt;

#pragma unroll
        for (int s = 0; s < 2; ++s) {
            f32x16 sc = __builtin_amdgcn_mfma_f32_32x32x16_bf16(
                s ? kc2 : kc0, qf0, zv, 0, 0, 0);
            sc = __builtin_amdgcn_mfma_f32_32x32x16_bf16(
                s ? kc3 : kc1, qf1, sc, 0, 0, 0);

            uint ms = (uint)(sh >> (32 * s));
            float p[16];
#pragma unroll
            for (int r = 0; r < 16; ++r) {
                int pos = (r & 3) + 8 * (r >> 2);
                float e = __expf(sc[r]);                          // native v_exp
                int mb = __builtin_amdgcn_sbfe((int)ms, (uint)pos, 1u);  // 0 or -1
                p[r] = __uint_as_float(__float_as_uint(e) & (uint)mb);
            }

#pragma unroll
            for (int h2 = 0; h2 < 2; ++h2) {
                uint w0, w1, w2, w3;
                asm("v_cvt_pk_bf16_f32 %0, %1, %2" : "=v"(w0) : "v"(p[8 * h2 + 0]), "v"(p[8 * h2 + 1]));
                asm("v_cvt_pk_bf16_f32 %0, %1, %2" : "=v"(w1) : "v"(p[8 * h2 + 2]), "v"(p[8 * h2 + 3]));
                asm("v_cvt_pk_bf16_f32 %0, %1, %2" : "=v"(w2) : "v"(p[8 * h2 + 4]), "v"(p[8 * h2 + 5]));
                asm("v_cvt_pk_bf16_f32 %0, %1, %2" : "=v"(w3) : "v"(p[8 * h2 + 6]), "v"(p[8 * h2 + 7]));
                asm volatile("v_permlane32_swap_b32 %0, %1" : "+v"(w0), "+v"(w2));
                asm volatile("v_permlane32_swap_b32 %0, %1" : "+v"(w1), "+v"(w3));
                union { uint u[4]; bf16x8 v; } pa;
                pa.u[0] = w0; pa.u[1] = w1; pa.u[2] = w2; pa.u[3] = w3;
                bf16x8 vfr = (s == 0) ? (h2 == 0 ? vc0 : vc1) : (h2 == 0 ? vc2 : vc3);
                acc = __builtin_amdgcn_mfma_f32_32x32x16_bf16(pa.v, vfr, acc, 0, 0, 0);
                acc_l = __builtin_amdgcn_mfma_f32_32x32x16_bf16(pa.v, onesf.v, acc_l, 0, 0, 0);
            }
        }

        kp += 2048;
        vp += 2048;
        mp += T_;
        if (kt + 1 < TILES) {
            kc0 = kn0; kc1 = kn1; kc2 = kn2; kc3 = kn3;
            mw = mn;
        }
    }

    size_t obase = (((size_t)kh * B_ + b) * H_ + h) * T_ + qt * 128 + w * 32;
#pragma unroll
    for (int r = 0; r < 16; ++r) {
        int q = (r & 3) + 8 * (r >> 2) + 4 * l5;
        Opart[(obase + q) * DK_ + lq] = acc[r];
    }
    if (lq == 0) {
#pragma unroll
        for (int r = 0; r < 16; ++r) {
            int q = (r & 3) + 8 * (r >> 2) + 4 * l5;
            Lpart[obase + q] = acc_l[r];
        }
    }
}

// ------------------------------ merge split-K partials -> ctx bf16
__global__ __launch_bounds__(256) void merge_kernel(
    const float* __restrict__ Opart, const float* __restrict__ Lpart,
    __bf16* __restrict__ ctxb) {
    int idx = blockIdx.x * 256 + threadIdx.x;  // B*H*T*32 total
    int d = idx & 31;
    int t = (idx >> 5) & (T_ - 1);
    int bh = idx >> 14;
    int h = bh & 7, b = bh >> 3;
    size_t ps = (size_t)B_ * H_ * T_;
    size_t base = (size_t)bh * T_ + t;
    float L = 0.f, o = 0.f;
#pragma unroll
    for (int s = 0; s < SPLIT_; ++s) {
        L += Lpart[s * ps + base];
        o += Opart[(s * ps + base) * DK_ + d];
    }
    ctxb[((size_t)b * T_ + t) * D_ + h * DK_ + d] = (__bf16)(o / L);
}

// ------------------------------ out = xq + ctx@Wo + bo (MFMA), grid 64
__global__ __launch_bounds__(256) void out_mfma_kernel(
    const __bf16* __restrict__ ctxb, const float* __restrict__ xq,
    const __bf16* __restrict__ WoT, const float* __restrict__ bo,
    float* __restrict__ out) {
    int blk = blockIdx.x;
    int t0 = (blk & 15) * 32;
    int b = blk >> 4;
    int tid = threadIdx.x, lane = tid & 63;
    int wq = tid >> 6, lr = lane & 15, lg = lane >> 4;

    __shared__ __bf16 sc_[32 * SK_S];
    for (int idx = tid; idx < 32 * 64; idx += 256) {
        int r = idx >> 6, c4 = (idx & 63) * 4;
        *(ushort4*)(sc_ + r * SK_S + c4) =
            *(const ushort4*)(ctxb + ((size_t)b * T_ + t0 + r) * D_ + c4);
    }
    __syncthreads();

    int foff = lr * 32 + lg * 8;
    int crow0 = lg * 4;
    f32x4 z4 = {0.f, 0.f, 0.f, 0.f};
    f32x4 oa[2][4];
#pragma unroll
    for (int i = 0; i < 4; ++i) { oa[0][i] = z4; oa[1][i] = z4; }
    const __bf16* obse = WoT + (size_t)(wq * 4) * 8 * 512 + foff;
#pragma unroll
    for (int ks = 0; ks < 8; ++ks) {
        bf16x8 af0 = *(const bf16x8*)(sc_ + lr * SK_S + ks * 32 + lg * 8);
        bf16x8 af1 = *(const bf16x8*)(sc_ + (16 + lr) * SK_S + ks * 32 + lg * 8);
#pragma unroll
        for (int i = 0; i < 4; ++i) {
            bf16x8 b8 = *(const bf16x8*)(obse + i * 4096 + ks * 512);
            oa[0][i] = __builtin_amdgcn_mfma_f32_16x16x32_bf16(af0, b8, oa[0][i], 0, 0, 0);
            oa[1][i] = __builtin_amdgcn_mfma_f32_16x16x32_bf16(af1, b8, oa[1][i], 0, 0, 0);
        }
    }
#pragma unroll
    for (int i = 0; i < 4; ++i) {
        int gcol = wq * 64 + i * 16 + lr;
        float bias = bo[gcol];
#pragma unroll
        for (int rf = 0; rf < 2; ++rf)
#pragma unroll
            for (int r = 0; r < 4; ++r) {
                size_t off = ((size_t)b * T_ + t0 + rf * 16 + crow0 + r) * D_ + gcol;
                out[off] = xq[off] + oa[rf][i][r] + bias;
            }
    }
}

// ---------------------------------------------------------------- launcher
extern "C" void kernel_launch(void* const* d_in, const int* in_sizes, int n_in,
                              void* d_out, int out_size, void* d_ws, size_t ws_size,
                              hipStream_t stream) {
    const float* x = (const float*)d_in[0];
    const float* md = (const float*)d_in[1];
    const float* na = (const float*)d_in[2];
    const float* ea = (const float*)d_in[3];
    const int* mask = (const int*)d_in[4];
    const float* W_ts1 = (const float*)d_in[5];
    const float* b_ts1 = (const float*)d_in[6];
    const float* W_ts2 = (const float*)d_in[7];
    const float* b_ts2 = (const float*)d_in[8];
    const float* W_a1 = (const float*)d_in[9];
    const float* b_a1 = (const float*)d_in[10];
    const float* W_a2 = (const float*)d_in[11];
    const float* b_a2 = (const float*)d_in[12];
    const float* W_e1 = (const float*)d_in[13];
    const float* b_e1 = (const float*)d_in[14];
    const float* W_e2 = (const float*)d_in[15];
    const float* b_e2 = (const float*)d_in[16];
    const float* Wq = (const float*)d_in[17];
    const float* bq = (const float*)d_in[18];
    const float* Wk = (const float*)d_in[19];
    const float* bk = (const float*)d_in[20];
    const float* Wv = (const float*)d_in[21];
    const float* bv = (const float*)d_in[22];
    const float* Wo = (const float*)d_in[23];
    const float* bo = (const float*)d_in[24];
    const float* ln_g = (const float*)d_in[25];
    const float* ln_b = (const float*)d_in[26];
    float* out = (float*)d_out;

    char* ws = (char*)d_ws;
    float* pe = (float*)ws;     ws += (size_t)T_ * D_ * 4;
    ull* bitsT = (ull*)ws;      ws += (size_t)B_ * KWORDS_ * T_ * 8;
    __bf16* Kb = (__bf16*)ws;   ws += (size_t)B_ * H_ * NT_ * DK_ * 2;
    __bf16* Vf = (__bf16*)ws;   ws += (size_t)B_ * H_ * NT_ * DK_ * 2;
    float* xq = (float*)ws;     ws += (size_t)B_ * T_ * D_ * 4;
    __bf16* Qb = (__bf16*)ws;   ws += (size_t)B_ * T_ * D_ * 2;
    __bf16* ctxb = (__bf16*)ws; ws += (size_t)B_ * T_ * D_ * 2;
    float* Opart = (float*)ws;  ws += (size_t)SPLIT_ * B_ * H_ * T_ * DK_ * 4;
    float* Lpart = (float*)ws;  ws += (size_t)SPLIT_ * B_ * H_ * T_ * 4;
    // bf16 prepped weights
    __bf16* ts1P = (__bf16*)ws; ws += 6144 * 2;
    __bf16* a1P = (__bf16*)ws;  ws += 2048 * 2;
    __bf16* e1P = (__bf16*)ws;  ws += 8192 * 2;
    __bf16* ts2T = (__bf16*)ws; ws += 36864 * 2;
    __bf16* a2T = (__bf16*)ws;  ws += 4096 * 2;
    __bf16* e2T = (__bf16*)ws;  ws += 65536 * 2;
    __bf16* WkT = (__bf16*)ws;  ws += 65536 * 2;
    __bf16* WvT = (__bf16*)ws;  ws += 65536 * 2;
    __bf16* WqT = (__bf16*)ws;  ws += 65536 * 2;
    __bf16* WoT = (__bf16*)ws;  ws += 65536 * 2;

    pe_kernel<<<T_, 256, 0, stream>>>(pe);
    maskbits_kernel<<<B_ * T_, 256, 0, stream>>>(mask, bitsT);
    wprep_kernel<<<1504, 256, 0, stream>>>(W_ts1, W_a1, W_e1, W_ts2, W_a2, W_e2,
                                           Wk, Wv, Wq, Wo,
                                           ts1P, a1P, e1P, ts2T, a2T, e2T,
                                           WkT, WvT, WqT, WoT);
    kv_mfma_kernel<<<B_ * N_ * (T_ / 32), 256, 0, stream>>>(
        md, na, ea, ts1P, a1P, e1P, b_ts1, b_a1, b_e1,
        ts2T, a2T, e2T, b_ts2, b_a2, b_e2, WkT, bk, WvT, bv, pe, Kb, Vf);
    q_mfma_kernel<<<B_ * (T_ / 32), 256, 0, stream>>>(x, pe, WqT, bq, ln_g, ln_b, xq, Qb);
    attn_mfma_kernel<<<B_ * H_ * (T_ / 128) * SPLIT_, 256, 0, stream>>>(
        Qb, Kb, Vf, bitsT, Opart, Lpart);
    merge_kernel<<<(B_ * H_ * T_ * DK_) / 256, 256, 0, stream>>>(Opart, Lpart, ctxb);
    out_mfma_kernel<<<B_ * (T_ / 32), 256, 0, stream>>>(ctxb, xq, WoT, bo, out);
}